// Round 10
// baseline (566.255 us; speedup 1.0000x reference)
//
#include <hip/hip_runtime.h>
#include <stdint.h>

// ---------------- constants ----------------
#define NPOS 2500      // 50*50
#define NANCH 22500    // NPOS*9
#define NPRE 6000
#define NW 94          // ceil(6000/64)
#define XPAD 2704      // 52*52 padded plane
#define NSLOT 94       // ceil(NPRE/64) radix slots

// async global->LDS DMA (gfx950). dst is wave-uniform base + lane*size.
__device__ __forceinline__ void gl_lds4(const float* g, float* l) {
  __builtin_amdgcn_global_load_lds((const __attribute__((address_space(1))) void*)g,
                                   (__attribute__((address_space(3))) void*)l, 4, 0, 0);
}
__device__ __forceinline__ void gl_lds16(const float* g, float* l) {
  __builtin_amdgcn_global_load_lds((const __attribute__((address_space(1))) void*)g,
                                   (__attribute__((address_space(3))) void*)l, 16, 0, 0);
}

// ---------------- zero-pad x: [b][ic][50][50] -> [b][ic][52][52] ----------------
__global__ __launch_bounds__(256) void pad_x(const float* __restrict__ x,
                                             float* __restrict__ xp) {
  int t = blockIdx.x * 256 + threadIdx.x;
  if (t >= 2 * 256 * XPAD) return;
  int c = t / XPAD;        // b*256 + ic
  int r = t % XPAD;
  int yy = r / 52, xx = r % 52;
  float v = 0.f;
  if (yy >= 1 && yy <= 50 && xx >= 1 && xx <= 50)
    v = x[(size_t)c * NPOS + (yy - 1) * 50 + (xx - 1)];
  xp[t] = v;
}

// ---------------- weight transpose: w[oc][ic][3][3] -> wt[(tap*256+ic)][oc] ----------------
__global__ __launch_bounds__(256) void transpose_w(const float* __restrict__ w,
                                                   float* __restrict__ wt) {
  __shared__ float tile[32][33];
  int k0 = blockIdx.x * 32;   // k' = ic*9 + tap, 0..2303
  int o0 = blockIdx.y * 32;
  int tx = threadIdx.x & 31;
  int ty = threadIdx.x >> 5;  // 0..7
#pragma unroll
  for (int i = 0; i < 4; ++i) {
    int oc = o0 + ty + i * 8;
    int kp = k0 + tx;
    tile[ty + i * 8][tx] = w[(size_t)oc * 2304 + kp];
  }
  __syncthreads();
#pragma unroll
  for (int i = 0; i < 4; ++i) {
    int kp = k0 + ty + i * 8;
    int ic = kp / 9, tap = kp % 9;
    wt[((size_t)tap * 256 + ic) * 512 + (o0 + tx)] = tile[tx][ty + i * 8];
  }
}

// ---------------- conv1 3x3 SAME + bias + relu, output NHWC h[b][p][oc] ----------------
// R10: conv is LDS-READ-THROUGHPUT bound (R7/R9 model: ~46K ds_read_b128/CU ~= the
// whole 203-227us). Fix: 128 threads (2 waves), 64x64 tile, acc[8][4]/thread ->
// 3 ds_read_b128 per 2x FMAs (1.5 B/FMA vs 2.0) = 25% less LDS traffic, grid
// unchanged (640 blocks). Single-buffer R7 loop (dbuf lost by 24us, R8/R9).
// Per-output fmaf (c,kk) order unchanged -> bitwise-identical h.
__global__ __launch_bounds__(128) void conv1_gemm(const float* __restrict__ xp,
                                                  const float* __restrict__ wt,
                                                  const float* __restrict__ bias,
                                                  float* __restrict__ h) {
  __shared__ __align__(16) float As[32][64];
  __shared__ __align__(16) float Bs[32][64];
  int b = blockIdx.z;
  int m0 = blockIdx.x * 64;
  int oc0 = blockIdx.y * 64;
  int tid = threadIdx.x;
  int lane = tid & 63;
  int wv = tid >> 6;       // wave 0..1
  int tn = tid & 15;       // 16 x 4 = 64 oc
  int tm = tid >> 4;       // 0..7 -> 8 groups x 8 pos = 64 pos
  float acc[8][4] = {};

  int p = m0 + lane;
  int pc = p < NPOS ? p : (NPOS - 1);
  int py = pc / 50, px = pc % 50;
  const float* gA0 = xp + (size_t)b * 256 * XPAD + py * 52 + px + 53;
  int brow = lane >> 4, bcol4 = (lane & 15) * 4;

  for (int tap = 0; tap < 9; ++tap) {
    int ky = tap / 3 - 1, kx = tap % 3 - 1;
    int koff = ky * 52 + kx;
    for (int icc = 0; icc < 8; ++icc) {
      int ic0 = icc * 32;
      __syncthreads();  // LDS consumed by previous chunk's compute
      // A: wave wv stages rows wv*16 .. wv*16+15 (one width-4 DMA per row)
#pragma unroll
      for (int j = 0; j < 16; ++j) {
        int kk = wv * 16 + j;
        gl_lds4(gA0 + (size_t)(ic0 + kk) * XPAD + koff, &As[kk][0]);
      }
      // B: wave wv stages rows wv*16 .. wv*16+15 (four width-16 DMAs, 4 rows each)
#pragma unroll
      for (int q = 0; q < 4; ++q) {
        int r0 = wv * 16 + q * 4;
        gl_lds16(wt + ((size_t)tap * 256 + ic0 + r0 + brow) * 512 + oc0 + bcol4,
                 &Bs[r0][0]);
      }
      __syncthreads();  // drains vmcnt -> DMAs complete
#pragma unroll
      for (int kk = 0; kk < 32; ++kk) {
        float4 a0 = *(const float4*)&As[kk][tm * 8];
        float4 a1 = *(const float4*)&As[kk][tm * 8 + 4];
        float4 bv = *(const float4*)&Bs[kk][tn * 4];
        float am[8] = {a0.x, a0.y, a0.z, a0.w, a1.x, a1.y, a1.z, a1.w};
        float bn[4] = {bv.x, bv.y, bv.z, bv.w};
#pragma unroll
        for (int i = 0; i < 8; ++i)
#pragma unroll
          for (int j = 0; j < 4; ++j) acc[i][j] = fmaf(am[i], bn[j], acc[i][j]);
      }
    }
  }
#pragma unroll
  for (int i = 0; i < 8; ++i) {
    int pp = m0 + tm * 8 + i;
    if (pp < NPOS) {
      float4 v;
      float* vp = (float*)&v;
#pragma unroll
      for (int j = 0; j < 4; ++j) {
        int oc = oc0 + tn * 4 + j;
        vp[j] = fmaxf(acc[i][j] + bias[oc], 0.f);
      }
      *(float4*)&h[((size_t)b * NPOS + pp) * 512 + oc0 + tn * 4] = v;
    }
  }
}

// ---------------- heads: 1x1 convs + softmax + decode + valid ----------------
__global__ __launch_bounds__(64) void heads(const float* __restrict__ h,
                                            const float* __restrict__ objw,
                                            const float* __restrict__ objb,
                                            const float* __restrict__ locw,
                                            const float* __restrict__ locb,
                                            const float* __restrict__ anch,
                                            const int* __restrict__ imgh,
                                            const int* __restrict__ imgw,
                                            float* __restrict__ scores,
                                            float4* __restrict__ boxes) {
  __shared__ float hv[512];
  __shared__ float outs[64];
  int blk = blockIdx.x;
  int b = blk / NPOS, p = blk % NPOS;
  int lane = threadIdx.x;
  const float4* hp4 = (const float4*)(h + ((size_t)b * NPOS + p) * 512);
  float4* hv4 = (float4*)hv;
  hv4[lane] = hp4[lane];
  hv4[lane + 64] = hp4[lane + 64];
  __syncthreads();
  if (lane < 54) {
    const float* wrow;
    float acc;
    if (lane < 18) { wrow = objw + (size_t)lane * 512; acc = objb[lane]; }
    else           { wrow = locw + (size_t)(lane - 18) * 512; acc = locb[lane - 18]; }
    const float4* w4 = (const float4*)wrow;
#pragma unroll 4
    for (int k = 0; k < 128; ++k) {
      float4 wv = w4[k], hh = hv4[k];
      acc = fmaf(wv.x, hh.x, acc);
      acc = fmaf(wv.y, hh.y, acc);
      acc = fmaf(wv.z, hh.z, acc);
      acc = fmaf(wv.w, hh.w, acc);
    }
    outs[lane] = acc;
  }
  __syncthreads();
  if (lane < 9) {
    float l0 = outs[2 * lane], l1 = outs[2 * lane + 1];
    float mx = fmaxf(l0, l1);
    float e0 = expf(l0 - mx);
    float e1 = expf(l1 - mx);
    float s = e1 / (e0 + e1);
    float d0 = outs[18 + 4 * lane + 0];
    float d1 = outs[18 + 4 * lane + 1];
    float d2 = outs[18 + 4 * lane + 2];
    float d3 = outs[18 + 4 * lane + 3];
    int ai = p * 9 + lane;
    float4 A = ((const float4*)anch)[ai];
    float aw = A.z - A.x, ah = A.w - A.y;
    float acx = A.x + 0.5f * aw, acy = A.y + 0.5f * ah;
    float cx = acx + d0 * aw, cy = acy + d1 * ah;
    float w = aw * expf(d2), hh = ah * expf(d3);
    float W = (float)imgw[0], H = (float)imgh[0];
    float x1 = fminf(fmaxf(cx - 0.5f * w, 0.f), W);
    float y1 = fminf(fmaxf(cy - 0.5f * hh, 0.f), H);
    float x2 = fminf(fmaxf(cx + 0.5f * w, 0.f), W);
    float y2 = fminf(fmaxf(cy + 0.5f * hh, 0.f), H);
    bool valid = (x2 - x1 >= 16.f) && (y2 - y1 >= 16.f);
    scores[(size_t)b * NANCH + ai] = valid ? s : -1.f;
    boxes[(size_t)b * NANCH + ai] = make_float4(x1, y1, x2, y2);
  }
}

// ---------------- top-6000 select + stable radix sort (one block per batch) ----------------
__device__ inline unsigned int mono_of(float f) {
  unsigned int u = __float_as_uint(f);
  return (u & 0x80000000u) ? ~u : (u | 0x80000000u);
}

// R6 lesson: wave-aggregated hist_add REGRESSED (+67us). Plain atomics kept.
// R7: 6-pass 6-bit stable LSD radix replaced the bitonic (268 -> ~84us).
__global__ __launch_bounds__(1024) void topk_sort(const float* __restrict__ scores,
                                                  const float4* __restrict__ boxes,
                                                  float* __restrict__ sscore,
                                                  float4* __restrict__ sbox) {
  int b = blockIdx.x;
  const float* sc = scores + (size_t)b * NANCH;
  __shared__ unsigned int hist[4096];
  __shared__ unsigned int part[1024];
  __shared__ unsigned short pidA[6016];
  __shared__ unsigned short pidB[6016];
  __shared__ unsigned short table[6144];   // 64 digits x 94 slots (padded)
  __shared__ int res[8];
  int tid = threadIdx.x;
  int lane = tid & 63;
  int wv = tid >> 6;

  // ---------- phase 1: top-12-bit histogram ----------
  for (int i = tid; i < 4096; i += 1024) hist[i] = 0;
  __syncthreads();
  for (int i = tid; i < NANCH; i += 1024) atomicAdd(&hist[mono_of(sc[i]) >> 20], 1u);
  __syncthreads();
  {
    unsigned int h0 = hist[4 * tid], h1 = hist[4 * tid + 1];
    unsigned int h2 = hist[4 * tid + 2], h3 = hist[4 * tid + 3];
    part[tid] = h0 + h1 + h2 + h3;
    __syncthreads();
    for (int off = 1; off < 1024; off <<= 1) {
      unsigned int v = part[tid];
      unsigned int u = (tid + off < 1024) ? part[tid + off] : 0;
      __syncthreads();
      part[tid] = v + u;
      __syncthreads();
    }
    unsigned int c = (tid < 1023) ? part[tid + 1] : 0;  // strict suffix over groups
    const int need = NPRE;
    if (c < (unsigned)need && c + h3 >= (unsigned)need) { res[0] = 4 * tid + 3; res[1] = (int)c; }
    c += h3;
    if (c < (unsigned)need && c + h2 >= (unsigned)need) { res[0] = 4 * tid + 2; res[1] = (int)c; }
    c += h2;
    if (c < (unsigned)need && c + h1 >= (unsigned)need) { res[0] = 4 * tid + 1; res[1] = (int)c; }
    c += h1;
    if (c < (unsigned)need && c + h0 >= (unsigned)need) { res[0] = 4 * tid + 0; res[1] = (int)c; }
  }
  __syncthreads();
  int t1 = res[0], a1 = res[1];
  __syncthreads();

  // ---------- phase 2: middle-12 bits within bin t1 ----------
  for (int i = tid; i < 4096; i += 1024) hist[i] = 0;
  __syncthreads();
  for (int i = tid; i < NANCH; i += 1024) {
    unsigned int m = mono_of(sc[i]);
    if ((int)(m >> 20) == t1) atomicAdd(&hist[(m >> 8) & 0xFFF], 1u);
  }
  __syncthreads();
  {
    unsigned int h0 = hist[4 * tid], h1 = hist[4 * tid + 1];
    unsigned int h2 = hist[4 * tid + 2], h3 = hist[4 * tid + 3];
    part[tid] = h0 + h1 + h2 + h3;
    __syncthreads();
    for (int off = 1; off < 1024; off <<= 1) {
      unsigned int v = part[tid];
      unsigned int u = (tid + off < 1024) ? part[tid + off] : 0;
      __syncthreads();
      part[tid] = v + u;
      __syncthreads();
    }
    unsigned int c = (tid < 1023) ? part[tid + 1] : 0;
    const unsigned int need = (unsigned)(NPRE - a1);
    if (c < need && c + h3 >= need) { res[2] = 4 * tid + 3; res[3] = (int)c; }
    c += h3;
    if (c < need && c + h2 >= need) { res[2] = 4 * tid + 2; res[3] = (int)c; }
    c += h2;
    if (c < need && c + h1 >= need) { res[2] = 4 * tid + 1; res[3] = (int)c; }
    c += h1;
    if (c < need && c + h0 >= need) { res[2] = 4 * tid + 0; res[3] = (int)c; }
  }
  __syncthreads();
  int t2 = res[2], a2 = res[3];
  __syncthreads();

  // ---------- phase 3: low-8 bits within (t1,t2) ----------
  for (int i = tid; i < 256; i += 1024) hist[i] = 0;
  __syncthreads();
  unsigned int top24 = ((unsigned int)t1 << 12) | (unsigned int)t2;
  for (int i = tid; i < NANCH; i += 1024) {
    unsigned int m = mono_of(sc[i]);
    if ((m >> 8) == top24) atomicAdd(&hist[m & 0xFF], 1u);
  }
  __syncthreads();
  {
    unsigned int hb = (tid < 256) ? hist[tid] : 0;
    part[tid] = hb;
    __syncthreads();
    for (int off = 1; off < 1024; off <<= 1) {
      unsigned int v = part[tid];
      unsigned int u = (tid + off < 1024) ? part[tid + off] : 0;
      __syncthreads();
      part[tid] = v + u;
      __syncthreads();
    }
    if (tid < 256) {
      unsigned int c = part[tid + 1];
      const unsigned int need = (unsigned)(NPRE - a1 - a2);
      if (c < need && c + hb >= need) {
        res[4] = tid;
        res[6] = (int)(need - c);                         // ties_needed
        res[7] = (hb == need - c) ? NANCH : -1;           // idx_cut or TBD
      }
    }
  }
  __syncthreads();
  int t3 = res[4];
  unsigned int T = (top24 << 8) | (unsigned int)t3;
  int ties_needed = res[6];
  int idx_cut = res[7];
  __syncthreads();

  // ---------- phase 4 (rare): tie resolution by smallest index ----------
  if (idx_cut < 0) {
    for (int i = tid; i < 704; i += 1024) hist[i] = 0;
    __syncthreads();
    for (int i = tid; i < NANCH; i += 1024)
      if (mono_of(sc[i]) == T) atomicAdd(&hist[i >> 5], 1u);
    __syncthreads();
    if (tid == 0) {
      int c = 0, cut = NANCH;
      for (int bin = 0; bin < 704; ++bin) {
        int hc = (int)hist[bin];
        if (c + hc >= ties_needed) {
          int c2 = c;
          for (int idx = bin * 32; idx < bin * 32 + 32; ++idx) {
            if (idx < NANCH && mono_of(sc[idx]) == T) {
              ++c2;
              if (c2 == ties_needed) { cut = idx; break; }
            }
          }
          break;
        }
        c += hc;
      }
      res[7] = cut;
    }
    __syncthreads();
    idx_cut = res[7];
    __syncthreads();
  }

  // ---------- phase 5: deterministic idx-order compact (blocked ranges + scan) ----------
  int base0 = tid * 22;  // 1024*22 = 22528 >= NANCH
  unsigned int selm = 0;
  int cnt = 0;
  for (int k = 0; k < 22; ++k) {
    int i = base0 + k;
    if (i < NANCH) {
      unsigned int m = mono_of(sc[i]);
      if (m > T || (m == T && i <= idx_cut)) { selm |= 1u << k; ++cnt; }
    }
  }
  {
    int inc = cnt;
#pragma unroll
    for (int d = 1; d < 64; d <<= 1) {
      int u = __shfl_up(inc, d, 64);
      if (lane >= d) inc += u;
    }
    if (lane == 63) part[wv] = (unsigned int)inc;
    __syncthreads();
    if (tid < 16) {
      int v = (int)part[tid];
      int inc2 = v;
#pragma unroll
      for (int d = 1; d < 16; d <<= 1) {
        int u = __shfl_up(inc2, d, 16);
        if (tid >= d) inc2 += u;
      }
      part[tid] = (unsigned int)(inc2 - v);  // exclusive wave base
    }
    __syncthreads();
    int pos = (int)part[wv] + (inc - cnt);
    for (int k = 0; k < 22; ++k)
      if ((selm >> k) & 1u) pidA[pos++] = (unsigned short)(base0 + k);
  }
  __syncthreads();

  // ---------- phase 6: 6-pass 6-bit stable LSD radix, key = ~mono (asc) ----------
  unsigned short* src = pidA;
  unsigned short* dst = pidB;
  for (int pass = 0; pass < 6; ++pass) {
    int shift = pass * 6;
    for (int i = tid; i < 6144; i += 1024) table[i] = 0;
    __syncthreads();
    int dig[6], irk[6], pidr[6];
#pragma unroll
    for (int k = 0; k < 6; ++k) {
      dig[k] = 0; irk[k] = 0; pidr[k] = 0;
      int s = wv + 16 * k;          // wave-uniform
      if (s < NSLOT) {
        int e = s * 64 + lane;
        bool act = e < NPRE;
        int pid = act ? (int)src[e] : 0;
        unsigned int key = act ? ~mono_of(sc[pid]) : 0u;
        int d = (int)((key >> shift) & 63u);
        uint64_t peers = __ballot(act);
#pragma unroll
        for (int bb = 0; bb < 6; ++bb) {
          uint64_t bl = __ballot(((d >> bb) & 1) != 0);
          peers &= ((d >> bb) & 1) ? bl : ~bl;
        }
        if (act) {
          dig[k] = d;
          pidr[k] = pid;
          irk[k] = (int)__popcll(peers & ((1ull << lane) - 1ull));
          int leader = __ffsll((long long)peers) - 1;
          if (lane == leader)
            table[d * NSLOT + s] = (unsigned short)__popcll(peers);
        }
      }
    }
    __syncthreads();
    // exclusive scan over table[0..6143] (digit-major, slot-minor)
    {
      int t6 = tid * 6;
      int v0 = table[t6], v1 = table[t6 + 1], v2 = table[t6 + 2];
      int v3 = table[t6 + 3], v4 = table[t6 + 4], v5 = table[t6 + 5];
      int lsum = v0 + v1 + v2 + v3 + v4 + v5;
      int inc = lsum;
#pragma unroll
      for (int d = 1; d < 64; d <<= 1) {
        int u = __shfl_up(inc, d, 64);
        if (lane >= d) inc += u;
      }
      if (lane == 63) part[wv] = (unsigned int)inc;
      __syncthreads();
      if (tid < 16) {
        int v = (int)part[tid];
        int inc2 = v;
#pragma unroll
        for (int d = 1; d < 16; d <<= 1) {
          int u = __shfl_up(inc2, d, 16);
          if (tid >= d) inc2 += u;
        }
        part[tid] = (unsigned int)(inc2 - v);
      }
      __syncthreads();
      int run = (int)part[wv] + (inc - lsum);
      table[t6] = (unsigned short)run; run += v0;
      table[t6 + 1] = (unsigned short)run; run += v1;
      table[t6 + 2] = (unsigned short)run; run += v2;
      table[t6 + 3] = (unsigned short)run; run += v3;
      table[t6 + 4] = (unsigned short)run; run += v4;
      table[t6 + 5] = (unsigned short)run;
    }
    __syncthreads();
    // scatter (stable): pos = base(digit,slot) + intra-slot rank
#pragma unroll
    for (int k = 0; k < 6; ++k) {
      int s = wv + 16 * k;
      if (s < NSLOT) {
        int e = s * 64 + lane;
        if (e < NPRE) {
          int pos = (int)table[dig[k] * NSLOT + s] + irk[k];
          dst[pos] = (unsigned short)pidr[k];
        }
      }
    }
    __syncthreads();
    unsigned short* tmp = src; src = dst; dst = tmp;
  }
  // 6 passes -> result back in pidA (== src)

  // ---------- phase 7: gather sorted scores/boxes ----------
  for (int r = tid; r < NPRE; r += 1024) {
    int idx = (int)src[r];
    sscore[(size_t)b * NPRE + r] = sc[idx];
    sbox[(size_t)b * NPRE + r] = boxes[(size_t)b * NANCH + idx];
  }
}

// ---------------- IoU suppression bitmask ----------------
__global__ __launch_bounds__(256) void iou_mat(const float4* __restrict__ sbox,
                                               uint64_t* __restrict__ M) {
  __shared__ float4 bi[64];
  __shared__ float4 bj[256];
  int b = blockIdx.z;
  int it = blockIdx.x;  // 94 tiles of 64 i
  int jt = blockIdx.y;  // 24 tiles of 4 words
  int tid = threadIdx.x;
  if (tid < 64) {
    int i = it * 64 + tid;
    bi[tid] = (i < NPRE) ? sbox[(size_t)b * NPRE + i] : make_float4(0, 0, 0, 0);
  }
  {
    int j = jt * 256 + tid;
    bj[tid] = (j < NPRE) ? sbox[(size_t)b * NPRE + j] : make_float4(0, 0, 0, 0);
  }
  __syncthreads();
  int li = tid & 63, wq = tid >> 6;
  int i = it * 64 + li;
  int w = jt * 4 + wq;
  if (i < NPRE && w < NW) {
    float4 A = bi[li];
    float areaA = (A.z - A.x) * (A.w - A.y);
    uint64_t bits = 0;
#pragma unroll 8
    for (int jj = 0; jj < 64; ++jj) {
      int j = w * 64 + jj;
      float4 Bx = bj[wq * 64 + jj];
      float ix1 = fmaxf(A.x, Bx.x), iy1 = fmaxf(A.y, Bx.y);
      float ix2 = fminf(A.z, Bx.z), iy2 = fminf(A.w, Bx.w);
      float inter = fmaxf(ix2 - ix1, 0.f) * fmaxf(iy2 - iy1, 0.f);
      float areaB = (Bx.z - Bx.x) * (Bx.w - Bx.y);
      float iou = inter / (areaA + areaB - inter);
      if ((j > i) && (j < NPRE) && (iou > 0.7f)) bits |= (1ull << jj);
    }
    M[((size_t)b * NPRE + i) * NW + w] = bits;
  }
}

// ---------------- NMS scan: wave0 serial closure + block-parallel OR + early exit ----------------
__device__ inline uint64_t shfl64(uint64_t v, int src) {
  int lo = __shfl((int)(unsigned int)(v & 0xFFFFFFFFull), src, 64);
  int hi = __shfl((int)(unsigned int)(v >> 32), src, 64);
  return ((uint64_t)(unsigned int)hi << 32) | (unsigned int)lo;
}

__global__ __launch_bounds__(1024) void nms_scan(const uint64_t* __restrict__ M,
                                                 const float* __restrict__ sscore,
                                                 uint64_t* __restrict__ keep) {
  __shared__ unsigned int supLo[NW], supHi[NW];
  __shared__ int klist[64];
  __shared__ int knS;
  __shared__ int countS;
  int b = blockIdx.x;
  int tid = threadIdx.x;
  const uint64_t* Mb = M + (size_t)b * NPRE * NW;

  for (int w = tid; w < NW; w += 1024) {
    supLo[w] = 0;
    supHi[w] = 0;
    keep[b * NW + w] = 0;  // early-exit leaves tail chunks zeroed
  }
  if (tid == 0) countS = 0;
  __syncthreads();

  for (int c = 0; c < NW; ++c) {
    int ibase = c * 64;
    if (tid < 64) {
      int lane = tid;
      if (lane == 0) knS = 0;
      uint64_t supc = ((uint64_t)supHi[c] << 32) | supLo[c];
      uint64_t validm = (c == NW - 1) ? ((1ull << (NPRE - (NW - 1) * 64)) - 1ull) : ~0ull;
      int pos = ibase + lane;
      uint64_t myrow = (pos < NPRE) ? Mb[(size_t)pos * NW + c] : 0ull;
      bool sval = (pos < NPRE) && (sscore[(size_t)b * NPRE + pos] >= 0.f);
      uint64_t vb = __ballot(sval);
      uint64_t cur = validm & ~supc;
      uint64_t kept = 0;
      while (cur) {
        int i = __ffsll((long long)cur) - 1;
        kept |= (1ull << i);
        cur &= ~(1ull << i);
        uint64_t row = shfl64(myrow, i);
        cur &= ~row;
      }
      if (kept & (1ull << lane)) {
        int pp = atomicAdd(&knS, 1);
        klist[pp] = lane;
      }
      if (lane == 0) {
        keep[b * NW + c] = kept;
        countS += __popcll(kept & vb);
      }
    }
    __syncthreads();  // [A] klist/knS/count visible; sup[c] consumed
    int kn = knS;
    for (int t = tid; t < kn * 128; t += 1024) {
      int ii = t >> 7, w = t & 127;
      if (w > c && w < NW) {
        uint64_t row = Mb[(size_t)(ibase + klist[ii]) * NW + w];
        unsigned int lo = (unsigned int)row;
        unsigned int hi = (unsigned int)(row >> 32);
        if (lo) atomicOr(&supLo[w], lo);
        if (hi) atomicOr(&supHi[w], hi);
      }
    }
    __syncthreads();  // [B] sup updated before next chunk's closure
    if (countS >= 300) break;  // first 300 kept(valid) found; rest irrelevant
  }
}

// ---------------- emit top-300 ----------------
__global__ __launch_bounds__(128) void emit(const uint64_t* __restrict__ keep,
                                            const float* __restrict__ sscore,
                                            const float4* __restrict__ sbox,
                                            float* __restrict__ out) {
  __shared__ int cnt[128];
  __shared__ uint64_t fw[NW];
  int b = blockIdx.x;
  int tid = threadIdx.x;
  for (int i = tid; i < 1200; i += 128) out[b * 1200 + i] = 0.f;
  for (int i = tid; i < 300; i += 128) {
    out[2400 + b * 300 + i] = 0.f;
    out[3000 + b * 300 + i] = 0.f;
  }
  uint64_t w = 0;
  if (tid < NW) {
    uint64_t kw = keep[b * NW + tid];
    while (kw) {
      int j = __ffsll((long long)kw) - 1;
      kw &= kw - 1;
      if (sscore[(size_t)b * NPRE + tid * 64 + j] >= 0.f) w |= (1ull << j);
    }
    fw[tid] = w;
  }
  cnt[tid] = (tid < NW) ? __popcll(w) : 0;
  __syncthreads();
  for (int off = 1; off < 128; off <<= 1) {
    int v = cnt[tid];
    int u = (tid >= off) ? cnt[tid - off] : 0;
    __syncthreads();
    cnt[tid] = v + u;
    __syncthreads();
  }
  if (tid < NW) {
    int base = cnt[tid] - __popcll(fw[tid]);
    uint64_t ww = fw[tid];
    while (ww) {
      int j = __ffsll((long long)ww) - 1;
      ww &= ww - 1;
      if (base < 300) {
        int p = tid * 64 + j;
        float4 bx = sbox[(size_t)b * NPRE + p];
        float* ob = out + b * 1200 + base * 4;
        ob[0] = bx.x; ob[1] = bx.y; ob[2] = bx.z; ob[3] = bx.w;
        out[2400 + b * 300 + base] = sscore[(size_t)b * NPRE + p];
        out[3000 + b * 300 + base] = 1.0f;
      }
      ++base;
    }
  }
}

// ---------------- launch ----------------
extern "C" void kernel_launch(void* const* d_in, const int* in_sizes, int n_in,
                              void* d_out, int out_size, void* d_ws, size_t ws_size,
                              hipStream_t stream) {
  const float* x       = (const float*)d_in[0];
  const float* conv1_w = (const float*)d_in[1];
  const float* conv1_b = (const float*)d_in[2];
  const float* obj_w   = (const float*)d_in[3];
  const float* obj_b   = (const float*)d_in[4];
  const float* loc_w   = (const float*)d_in[5];
  const float* loc_b   = (const float*)d_in[6];
  const float* anch    = (const float*)d_in[7];
  const int*   img_h   = (const int*)d_in[8];
  const int*   img_w   = (const int*)d_in[9];

  char* base = (char*)d_ws;
  float*    wt     = (float*)(base + 0);            // 2304*512*4 = 4,718,592
  float*    h      = (float*)(base + 4718592);      // 2*2500*512*4 = 10,240,000
  uint64_t* M      = (uint64_t*)(base + 4718592);   // alias h (9,024,000 <= 10,240,000)
  float*    scores = (float*)(base + 14958592);     // 180,000
  float4*   boxes  = (float4*)(base + 15138592);    // 720,000
  float*    sscore = (float*)(base + 15858592);     // 48,000
  float4*   sbox   = (float4*)(base + 15906592);    // 192,000
  uint64_t* keep   = (uint64_t*)(base + 16098592);  // 1,504
  float*    xp     = (float*)(base + 16100096);     // 2*256*2704*4 = 5,537,792 -> 21.6MB total

  hipLaunchKernelGGL(pad_x, dim3((2 * 256 * XPAD + 255) / 256), dim3(256), 0, stream, x, xp);
  hipLaunchKernelGGL(transpose_w, dim3(72, 16), dim3(256), 0, stream, conv1_w, wt);
  hipLaunchKernelGGL(conv1_gemm, dim3(40, 8, 2), dim3(128), 0, stream, xp, wt, conv1_b, h);
  hipLaunchKernelGGL(heads, dim3(5000), dim3(64), 0, stream, h, obj_w, obj_b, loc_w, loc_b,
                     anch, img_h, img_w, scores, boxes);
  hipLaunchKernelGGL(topk_sort, dim3(2), dim3(1024), 0, stream, scores, boxes, sscore, sbox);
  hipLaunchKernelGGL(iou_mat, dim3(NW, 24, 2), dim3(256), 0, stream, sbox, M);
  hipLaunchKernelGGL(nms_scan, dim3(2), dim3(1024), 0, stream, M, sscore, keep);
  hipLaunchKernelGGL(emit, dim3(2), dim3(128), 0, stream, keep, sscore, sbox, (float*)d_out);
}

// Round 11
// 500.803 us; speedup vs baseline: 1.1307x; 1.1307x over previous
//
#include <hip/hip_runtime.h>
#include <stdint.h>

// ---------------- constants ----------------
#define NPOS 2500      // 50*50
#define NANCH 22500    // NPOS*9
#define NPRE 6000
#define NW 94          // ceil(6000/64)
#define XPAD 2704      // 52*52 padded plane
#define NSLOT 94       // ceil(NPRE/64) radix slots
#define CMAX 32        // restricted NMS chunk budget (2048 candidates)

// async global->LDS DMA (gfx950). dst is wave-uniform base + lane*size.
__device__ __forceinline__ void gl_lds4(const float* g, float* l) {
  __builtin_amdgcn_global_load_lds((const __attribute__((address_space(1))) void*)g,
                                   (__attribute__((address_space(3))) void*)l, 4, 0, 0);
}
__device__ __forceinline__ void gl_lds16(const float* g, float* l) {
  __builtin_amdgcn_global_load_lds((const __attribute__((address_space(1))) void*)g,
                                   (__attribute__((address_space(3))) void*)l, 16, 0, 0);
}

// ---------------- zero-pad x: [b][ic][50][50] -> [b][ic][52][52] ----------------
__global__ __launch_bounds__(256) void pad_x(const float* __restrict__ x,
                                             float* __restrict__ xp) {
  int t = blockIdx.x * 256 + threadIdx.x;
  if (t >= 2 * 256 * XPAD) return;
  int c = t / XPAD;        // b*256 + ic
  int r = t % XPAD;
  int yy = r / 52, xx = r % 52;
  float v = 0.f;
  if (yy >= 1 && yy <= 50 && xx >= 1 && xx <= 50)
    v = x[(size_t)c * NPOS + (yy - 1) * 50 + (xx - 1)];
  xp[t] = v;
}

// ---------------- weight transpose: w[oc][ic][3][3] -> wt[(tap*256+ic)][oc] ----------------
__global__ __launch_bounds__(256) void transpose_w(const float* __restrict__ w,
                                                   float* __restrict__ wt) {
  __shared__ float tile[32][33];
  int k0 = blockIdx.x * 32;   // k' = ic*9 + tap, 0..2303
  int o0 = blockIdx.y * 32;
  int tx = threadIdx.x & 31;
  int ty = threadIdx.x >> 5;  // 0..7
#pragma unroll
  for (int i = 0; i < 4; ++i) {
    int oc = o0 + ty + i * 8;
    int kp = k0 + tx;
    tile[ty + i * 8][tx] = w[(size_t)oc * 2304 + kp];
  }
  __syncthreads();
#pragma unroll
  for (int i = 0; i < 4; ++i) {
    int kp = k0 + ty + i * 8;
    int ic = kp / 9, tap = kp % 9;
    wt[((size_t)tap * 256 + ic) * 512 + (o0 + tx)] = tile[tx][ty + i * 8];
  }
}

// ---------------- conv1 3x3 SAME + bias + relu, output NHWC h[b][p][oc] ----------------
// EXACT R7 version (203us measured, best of R2..R10). 64x64 tile, 256 threads,
// single-buffer LDS, DMA staging. Conv verdict: LDS-read-instruction bound
// (~46K b128/CU x 8-12cyc); dbuf (R8/R9 +24us), fat tiles (R10, occupancy
// collapse), reg prefetch (R3, VGPR cliff), small tiles (R4, 2x staging) all lose.
__global__ __launch_bounds__(256) void conv1_gemm(const float* __restrict__ xp,
                                                  const float* __restrict__ wt,
                                                  const float* __restrict__ bias,
                                                  float* __restrict__ h) {
  __shared__ __align__(16) float As[32][64];
  __shared__ __align__(16) float Bs[32][64];
  int b = blockIdx.z;
  int m0 = blockIdx.x * 64;
  int oc0 = blockIdx.y * 64;
  int tid = threadIdx.x;
  int lane = tid & 63;
  int wv = tid >> 6;       // wave 0..3
  int tn = tid & 15, tm = tid >> 4;
  float acc[4][4] = {};

  int p = m0 + lane;
  int pc = p < NPOS ? p : (NPOS - 1);
  int py = pc / 50, px = pc % 50;
  const float* gA0 = xp + (size_t)b * 256 * XPAD + py * 52 + px + 53;
  int brow = lane >> 4, bcol4 = (lane & 15) * 4;

  for (int tap = 0; tap < 9; ++tap) {
    int ky = tap / 3 - 1, kx = tap % 3 - 1;
    int koff = ky * 52 + kx;
    for (int icc = 0; icc < 8; ++icc) {
      int ic0 = icc * 32;
      __syncthreads();  // LDS consumed by previous chunk's compute
#pragma unroll
      for (int j = 0; j < 8; ++j) {
        int kk = wv * 8 + j;
        gl_lds4(gA0 + (size_t)(ic0 + kk) * XPAD + koff, &As[kk][0]);
      }
#pragma unroll
      for (int q = 0; q < 2; ++q) {
        int r0 = wv * 8 + q * 4;
        gl_lds16(wt + ((size_t)tap * 256 + ic0 + r0 + brow) * 512 + oc0 + bcol4,
                 &Bs[r0][0]);
      }
      __syncthreads();  // drains vmcnt -> DMAs complete
#pragma unroll
      for (int kk = 0; kk < 32; ++kk) {
        float4 av = *(const float4*)&As[kk][tm * 4];
        float4 bv = *(const float4*)&Bs[kk][tn * 4];
        float am[4] = {av.x, av.y, av.z, av.w};
        float bn[4] = {bv.x, bv.y, bv.z, bv.w};
#pragma unroll
        for (int i = 0; i < 4; ++i)
#pragma unroll
          for (int j = 0; j < 4; ++j) acc[i][j] = fmaf(am[i], bn[j], acc[i][j]);
      }
    }
  }
#pragma unroll
  for (int i = 0; i < 4; ++i) {
    int pp = m0 + tm * 4 + i;
    if (pp < NPOS) {
      float4 v;
      float* vp = (float*)&v;
#pragma unroll
      for (int j = 0; j < 4; ++j) {
        int oc = oc0 + tn * 4 + j;
        vp[j] = fmaxf(acc[i][j] + bias[oc], 0.f);
      }
      *(float4*)&h[((size_t)b * NPOS + pp) * 512 + oc0 + tn * 4] = v;
    }
  }
}

// ---------------- heads: 1x1 convs + softmax + decode + valid ----------------
__global__ __launch_bounds__(64) void heads(const float* __restrict__ h,
                                            const float* __restrict__ objw,
                                            const float* __restrict__ objb,
                                            const float* __restrict__ locw,
                                            const float* __restrict__ locb,
                                            const float* __restrict__ anch,
                                            const int* __restrict__ imgh,
                                            const int* __restrict__ imgw,
                                            float* __restrict__ scores,
                                            float4* __restrict__ boxes) {
  __shared__ float hv[512];
  __shared__ float outs[64];
  int blk = blockIdx.x;
  int b = blk / NPOS, p = blk % NPOS;
  int lane = threadIdx.x;
  const float4* hp4 = (const float4*)(h + ((size_t)b * NPOS + p) * 512);
  float4* hv4 = (float4*)hv;
  hv4[lane] = hp4[lane];
  hv4[lane + 64] = hp4[lane + 64];
  __syncthreads();
  if (lane < 54) {
    const float* wrow;
    float acc;
    if (lane < 18) { wrow = objw + (size_t)lane * 512; acc = objb[lane]; }
    else           { wrow = locw + (size_t)(lane - 18) * 512; acc = locb[lane - 18]; }
    const float4* w4 = (const float4*)wrow;
#pragma unroll 4
    for (int k = 0; k < 128; ++k) {
      float4 wv = w4[k], hh = hv4[k];
      acc = fmaf(wv.x, hh.x, acc);
      acc = fmaf(wv.y, hh.y, acc);
      acc = fmaf(wv.z, hh.z, acc);
      acc = fmaf(wv.w, hh.w, acc);
    }
    outs[lane] = acc;
  }
  __syncthreads();
  if (lane < 9) {
    float l0 = outs[2 * lane], l1 = outs[2 * lane + 1];
    float mx = fmaxf(l0, l1);
    float e0 = expf(l0 - mx);
    float e1 = expf(l1 - mx);
    float s = e1 / (e0 + e1);
    float d0 = outs[18 + 4 * lane + 0];
    float d1 = outs[18 + 4 * lane + 1];
    float d2 = outs[18 + 4 * lane + 2];
    float d3 = outs[18 + 4 * lane + 3];
    int ai = p * 9 + lane;
    float4 A = ((const float4*)anch)[ai];
    float aw = A.z - A.x, ah = A.w - A.y;
    float acx = A.x + 0.5f * aw, acy = A.y + 0.5f * ah;
    float cx = acx + d0 * aw, cy = acy + d1 * ah;
    float w = aw * expf(d2), hh = ah * expf(d3);
    float W = (float)imgw[0], H = (float)imgh[0];
    float x1 = fminf(fmaxf(cx - 0.5f * w, 0.f), W);
    float y1 = fminf(fmaxf(cy - 0.5f * hh, 0.f), H);
    float x2 = fminf(fmaxf(cx + 0.5f * w, 0.f), W);
    float y2 = fminf(fmaxf(cy + 0.5f * hh, 0.f), H);
    bool valid = (x2 - x1 >= 16.f) && (y2 - y1 >= 16.f);
    scores[(size_t)b * NANCH + ai] = valid ? s : -1.f;
    boxes[(size_t)b * NANCH + ai] = make_float4(x1, y1, x2, y2);
  }
}

// ---------------- top-6000 select + stable radix sort (one block per batch) ----------------
__device__ inline unsigned int mono_of(float f) {
  unsigned int u = __float_as_uint(f);
  return (u & 0x80000000u) ? ~u : (u | 0x80000000u);
}

// R6 lesson: wave-aggregated hist_add REGRESSED (+67us). Plain atomics kept.
// R7: 6-pass 6-bit stable LSD radix replaced the bitonic (268 -> ~84us).
__global__ __launch_bounds__(1024) void topk_sort(const float* __restrict__ scores,
                                                  const float4* __restrict__ boxes,
                                                  float* __restrict__ sscore,
                                                  float4* __restrict__ sbox) {
  int b = blockIdx.x;
  const float* sc = scores + (size_t)b * NANCH;
  __shared__ unsigned int hist[4096];
  __shared__ unsigned int part[1024];
  __shared__ unsigned short pidA[6016];
  __shared__ unsigned short pidB[6016];
  __shared__ unsigned short table[6144];   // 64 digits x 94 slots (padded)
  __shared__ int res[8];
  int tid = threadIdx.x;
  int lane = tid & 63;
  int wv = tid >> 6;

  // ---------- phase 1: top-12-bit histogram ----------
  for (int i = tid; i < 4096; i += 1024) hist[i] = 0;
  __syncthreads();
  for (int i = tid; i < NANCH; i += 1024) atomicAdd(&hist[mono_of(sc[i]) >> 20], 1u);
  __syncthreads();
  {
    unsigned int h0 = hist[4 * tid], h1 = hist[4 * tid + 1];
    unsigned int h2 = hist[4 * tid + 2], h3 = hist[4 * tid + 3];
    part[tid] = h0 + h1 + h2 + h3;
    __syncthreads();
    for (int off = 1; off < 1024; off <<= 1) {
      unsigned int v = part[tid];
      unsigned int u = (tid + off < 1024) ? part[tid + off] : 0;
      __syncthreads();
      part[tid] = v + u;
      __syncthreads();
    }
    unsigned int c = (tid < 1023) ? part[tid + 1] : 0;  // strict suffix over groups
    const int need = NPRE;
    if (c < (unsigned)need && c + h3 >= (unsigned)need) { res[0] = 4 * tid + 3; res[1] = (int)c; }
    c += h3;
    if (c < (unsigned)need && c + h2 >= (unsigned)need) { res[0] = 4 * tid + 2; res[1] = (int)c; }
    c += h2;
    if (c < (unsigned)need && c + h1 >= (unsigned)need) { res[0] = 4 * tid + 1; res[1] = (int)c; }
    c += h1;
    if (c < (unsigned)need && c + h0 >= (unsigned)need) { res[0] = 4 * tid + 0; res[1] = (int)c; }
  }
  __syncthreads();
  int t1 = res[0], a1 = res[1];
  __syncthreads();

  // ---------- phase 2: middle-12 bits within bin t1 ----------
  for (int i = tid; i < 4096; i += 1024) hist[i] = 0;
  __syncthreads();
  for (int i = tid; i < NANCH; i += 1024) {
    unsigned int m = mono_of(sc[i]);
    if ((int)(m >> 20) == t1) atomicAdd(&hist[(m >> 8) & 0xFFF], 1u);
  }
  __syncthreads();
  {
    unsigned int h0 = hist[4 * tid], h1 = hist[4 * tid + 1];
    unsigned int h2 = hist[4 * tid + 2], h3 = hist[4 * tid + 3];
    part[tid] = h0 + h1 + h2 + h3;
    __syncthreads();
    for (int off = 1; off < 1024; off <<= 1) {
      unsigned int v = part[tid];
      unsigned int u = (tid + off < 1024) ? part[tid + off] : 0;
      __syncthreads();
      part[tid] = v + u;
      __syncthreads();
    }
    unsigned int c = (tid < 1023) ? part[tid + 1] : 0;
    const unsigned int need = (unsigned)(NPRE - a1);
    if (c < need && c + h3 >= need) { res[2] = 4 * tid + 3; res[3] = (int)c; }
    c += h3;
    if (c < need && c + h2 >= need) { res[2] = 4 * tid + 2; res[3] = (int)c; }
    c += h2;
    if (c < need && c + h1 >= need) { res[2] = 4 * tid + 1; res[3] = (int)c; }
    c += h1;
    if (c < need && c + h0 >= need) { res[2] = 4 * tid + 0; res[3] = (int)c; }
  }
  __syncthreads();
  int t2 = res[2], a2 = res[3];
  __syncthreads();

  // ---------- phase 3: low-8 bits within (t1,t2) ----------
  for (int i = tid; i < 256; i += 1024) hist[i] = 0;
  __syncthreads();
  unsigned int top24 = ((unsigned int)t1 << 12) | (unsigned int)t2;
  for (int i = tid; i < NANCH; i += 1024) {
    unsigned int m = mono_of(sc[i]);
    if ((m >> 8) == top24) atomicAdd(&hist[m & 0xFF], 1u);
  }
  __syncthreads();
  {
    unsigned int hb = (tid < 256) ? hist[tid] : 0;
    part[tid] = hb;
    __syncthreads();
    for (int off = 1; off < 1024; off <<= 1) {
      unsigned int v = part[tid];
      unsigned int u = (tid + off < 1024) ? part[tid + off] : 0;
      __syncthreads();
      part[tid] = v + u;
      __syncthreads();
    }
    if (tid < 256) {
      unsigned int c = part[tid + 1];
      const unsigned int need = (unsigned)(NPRE - a1 - a2);
      if (c < need && c + hb >= need) {
        res[4] = tid;
        res[6] = (int)(need - c);                         // ties_needed
        res[7] = (hb == need - c) ? NANCH : -1;           // idx_cut or TBD
      }
    }
  }
  __syncthreads();
  int t3 = res[4];
  unsigned int T = (top24 << 8) | (unsigned int)t3;
  int ties_needed = res[6];
  int idx_cut = res[7];
  __syncthreads();

  // ---------- phase 4 (rare): tie resolution by smallest index ----------
  if (idx_cut < 0) {
    for (int i = tid; i < 704; i += 1024) hist[i] = 0;
    __syncthreads();
    for (int i = tid; i < NANCH; i += 1024)
      if (mono_of(sc[i]) == T) atomicAdd(&hist[i >> 5], 1u);
    __syncthreads();
    if (tid == 0) {
      int c = 0, cut = NANCH;
      for (int bin = 0; bin < 704; ++bin) {
        int hc = (int)hist[bin];
        if (c + hc >= ties_needed) {
          int c2 = c;
          for (int idx = bin * 32; idx < bin * 32 + 32; ++idx) {
            if (idx < NANCH && mono_of(sc[idx]) == T) {
              ++c2;
              if (c2 == ties_needed) { cut = idx; break; }
            }
          }
          break;
        }
        c += hc;
      }
      res[7] = cut;
    }
    __syncthreads();
    idx_cut = res[7];
    __syncthreads();
  }

  // ---------- phase 5: deterministic idx-order compact (blocked ranges + scan) ----------
  int base0 = tid * 22;  // 1024*22 = 22528 >= NANCH
  unsigned int selm = 0;
  int cnt = 0;
  for (int k = 0; k < 22; ++k) {
    int i = base0 + k;
    if (i < NANCH) {
      unsigned int m = mono_of(sc[i]);
      if (m > T || (m == T && i <= idx_cut)) { selm |= 1u << k; ++cnt; }
    }
  }
  {
    int inc = cnt;
#pragma unroll
    for (int d = 1; d < 64; d <<= 1) {
      int u = __shfl_up(inc, d, 64);
      if (lane >= d) inc += u;
    }
    if (lane == 63) part[wv] = (unsigned int)inc;
    __syncthreads();
    if (tid < 16) {
      int v = (int)part[tid];
      int inc2 = v;
#pragma unroll
      for (int d = 1; d < 16; d <<= 1) {
        int u = __shfl_up(inc2, d, 16);
        if (tid >= d) inc2 += u;
      }
      part[tid] = (unsigned int)(inc2 - v);  // exclusive wave base
    }
    __syncthreads();
    int pos = (int)part[wv] + (inc - cnt);
    for (int k = 0; k < 22; ++k)
      if ((selm >> k) & 1u) pidA[pos++] = (unsigned short)(base0 + k);
  }
  __syncthreads();

  // ---------- phase 6: 6-pass 6-bit stable LSD radix, key = ~mono (asc) ----------
  unsigned short* src = pidA;
  unsigned short* dst = pidB;
  for (int pass = 0; pass < 6; ++pass) {
    int shift = pass * 6;
    for (int i = tid; i < 6144; i += 1024) table[i] = 0;
    __syncthreads();
    int dig[6], irk[6], pidr[6];
#pragma unroll
    for (int k = 0; k < 6; ++k) {
      dig[k] = 0; irk[k] = 0; pidr[k] = 0;
      int s = wv + 16 * k;          // wave-uniform
      if (s < NSLOT) {
        int e = s * 64 + lane;
        bool act = e < NPRE;
        int pid = act ? (int)src[e] : 0;
        unsigned int key = act ? ~mono_of(sc[pid]) : 0u;
        int d = (int)((key >> shift) & 63u);
        uint64_t peers = __ballot(act);
#pragma unroll
        for (int bb = 0; bb < 6; ++bb) {
          uint64_t bl = __ballot(((d >> bb) & 1) != 0);
          peers &= ((d >> bb) & 1) ? bl : ~bl;
        }
        if (act) {
          dig[k] = d;
          pidr[k] = pid;
          irk[k] = (int)__popcll(peers & ((1ull << lane) - 1ull));
          int leader = __ffsll((long long)peers) - 1;
          if (lane == leader)
            table[d * NSLOT + s] = (unsigned short)__popcll(peers);
        }
      }
    }
    __syncthreads();
    // exclusive scan over table[0..6143] (digit-major, slot-minor)
    {
      int t6 = tid * 6;
      int v0 = table[t6], v1 = table[t6 + 1], v2 = table[t6 + 2];
      int v3 = table[t6 + 3], v4 = table[t6 + 4], v5 = table[t6 + 5];
      int lsum = v0 + v1 + v2 + v3 + v4 + v5;
      int inc = lsum;
#pragma unroll
      for (int d = 1; d < 64; d <<= 1) {
        int u = __shfl_up(inc, d, 64);
        if (lane >= d) inc += u;
      }
      if (lane == 63) part[wv] = (unsigned int)inc;
      __syncthreads();
      if (tid < 16) {
        int v = (int)part[tid];
        int inc2 = v;
#pragma unroll
        for (int d = 1; d < 16; d <<= 1) {
          int u = __shfl_up(inc2, d, 16);
          if (tid >= d) inc2 += u;
        }
        part[tid] = (unsigned int)(inc2 - v);
      }
      __syncthreads();
      int run = (int)part[wv] + (inc - lsum);
      table[t6] = (unsigned short)run; run += v0;
      table[t6 + 1] = (unsigned short)run; run += v1;
      table[t6 + 2] = (unsigned short)run; run += v2;
      table[t6 + 3] = (unsigned short)run; run += v3;
      table[t6 + 4] = (unsigned short)run; run += v4;
      table[t6 + 5] = (unsigned short)run;
    }
    __syncthreads();
    // scatter (stable): pos = base(digit,slot) + intra-slot rank
#pragma unroll
    for (int k = 0; k < 6; ++k) {
      int s = wv + 16 * k;
      if (s < NSLOT) {
        int e = s * 64 + lane;
        if (e < NPRE) {
          int pos = (int)table[dig[k] * NSLOT + s] + irk[k];
          dst[pos] = (unsigned short)pidr[k];
        }
      }
    }
    __syncthreads();
    unsigned short* tmp = src; src = dst; dst = tmp;
  }
  // 6 passes -> result back in pidA (== src)

  // ---------- phase 7: gather sorted scores/boxes ----------
  for (int r = tid; r < NPRE; r += 1024) {
    int idx = (int)src[r];
    sscore[(size_t)b * NPRE + r] = sc[idx];
    sbox[(size_t)b * NPRE + r] = boxes[(size_t)b * NANCH + idx];
  }
}

// ---------------- IoU suppression bitmask (shared body) ----------------
__device__ __forceinline__ void iou_tile(const float4* __restrict__ sbox,
                                         uint64_t* __restrict__ M,
                                         int b, int it, int jt, int tid,
                                         float4* bi, float4* bj) {
  if (tid < 64) {
    int i = it * 64 + tid;
    bi[tid] = (i < NPRE) ? sbox[(size_t)b * NPRE + i] : make_float4(0, 0, 0, 0);
  }
  {
    int j = jt * 256 + tid;
    bj[tid] = (j < NPRE) ? sbox[(size_t)b * NPRE + j] : make_float4(0, 0, 0, 0);
  }
  __syncthreads();
  int li = tid & 63, wq = tid >> 6;
  int i = it * 64 + li;
  int w = jt * 4 + wq;
  if (i < NPRE && w < NW) {
    float4 A = bi[li];
    float areaA = (A.z - A.x) * (A.w - A.y);
    uint64_t bits = 0;
#pragma unroll 8
    for (int jj = 0; jj < 64; ++jj) {
      int j = w * 64 + jj;
      float4 Bx = bj[wq * 64 + jj];
      float ix1 = fmaxf(A.x, Bx.x), iy1 = fmaxf(A.y, Bx.y);
      float ix2 = fminf(A.z, Bx.z), iy2 = fminf(A.w, Bx.w);
      float inter = fmaxf(ix2 - ix1, 0.f) * fmaxf(iy2 - iy1, 0.f);
      float areaB = (Bx.z - Bx.x) * (Bx.w - Bx.y);
      float iou = inter / (areaA + areaB - inter);
      if ((j > i) && (j < NPRE) && (iou > 0.7f)) bits |= (1ull << jj);
    }
    M[((size_t)b * NPRE + i) * NW + w] = bits;
  }
}

// restricted: rows < CMAX*64 only (full 94-word width -> sup state stays complete)
__global__ __launch_bounds__(256) void iou_mat(const float4* __restrict__ sbox,
                                               uint64_t* __restrict__ M) {
  __shared__ float4 bi[64];
  __shared__ float4 bj[256];
  iou_tile(sbox, M, blockIdx.z, blockIdx.x, blockIdx.y, threadIdx.x, bi, bj);
}

// fallback: rows >= CMAX*64; no-op when NMS finished within CMAX chunks
__global__ __launch_bounds__(256) void iou_rest(const float4* __restrict__ sbox,
                                                uint64_t* __restrict__ M,
                                                const unsigned int* __restrict__ state) {
  if (state[blockIdx.z * 192 + 189]) return;  // done
  __shared__ float4 bi[64];
  __shared__ float4 bj[256];
  iou_tile(sbox, M, blockIdx.z, blockIdx.x + CMAX, blockIdx.y, threadIdx.x, bi, bj);
}

// ---------------- NMS scan: wave0 serial closure + block-parallel OR + early exit ----------------
__device__ inline uint64_t shfl64(uint64_t v, int src) {
  int lo = __shfl((int)(unsigned int)(v & 0xFFFFFFFFull), src, 64);
  int hi = __shfl((int)(unsigned int)(v >> 32), src, 64);
  return ((uint64_t)(unsigned int)hi << 32) | (unsigned int)lo;
}

// one NMS chunk step; returns updated countS validity via shared countS
__device__ __forceinline__ void nms_chunk(const uint64_t* __restrict__ Mb,
                                          const float* __restrict__ sscore,
                                          uint64_t* __restrict__ keep,
                                          int b, int c, int tid,
                                          unsigned int* supLo, unsigned int* supHi,
                                          int* klist, int* knS, int* countS) {
  int ibase = c * 64;
  if (tid < 64) {
    int lane = tid;
    if (lane == 0) *knS = 0;
    uint64_t supc = ((uint64_t)supHi[c] << 32) | supLo[c];
    uint64_t validm = (c == NW - 1) ? ((1ull << (NPRE - (NW - 1) * 64)) - 1ull) : ~0ull;
    int pos = ibase + lane;
    uint64_t myrow = (pos < NPRE) ? Mb[(size_t)pos * NW + c] : 0ull;
    bool sval = (pos < NPRE) && (sscore[(size_t)b * NPRE + pos] >= 0.f);
    uint64_t vb = __ballot(sval);
    uint64_t cur = validm & ~supc;
    uint64_t kept = 0;
    while (cur) {
      int i = __ffsll((long long)cur) - 1;
      kept |= (1ull << i);
      cur &= ~(1ull << i);
      uint64_t row = shfl64(myrow, i);
      cur &= ~row;
    }
    if (kept & (1ull << lane)) {
      int pp = atomicAdd(knS, 1);
      klist[pp] = lane;
    }
    if (lane == 0) {
      keep[b * NW + c] = kept;
      *countS += __popcll(kept & vb);
    }
  }
  __syncthreads();  // [A] klist/knS/count visible; sup[c] consumed
  int kn = *knS;
  for (int t = tid; t < kn * 128; t += 1024) {
    int ii = t >> 7, w = t & 127;
    if (w > c && w < NW) {
      uint64_t row = Mb[(size_t)(ibase + klist[ii]) * NW + w];
      unsigned int lo = (unsigned int)row;
      unsigned int hi = (unsigned int)(row >> 32);
      if (lo) atomicOr(&supLo[w], lo);
      if (hi) atomicOr(&supHi[w], hi);
    }
  }
  __syncthreads();  // [B] sup updated before next chunk's closure
}

// phase A: chunks 0..CMAX; persists (sup, count, done) for the gated fallback
__global__ __launch_bounds__(1024) void nms_scan(const uint64_t* __restrict__ M,
                                                 const float* __restrict__ sscore,
                                                 uint64_t* __restrict__ keep,
                                                 unsigned int* __restrict__ state) {
  __shared__ unsigned int supLo[NW], supHi[NW];
  __shared__ int klist[64];
  __shared__ int knS;
  __shared__ int countS;
  int b = blockIdx.x;
  int tid = threadIdx.x;
  const uint64_t* Mb = M + (size_t)b * NPRE * NW;

  for (int w = tid; w < NW; w += 1024) {
    supLo[w] = 0;
    supHi[w] = 0;
    keep[b * NW + w] = 0;  // early-exit / fallback leaves untouched chunks zeroed
  }
  if (tid == 0) countS = 0;
  __syncthreads();

  int done = 0;
  for (int c = 0; c < CMAX; ++c) {
    nms_chunk(Mb, sscore, keep, b, c, tid, supLo, supHi, klist, &knS, &countS);
    if (countS >= 300) { done = 1; break; }  // uniform: countS read post-barrier
  }
  __syncthreads();
  unsigned int* st = state + b * 192;
  for (int w = tid; w < NW; w += 1024) { st[w] = supLo[w]; st[94 + w] = supHi[w]; }
  if (tid == 0) { st[188] = (unsigned int)countS; st[189] = (unsigned int)done; }
}

// fallback: continues from chunk CMAX with complete sup state; no-op when done
__global__ __launch_bounds__(1024) void nms_rest(const uint64_t* __restrict__ M,
                                                 const float* __restrict__ sscore,
                                                 uint64_t* __restrict__ keep,
                                                 const unsigned int* __restrict__ state) {
  int b = blockIdx.x;
  const unsigned int* st = state + b * 192;
  if (st[189]) return;  // done — uniform
  __shared__ unsigned int supLo[NW], supHi[NW];
  __shared__ int klist[64];
  __shared__ int knS;
  __shared__ int countS;
  int tid = threadIdx.x;
  const uint64_t* Mb = M + (size_t)b * NPRE * NW;
  for (int w = tid; w < NW; w += 1024) { supLo[w] = st[w]; supHi[w] = st[94 + w]; }
  if (tid == 0) countS = (int)st[188];
  __syncthreads();
  for (int c = CMAX; c < NW; ++c) {
    nms_chunk(Mb, sscore, keep, b, c, tid, supLo, supHi, klist, &knS, &countS);
    if (countS >= 300) break;
  }
}

// ---------------- emit top-300 ----------------
__global__ __launch_bounds__(128) void emit(const uint64_t* __restrict__ keep,
                                            const float* __restrict__ sscore,
                                            const float4* __restrict__ sbox,
                                            float* __restrict__ out) {
  __shared__ int cnt[128];
  __shared__ uint64_t fw[NW];
  int b = blockIdx.x;
  int tid = threadIdx.x;
  for (int i = tid; i < 1200; i += 128) out[b * 1200 + i] = 0.f;
  for (int i = tid; i < 300; i += 128) {
    out[2400 + b * 300 + i] = 0.f;
    out[3000 + b * 300 + i] = 0.f;
  }
  uint64_t w = 0;
  if (tid < NW) {
    uint64_t kw = keep[b * NW + tid];
    while (kw) {
      int j = __ffsll((long long)kw) - 1;
      kw &= kw - 1;
      if (sscore[(size_t)b * NPRE + tid * 64 + j] >= 0.f) w |= (1ull << j);
    }
    fw[tid] = w;
  }
  cnt[tid] = (tid < NW) ? __popcll(w) : 0;
  __syncthreads();
  for (int off = 1; off < 128; off <<= 1) {
    int v = cnt[tid];
    int u = (tid >= off) ? cnt[tid - off] : 0;
    __syncthreads();
    cnt[tid] = v + u;
    __syncthreads();
  }
  if (tid < NW) {
    int base = cnt[tid] - __popcll(fw[tid]);
    uint64_t ww = fw[tid];
    while (ww) {
      int j = __ffsll((long long)ww) - 1;
      ww &= ww - 1;
      if (base < 300) {
        int p = tid * 64 + j;
        float4 bx = sbox[(size_t)b * NPRE + p];
        float* ob = out + b * 1200 + base * 4;
        ob[0] = bx.x; ob[1] = bx.y; ob[2] = bx.z; ob[3] = bx.w;
        out[2400 + b * 300 + base] = sscore[(size_t)b * NPRE + p];
        out[3000 + b * 300 + base] = 1.0f;
      }
      ++base;
    }
  }
}

// ---------------- launch ----------------
extern "C" void kernel_launch(void* const* d_in, const int* in_sizes, int n_in,
                              void* d_out, int out_size, void* d_ws, size_t ws_size,
                              hipStream_t stream) {
  const float* x       = (const float*)d_in[0];
  const float* conv1_w = (const float*)d_in[1];
  const float* conv1_b = (const float*)d_in[2];
  const float* obj_w   = (const float*)d_in[3];
  const float* obj_b   = (const float*)d_in[4];
  const float* loc_w   = (const float*)d_in[5];
  const float* loc_b   = (const float*)d_in[6];
  const float* anch    = (const float*)d_in[7];
  const int*   img_h   = (const int*)d_in[8];
  const int*   img_w   = (const int*)d_in[9];

  char* base = (char*)d_ws;
  float*        wt     = (float*)(base + 0);            // 2304*512*4 = 4,718,592
  float*        h      = (float*)(base + 4718592);      // 2*2500*512*4 = 10,240,000
  uint64_t*     M      = (uint64_t*)(base + 4718592);   // alias h (9,024,000 <= 10,240,000)
  float*        scores = (float*)(base + 14958592);     // 180,000
  float4*       boxes  = (float4*)(base + 15138592);    // 720,000
  float*        sscore = (float*)(base + 15858592);     // 48,000
  float4*       sbox   = (float4*)(base + 15906592);    // 192,000
  uint64_t*     keep   = (uint64_t*)(base + 16098592);  // 1,504
  float*        xp     = (float*)(base + 16100096);     // 5,537,792
  unsigned int* state  = (unsigned int*)(base + 21637888);  // 2*192*4 = 1,536 -> 21.64MB total

  hipLaunchKernelGGL(pad_x, dim3((2 * 256 * XPAD + 255) / 256), dim3(256), 0, stream, x, xp);
  hipLaunchKernelGGL(transpose_w, dim3(72, 16), dim3(256), 0, stream, conv1_w, wt);
  hipLaunchKernelGGL(conv1_gemm, dim3(40, 8, 2), dim3(256), 0, stream, xp, wt, conv1_b, h);
  hipLaunchKernelGGL(heads, dim3(5000), dim3(64), 0, stream, h, obj_w, obj_b, loc_w, loc_b,
                     anch, img_h, img_w, scores, boxes);
  hipLaunchKernelGGL(topk_sort, dim3(2), dim3(1024), 0, stream, scores, boxes, sscore, sbox);
  hipLaunchKernelGGL(iou_mat, dim3(CMAX, 24, 2), dim3(256), 0, stream, sbox, M);
  hipLaunchKernelGGL(nms_scan, dim3(2), dim3(1024), 0, stream, M, sscore, keep, state);
  hipLaunchKernelGGL(iou_rest, dim3(NW - CMAX, 24, 2), dim3(256), 0, stream, sbox, M, state);
  hipLaunchKernelGGL(nms_rest, dim3(2), dim3(1024), 0, stream, M, sscore, keep, state);
  hipLaunchKernelGGL(emit, dim3(2), dim3(128), 0, stream, keep, sscore, sbox, (float*)d_out);
}

// Round 12
// 449.036 us; speedup vs baseline: 1.2610x; 1.1153x over previous
//
#include <hip/hip_runtime.h>
#include <stdint.h>

// ---------------- constants ----------------
#define NPOS 2500      // 50*50
#define NANCH 22500    // NPOS*9
#define NPRE 6000
#define NW 94          // ceil(6000/64)
#define XPAD 2704      // 52*52 padded plane
#define NSLOT 94       // ceil(NPRE/64) radix slots
#define CMAX 32        // restricted NMS chunk budget (2048 candidates)

// async global->LDS DMA (gfx950). dst is wave-uniform base + lane*size.
__device__ __forceinline__ void gl_lds4(const float* g, float* l) {
  __builtin_amdgcn_global_load_lds((const __attribute__((address_space(1))) void*)g,
                                   (__attribute__((address_space(3))) void*)l, 4, 0, 0);
}
__device__ __forceinline__ void gl_lds16(const float* g, float* l) {
  __builtin_amdgcn_global_load_lds((const __attribute__((address_space(1))) void*)g,
                                   (__attribute__((address_space(3))) void*)l, 16, 0, 0);
}

// ---------------- fused prep: weight transpose + x pad + head-weight transpose ----------------
// role A (blocks 0..1151):    w[oc][ic][3][3] -> wt[(tap*256+ic)][oc]
// role B (blocks 1152..6559): x[b][ic][50][50] -> xp[b][ic][52][52] zero-padded
// role C (blocks 6560..6667): obj_w/loc_w rows -> wt54b[k/4][oc(64)][4] (coalesced
//   head-weight layout; R11 lesson: per-lane 2KB-strided weight rows in heads are
//   fully uncoalesced 16B granules -> ~4x L2 line amplification, est. 60-90us)
__global__ __launch_bounds__(256) void prep(const float* __restrict__ w,
                                            float* __restrict__ wt,
                                            const float* __restrict__ x,
                                            float* __restrict__ xp,
                                            const float* __restrict__ objw,
                                            const float* __restrict__ locw,
                                            float* __restrict__ wt54b) {
  __shared__ float tile[32][33];
  int bid = blockIdx.x;
  int tid = threadIdx.x;
  if (bid < 1152) {
    // ---- role A: conv weight transpose ----
    int k0 = (bid % 72) * 32;   // k' = ic*9 + tap
    int o0 = (bid / 72) * 32;
    int tx = tid & 31;
    int ty = tid >> 5;  // 0..7
#pragma unroll
    for (int i = 0; i < 4; ++i) {
      int oc = o0 + ty + i * 8;
      int kp = k0 + tx;
      tile[ty + i * 8][tx] = w[(size_t)oc * 2304 + kp];
    }
    __syncthreads();
#pragma unroll
    for (int i = 0; i < 4; ++i) {
      int kp = k0 + ty + i * 8;
      int ic = kp / 9, tap = kp % 9;
      wt[((size_t)tap * 256 + ic) * 512 + (o0 + tx)] = tile[tx][ty + i * 8];
    }
  } else if (bid < 6560) {
    // ---- role B: zero-pad x ----
    int t = (bid - 1152) * 256 + tid;
    if (t < 2 * 256 * XPAD) {
      int c = t / XPAD;        // b*256 + ic
      int r = t % XPAD;
      int yy = r / 52, xx = r % 52;
      float v = 0.f;
      if (yy >= 1 && yy <= 50 && xx >= 1 && xx <= 50)
        v = x[(size_t)c * NPOS + (yy - 1) * 50 + (xx - 1)];
      xp[t] = v;
    }
  } else {
    // ---- role C: head-weight transpose to [k/4][oc][4] ----
    int t = (bid - 6560) * 256 + tid;
    if (t < 54 * 512) {
      int oc = t / 512, k = t % 512;
      float v = (oc < 18) ? objw[(size_t)oc * 512 + k] : locw[(size_t)(oc - 18) * 512 + k];
      wt54b[((size_t)(k >> 2) * 64 + oc) * 4 + (k & 3)] = v;
    }
  }
}

// ---------------- conv1 3x3 SAME + bias + relu, output NHWC h[b][p][oc] ----------------
// EXACT R7 version (203us measured, best of R2..R10). 64x64 tile, 256 threads,
// single-buffer LDS, DMA staging. Conv verdict: LDS-read-instruction bound
// (~46K b128/CU x 8-12cyc); dbuf (R8/R9 +24us), fat tiles (R10, occupancy
// collapse), reg prefetch (R3, VGPR cliff), small tiles (R4, 2x staging) all lose.
__global__ __launch_bounds__(256) void conv1_gemm(const float* __restrict__ xp,
                                                  const float* __restrict__ wt,
                                                  const float* __restrict__ bias,
                                                  float* __restrict__ h) {
  __shared__ __align__(16) float As[32][64];
  __shared__ __align__(16) float Bs[32][64];
  int b = blockIdx.z;
  int m0 = blockIdx.x * 64;
  int oc0 = blockIdx.y * 64;
  int tid = threadIdx.x;
  int lane = tid & 63;
  int wv = tid >> 6;       // wave 0..3
  int tn = tid & 15, tm = tid >> 4;
  float acc[4][4] = {};

  int p = m0 + lane;
  int pc = p < NPOS ? p : (NPOS - 1);
  int py = pc / 50, px = pc % 50;
  const float* gA0 = xp + (size_t)b * 256 * XPAD + py * 52 + px + 53;
  int brow = lane >> 4, bcol4 = (lane & 15) * 4;

  for (int tap = 0; tap < 9; ++tap) {
    int ky = tap / 3 - 1, kx = tap % 3 - 1;
    int koff = ky * 52 + kx;
    for (int icc = 0; icc < 8; ++icc) {
      int ic0 = icc * 32;
      __syncthreads();  // LDS consumed by previous chunk's compute
#pragma unroll
      for (int j = 0; j < 8; ++j) {
        int kk = wv * 8 + j;
        gl_lds4(gA0 + (size_t)(ic0 + kk) * XPAD + koff, &As[kk][0]);
      }
#pragma unroll
      for (int q = 0; q < 2; ++q) {
        int r0 = wv * 8 + q * 4;
        gl_lds16(wt + ((size_t)tap * 256 + ic0 + r0 + brow) * 512 + oc0 + bcol4,
                 &Bs[r0][0]);
      }
      __syncthreads();  // drains vmcnt -> DMAs complete
#pragma unroll
      for (int kk = 0; kk < 32; ++kk) {
        float4 av = *(const float4*)&As[kk][tm * 4];
        float4 bv = *(const float4*)&Bs[kk][tn * 4];
        float am[4] = {av.x, av.y, av.z, av.w};
        float bn[4] = {bv.x, bv.y, bv.z, bv.w};
#pragma unroll
        for (int i = 0; i < 4; ++i)
#pragma unroll
          for (int j = 0; j < 4; ++j) acc[i][j] = fmaf(am[i], bn[j], acc[i][j]);
      }
    }
  }
#pragma unroll
  for (int i = 0; i < 4; ++i) {
    int pp = m0 + tm * 4 + i;
    if (pp < NPOS) {
      float4 v;
      float* vp = (float*)&v;
#pragma unroll
      for (int j = 0; j < 4; ++j) {
        int oc = oc0 + tn * 4 + j;
        vp[j] = fmaxf(acc[i][j] + bias[oc], 0.f);
      }
      *(float4*)&h[((size_t)b * NPOS + pp) * 512 + oc0 + tn * 4] = v;
    }
  }
}

// ---------------- heads: 1x1 convs + softmax + decode + valid ----------------
// R12: weights via wt54b[k/4][oc][4] -> lane=oc reads consecutive float4
// (1KB/instr coalesced). FMA component order identical to R11 -> bitwise-same.
__global__ __launch_bounds__(64) void heads(const float* __restrict__ h,
                                            const float* __restrict__ wt54b,
                                            const float* __restrict__ objb,
                                            const float* __restrict__ locb,
                                            const float* __restrict__ anch,
                                            const int* __restrict__ imgh,
                                            const int* __restrict__ imgw,
                                            float* __restrict__ scores,
                                            float4* __restrict__ boxes) {
  __shared__ float hv[512];
  __shared__ float outs[64];
  int blk = blockIdx.x;
  int b = blk / NPOS, p = blk % NPOS;
  int lane = threadIdx.x;
  const float4* hp4 = (const float4*)(h + ((size_t)b * NPOS + p) * 512);
  float4* hv4 = (float4*)hv;
  hv4[lane] = hp4[lane];
  hv4[lane + 64] = hp4[lane + 64];
  __syncthreads();
  if (lane < 54) {
    float acc = (lane < 18) ? objb[lane] : locb[lane - 18];
    const float4* w4 = (const float4*)wt54b;
#pragma unroll 4
    for (int k = 0; k < 128; ++k) {
      float4 wv = w4[k * 64 + lane];
      float4 hh = hv4[k];
      acc = fmaf(wv.x, hh.x, acc);
      acc = fmaf(wv.y, hh.y, acc);
      acc = fmaf(wv.z, hh.z, acc);
      acc = fmaf(wv.w, hh.w, acc);
    }
    outs[lane] = acc;
  }
  __syncthreads();
  if (lane < 9) {
    float l0 = outs[2 * lane], l1 = outs[2 * lane + 1];
    float mx = fmaxf(l0, l1);
    float e0 = expf(l0 - mx);
    float e1 = expf(l1 - mx);
    float s = e1 / (e0 + e1);
    float d0 = outs[18 + 4 * lane + 0];
    float d1 = outs[18 + 4 * lane + 1];
    float d2 = outs[18 + 4 * lane + 2];
    float d3 = outs[18 + 4 * lane + 3];
    int ai = p * 9 + lane;
    float4 A = ((const float4*)anch)[ai];
    float aw = A.z - A.x, ah = A.w - A.y;
    float acx = A.x + 0.5f * aw, acy = A.y + 0.5f * ah;
    float cx = acx + d0 * aw, cy = acy + d1 * ah;
    float w = aw * expf(d2), hh = ah * expf(d3);
    float W = (float)imgw[0], H = (float)imgh[0];
    float x1 = fminf(fmaxf(cx - 0.5f * w, 0.f), W);
    float y1 = fminf(fmaxf(cy - 0.5f * hh, 0.f), H);
    float x2 = fminf(fmaxf(cx + 0.5f * w, 0.f), W);
    float y2 = fminf(fmaxf(cy + 0.5f * hh, 0.f), H);
    bool valid = (x2 - x1 >= 16.f) && (y2 - y1 >= 16.f);
    scores[(size_t)b * NANCH + ai] = valid ? s : -1.f;
    boxes[(size_t)b * NANCH + ai] = make_float4(x1, y1, x2, y2);
  }
}

// ---------------- top-6000 select + stable radix sort (one block per batch) ----------------
__device__ inline unsigned int mono_of(float f) {
  unsigned int u = __float_as_uint(f);
  return (u & 0x80000000u) ? ~u : (u | 0x80000000u);
}

// R6 lesson: wave-aggregated hist_add REGRESSED (+67us). Plain atomics kept.
// R7: 6-pass 6-bit stable LSD radix replaced the bitonic (268 -> ~84us).
__global__ __launch_bounds__(1024) void topk_sort(const float* __restrict__ scores,
                                                  const float4* __restrict__ boxes,
                                                  float* __restrict__ sscore,
                                                  float4* __restrict__ sbox) {
  int b = blockIdx.x;
  const float* sc = scores + (size_t)b * NANCH;
  __shared__ unsigned int hist[4096];
  __shared__ unsigned int part[1024];
  __shared__ unsigned short pidA[6016];
  __shared__ unsigned short pidB[6016];
  __shared__ unsigned short table[6144];   // 64 digits x 94 slots (padded)
  __shared__ int res[8];
  int tid = threadIdx.x;
  int lane = tid & 63;
  int wv = tid >> 6;

  // ---------- phase 1: top-12-bit histogram ----------
  for (int i = tid; i < 4096; i += 1024) hist[i] = 0;
  __syncthreads();
  for (int i = tid; i < NANCH; i += 1024) atomicAdd(&hist[mono_of(sc[i]) >> 20], 1u);
  __syncthreads();
  {
    unsigned int h0 = hist[4 * tid], h1 = hist[4 * tid + 1];
    unsigned int h2 = hist[4 * tid + 2], h3 = hist[4 * tid + 3];
    part[tid] = h0 + h1 + h2 + h3;
    __syncthreads();
    for (int off = 1; off < 1024; off <<= 1) {
      unsigned int v = part[tid];
      unsigned int u = (tid + off < 1024) ? part[tid + off] : 0;
      __syncthreads();
      part[tid] = v + u;
      __syncthreads();
    }
    unsigned int c = (tid < 1023) ? part[tid + 1] : 0;  // strict suffix over groups
    const int need = NPRE;
    if (c < (unsigned)need && c + h3 >= (unsigned)need) { res[0] = 4 * tid + 3; res[1] = (int)c; }
    c += h3;
    if (c < (unsigned)need && c + h2 >= (unsigned)need) { res[0] = 4 * tid + 2; res[1] = (int)c; }
    c += h2;
    if (c < (unsigned)need && c + h1 >= (unsigned)need) { res[0] = 4 * tid + 1; res[1] = (int)c; }
    c += h1;
    if (c < (unsigned)need && c + h0 >= (unsigned)need) { res[0] = 4 * tid + 0; res[1] = (int)c; }
  }
  __syncthreads();
  int t1 = res[0], a1 = res[1];
  __syncthreads();

  // ---------- phase 2: middle-12 bits within bin t1 ----------
  for (int i = tid; i < 4096; i += 1024) hist[i] = 0;
  __syncthreads();
  for (int i = tid; i < NANCH; i += 1024) {
    unsigned int m = mono_of(sc[i]);
    if ((int)(m >> 20) == t1) atomicAdd(&hist[(m >> 8) & 0xFFF], 1u);
  }
  __syncthreads();
  {
    unsigned int h0 = hist[4 * tid], h1 = hist[4 * tid + 1];
    unsigned int h2 = hist[4 * tid + 2], h3 = hist[4 * tid + 3];
    part[tid] = h0 + h1 + h2 + h3;
    __syncthreads();
    for (int off = 1; off < 1024; off <<= 1) {
      unsigned int v = part[tid];
      unsigned int u = (tid + off < 1024) ? part[tid + off] : 0;
      __syncthreads();
      part[tid] = v + u;
      __syncthreads();
    }
    unsigned int c = (tid < 1023) ? part[tid + 1] : 0;
    const unsigned int need = (unsigned)(NPRE - a1);
    if (c < need && c + h3 >= need) { res[2] = 4 * tid + 3; res[3] = (int)c; }
    c += h3;
    if (c < need && c + h2 >= need) { res[2] = 4 * tid + 2; res[3] = (int)c; }
    c += h2;
    if (c < need && c + h1 >= need) { res[2] = 4 * tid + 1; res[3] = (int)c; }
    c += h1;
    if (c < need && c + h0 >= need) { res[2] = 4 * tid + 0; res[3] = (int)c; }
  }
  __syncthreads();
  int t2 = res[2], a2 = res[3];
  __syncthreads();

  // ---------- phase 3: low-8 bits within (t1,t2) ----------
  for (int i = tid; i < 256; i += 1024) hist[i] = 0;
  __syncthreads();
  unsigned int top24 = ((unsigned int)t1 << 12) | (unsigned int)t2;
  for (int i = tid; i < NANCH; i += 1024) {
    unsigned int m = mono_of(sc[i]);
    if ((m >> 8) == top24) atomicAdd(&hist[m & 0xFF], 1u);
  }
  __syncthreads();
  {
    unsigned int hb = (tid < 256) ? hist[tid] : 0;
    part[tid] = hb;
    __syncthreads();
    for (int off = 1; off < 1024; off <<= 1) {
      unsigned int v = part[tid];
      unsigned int u = (tid + off < 1024) ? part[tid + off] : 0;
      __syncthreads();
      part[tid] = v + u;
      __syncthreads();
    }
    if (tid < 256) {
      unsigned int c = part[tid + 1];
      const unsigned int need = (unsigned)(NPRE - a1 - a2);
      if (c < need && c + hb >= need) {
        res[4] = tid;
        res[6] = (int)(need - c);                         // ties_needed
        res[7] = (hb == need - c) ? NANCH : -1;           // idx_cut or TBD
      }
    }
  }
  __syncthreads();
  int t3 = res[4];
  unsigned int T = (top24 << 8) | (unsigned int)t3;
  int ties_needed = res[6];
  int idx_cut = res[7];
  __syncthreads();

  // ---------- phase 4 (rare): tie resolution by smallest index ----------
  if (idx_cut < 0) {
    for (int i = tid; i < 704; i += 1024) hist[i] = 0;
    __syncthreads();
    for (int i = tid; i < NANCH; i += 1024)
      if (mono_of(sc[i]) == T) atomicAdd(&hist[i >> 5], 1u);
    __syncthreads();
    if (tid == 0) {
      int c = 0, cut = NANCH;
      for (int bin = 0; bin < 704; ++bin) {
        int hc = (int)hist[bin];
        if (c + hc >= ties_needed) {
          int c2 = c;
          for (int idx = bin * 32; idx < bin * 32 + 32; ++idx) {
            if (idx < NANCH && mono_of(sc[idx]) == T) {
              ++c2;
              if (c2 == ties_needed) { cut = idx; break; }
            }
          }
          break;
        }
        c += hc;
      }
      res[7] = cut;
    }
    __syncthreads();
    idx_cut = res[7];
    __syncthreads();
  }

  // ---------- phase 5: deterministic idx-order compact (blocked ranges + scan) ----------
  int base0 = tid * 22;  // 1024*22 = 22528 >= NANCH
  unsigned int selm = 0;
  int cnt = 0;
  for (int k = 0; k < 22; ++k) {
    int i = base0 + k;
    if (i < NANCH) {
      unsigned int m = mono_of(sc[i]);
      if (m > T || (m == T && i <= idx_cut)) { selm |= 1u << k; ++cnt; }
    }
  }
  {
    int inc = cnt;
#pragma unroll
    for (int d = 1; d < 64; d <<= 1) {
      int u = __shfl_up(inc, d, 64);
      if (lane >= d) inc += u;
    }
    if (lane == 63) part[wv] = (unsigned int)inc;
    __syncthreads();
    if (tid < 16) {
      int v = (int)part[tid];
      int inc2 = v;
#pragma unroll
      for (int d = 1; d < 16; d <<= 1) {
        int u = __shfl_up(inc2, d, 16);
        if (tid >= d) inc2 += u;
      }
      part[tid] = (unsigned int)(inc2 - v);  // exclusive wave base
    }
    __syncthreads();
    int pos = (int)part[wv] + (inc - cnt);
    for (int k = 0; k < 22; ++k)
      if ((selm >> k) & 1u) pidA[pos++] = (unsigned short)(base0 + k);
  }
  __syncthreads();

  // ---------- phase 6: 6-pass 6-bit stable LSD radix, key = ~mono (asc) ----------
  unsigned short* src = pidA;
  unsigned short* dst = pidB;
  for (int pass = 0; pass < 6; ++pass) {
    int shift = pass * 6;
    for (int i = tid; i < 6144; i += 1024) table[i] = 0;
    __syncthreads();
    int dig[6], irk[6], pidr[6];
#pragma unroll
    for (int k = 0; k < 6; ++k) {
      dig[k] = 0; irk[k] = 0; pidr[k] = 0;
      int s = wv + 16 * k;          // wave-uniform
      if (s < NSLOT) {
        int e = s * 64 + lane;
        bool act = e < NPRE;
        int pid = act ? (int)src[e] : 0;
        unsigned int key = act ? ~mono_of(sc[pid]) : 0u;
        int d = (int)((key >> shift) & 63u);
        uint64_t peers = __ballot(act);
#pragma unroll
        for (int bb = 0; bb < 6; ++bb) {
          uint64_t bl = __ballot(((d >> bb) & 1) != 0);
          peers &= ((d >> bb) & 1) ? bl : ~bl;
        }
        if (act) {
          dig[k] = d;
          pidr[k] = pid;
          irk[k] = (int)__popcll(peers & ((1ull << lane) - 1ull));
          int leader = __ffsll((long long)peers) - 1;
          if (lane == leader)
            table[d * NSLOT + s] = (unsigned short)__popcll(peers);
        }
      }
    }
    __syncthreads();
    // exclusive scan over table[0..6143] (digit-major, slot-minor)
    {
      int t6 = tid * 6;
      int v0 = table[t6], v1 = table[t6 + 1], v2 = table[t6 + 2];
      int v3 = table[t6 + 3], v4 = table[t6 + 4], v5 = table[t6 + 5];
      int lsum = v0 + v1 + v2 + v3 + v4 + v5;
      int inc = lsum;
#pragma unroll
      for (int d = 1; d < 64; d <<= 1) {
        int u = __shfl_up(inc, d, 64);
        if (lane >= d) inc += u;
      }
      if (lane == 63) part[wv] = (unsigned int)inc;
      __syncthreads();
      if (tid < 16) {
        int v = (int)part[tid];
        int inc2 = v;
#pragma unroll
        for (int d = 1; d < 16; d <<= 1) {
          int u = __shfl_up(inc2, d, 16);
          if (tid >= d) inc2 += u;
        }
        part[tid] = (unsigned int)(inc2 - v);
      }
      __syncthreads();
      int run = (int)part[wv] + (inc - lsum);
      table[t6] = (unsigned short)run; run += v0;
      table[t6 + 1] = (unsigned short)run; run += v1;
      table[t6 + 2] = (unsigned short)run; run += v2;
      table[t6 + 3] = (unsigned short)run; run += v3;
      table[t6 + 4] = (unsigned short)run; run += v4;
      table[t6 + 5] = (unsigned short)run;
    }
    __syncthreads();
    // scatter (stable): pos = base(digit,slot) + intra-slot rank
#pragma unroll
    for (int k = 0; k < 6; ++k) {
      int s = wv + 16 * k;
      if (s < NSLOT) {
        int e = s * 64 + lane;
        if (e < NPRE) {
          int pos = (int)table[dig[k] * NSLOT + s] + irk[k];
          dst[pos] = (unsigned short)pidr[k];
        }
      }
    }
    __syncthreads();
    unsigned short* tmp = src; src = dst; dst = tmp;
  }
  // 6 passes -> result back in pidA (== src)

  // ---------- phase 7: gather sorted scores/boxes ----------
  for (int r = tid; r < NPRE; r += 1024) {
    int idx = (int)src[r];
    sscore[(size_t)b * NPRE + r] = sc[idx];
    sbox[(size_t)b * NPRE + r] = boxes[(size_t)b * NANCH + idx];
  }
}

// ---------------- IoU suppression bitmask (shared body) ----------------
__device__ __forceinline__ void iou_tile(const float4* __restrict__ sbox,
                                         uint64_t* __restrict__ M,
                                         int b, int it, int jt, int tid,
                                         float4* bi, float4* bj) {
  if (tid < 64) {
    int i = it * 64 + tid;
    bi[tid] = (i < NPRE) ? sbox[(size_t)b * NPRE + i] : make_float4(0, 0, 0, 0);
  }
  {
    int j = jt * 256 + tid;
    bj[tid] = (j < NPRE) ? sbox[(size_t)b * NPRE + j] : make_float4(0, 0, 0, 0);
  }
  __syncthreads();
  int li = tid & 63, wq = tid >> 6;
  int i = it * 64 + li;
  int w = jt * 4 + wq;
  if (i < NPRE && w < NW) {
    float4 A = bi[li];
    float areaA = (A.z - A.x) * (A.w - A.y);
    uint64_t bits = 0;
#pragma unroll 8
    for (int jj = 0; jj < 64; ++jj) {
      int j = w * 64 + jj;
      float4 Bx = bj[wq * 64 + jj];
      float ix1 = fmaxf(A.x, Bx.x), iy1 = fmaxf(A.y, Bx.y);
      float ix2 = fminf(A.z, Bx.z), iy2 = fminf(A.w, Bx.w);
      float inter = fmaxf(ix2 - ix1, 0.f) * fmaxf(iy2 - iy1, 0.f);
      float areaB = (Bx.z - Bx.x) * (Bx.w - Bx.y);
      float iou = inter / (areaA + areaB - inter);
      if ((j > i) && (j < NPRE) && (iou > 0.7f)) bits |= (1ull << jj);
    }
    M[((size_t)b * NPRE + i) * NW + w] = bits;
  }
}

// restricted: rows < CMAX*64 only (full 94-word width -> sup state stays complete)
__global__ __launch_bounds__(256) void iou_mat(const float4* __restrict__ sbox,
                                               uint64_t* __restrict__ M) {
  __shared__ float4 bi[64];
  __shared__ float4 bj[256];
  iou_tile(sbox, M, blockIdx.z, blockIdx.x, blockIdx.y, threadIdx.x, bi, bj);
}

// fallback: rows >= CMAX*64; no-op when NMS finished within CMAX chunks
__global__ __launch_bounds__(256) void iou_rest(const float4* __restrict__ sbox,
                                                uint64_t* __restrict__ M,
                                                const unsigned int* __restrict__ state) {
  if (state[blockIdx.z * 192 + 189]) return;  // done
  __shared__ float4 bi[64];
  __shared__ float4 bj[256];
  iou_tile(sbox, M, blockIdx.z, blockIdx.x + CMAX, blockIdx.y, threadIdx.x, bi, bj);
}

// ---------------- NMS scan: wave0 serial closure + block-parallel OR + early exit ----------------
__device__ inline uint64_t shfl64(uint64_t v, int src) {
  int lo = __shfl((int)(unsigned int)(v & 0xFFFFFFFFull), src, 64);
  int hi = __shfl((int)(unsigned int)(v >> 32), src, 64);
  return ((uint64_t)(unsigned int)hi << 32) | (unsigned int)lo;
}

// one NMS chunk step
__device__ __forceinline__ void nms_chunk(const uint64_t* __restrict__ Mb,
                                          const float* __restrict__ sscore,
                                          uint64_t* __restrict__ keep,
                                          int b, int c, int tid,
                                          unsigned int* supLo, unsigned int* supHi,
                                          int* klist, int* knS, int* countS) {
  int ibase = c * 64;
  if (tid < 64) {
    int lane = tid;
    if (lane == 0) *knS = 0;
    uint64_t supc = ((uint64_t)supHi[c] << 32) | supLo[c];
    uint64_t validm = (c == NW - 1) ? ((1ull << (NPRE - (NW - 1) * 64)) - 1ull) : ~0ull;
    int pos = ibase + lane;
    uint64_t myrow = (pos < NPRE) ? Mb[(size_t)pos * NW + c] : 0ull;
    bool sval = (pos < NPRE) && (sscore[(size_t)b * NPRE + pos] >= 0.f);
    uint64_t vb = __ballot(sval);
    uint64_t cur = validm & ~supc;
    uint64_t kept = 0;
    while (cur) {
      int i = __ffsll((long long)cur) - 1;
      kept |= (1ull << i);
      cur &= ~(1ull << i);
      uint64_t row = shfl64(myrow, i);
      cur &= ~row;
    }
    if (kept & (1ull << lane)) {
      int pp = atomicAdd(knS, 1);
      klist[pp] = lane;
    }
    if (lane == 0) {
      keep[b * NW + c] = kept;
      *countS += __popcll(kept & vb);
    }
  }
  __syncthreads();  // [A] klist/knS/count visible; sup[c] consumed
  int kn = *knS;
  for (int t = tid; t < kn * 128; t += 1024) {
    int ii = t >> 7, w = t & 127;
    if (w > c && w < NW) {
      uint64_t row = Mb[(size_t)(ibase + klist[ii]) * NW + w];
      unsigned int lo = (unsigned int)row;
      unsigned int hi = (unsigned int)(row >> 32);
      if (lo) atomicOr(&supLo[w], lo);
      if (hi) atomicOr(&supHi[w], hi);
    }
  }
  __syncthreads();  // [B] sup updated before next chunk's closure
}

// phase A: chunks 0..CMAX; persists (sup, count, done) for the gated fallback
__global__ __launch_bounds__(1024) void nms_scan(const uint64_t* __restrict__ M,
                                                 const float* __restrict__ sscore,
                                                 uint64_t* __restrict__ keep,
                                                 unsigned int* __restrict__ state) {
  __shared__ unsigned int supLo[NW], supHi[NW];
  __shared__ int klist[64];
  __shared__ int knS;
  __shared__ int countS;
  int b = blockIdx.x;
  int tid = threadIdx.x;
  const uint64_t* Mb = M + (size_t)b * NPRE * NW;

  for (int w = tid; w < NW; w += 1024) {
    supLo[w] = 0;
    supHi[w] = 0;
    keep[b * NW + w] = 0;  // early-exit / fallback leaves untouched chunks zeroed
  }
  if (tid == 0) countS = 0;
  __syncthreads();

  int done = 0;
  for (int c = 0; c < CMAX; ++c) {
    nms_chunk(Mb, sscore, keep, b, c, tid, supLo, supHi, klist, &knS, &countS);
    if (countS >= 300) { done = 1; break; }  // uniform: countS read post-barrier
  }
  __syncthreads();
  unsigned int* st = state + b * 192;
  for (int w = tid; w < NW; w += 1024) { st[w] = supLo[w]; st[94 + w] = supHi[w]; }
  if (tid == 0) { st[188] = (unsigned int)countS; st[189] = (unsigned int)done; }
}

// fallback: continues from chunk CMAX with complete sup state; no-op when done
__global__ __launch_bounds__(1024) void nms_rest(const uint64_t* __restrict__ M,
                                                 const float* __restrict__ sscore,
                                                 uint64_t* __restrict__ keep,
                                                 const unsigned int* __restrict__ state) {
  int b = blockIdx.x;
  const unsigned int* st = state + b * 192;
  if (st[189]) return;  // done — uniform
  __shared__ unsigned int supLo[NW], supHi[NW];
  __shared__ int klist[64];
  __shared__ int knS;
  __shared__ int countS;
  int tid = threadIdx.x;
  const uint64_t* Mb = M + (size_t)b * NPRE * NW;
  for (int w = tid; w < NW; w += 1024) { supLo[w] = st[w]; supHi[w] = st[94 + w]; }
  if (tid == 0) countS = (int)st[188];
  __syncthreads();
  for (int c = CMAX; c < NW; ++c) {
    nms_chunk(Mb, sscore, keep, b, c, tid, supLo, supHi, klist, &knS, &countS);
    if (countS >= 300) break;
  }
}

// ---------------- emit top-300 ----------------
__global__ __launch_bounds__(128) void emit(const uint64_t* __restrict__ keep,
                                            const float* __restrict__ sscore,
                                            const float4* __restrict__ sbox,
                                            float* __restrict__ out) {
  __shared__ int cnt[128];
  __shared__ uint64_t fw[NW];
  int b = blockIdx.x;
  int tid = threadIdx.x;
  for (int i = tid; i < 1200; i += 128) out[b * 1200 + i] = 0.f;
  for (int i = tid; i < 300; i += 128) {
    out[2400 + b * 300 + i] = 0.f;
    out[3000 + b * 300 + i] = 0.f;
  }
  uint64_t w = 0;
  if (tid < NW) {
    uint64_t kw = keep[b * NW + tid];
    while (kw) {
      int j = __ffsll((long long)kw) - 1;
      kw &= kw - 1;
      if (sscore[(size_t)b * NPRE + tid * 64 + j] >= 0.f) w |= (1ull << j);
    }
    fw[tid] = w;
  }
  cnt[tid] = (tid < NW) ? __popcll(w) : 0;
  __syncthreads();
  for (int off = 1; off < 128; off <<= 1) {
    int v = cnt[tid];
    int u = (tid >= off) ? cnt[tid - off] : 0;
    __syncthreads();
    cnt[tid] = v + u;
    __syncthreads();
  }
  if (tid < NW) {
    int base = cnt[tid] - __popcll(fw[tid]);
    uint64_t ww = fw[tid];
    while (ww) {
      int j = __ffsll((long long)ww) - 1;
      ww &= ww - 1;
      if (base < 300) {
        int p = tid * 64 + j;
        float4 bx = sbox[(size_t)b * NPRE + p];
        float* ob = out + b * 1200 + base * 4;
        ob[0] = bx.x; ob[1] = bx.y; ob[2] = bx.z; ob[3] = bx.w;
        out[2400 + b * 300 + base] = sscore[(size_t)b * NPRE + p];
        out[3000 + b * 300 + base] = 1.0f;
      }
      ++base;
    }
  }
}

// ---------------- launch ----------------
extern "C" void kernel_launch(void* const* d_in, const int* in_sizes, int n_in,
                              void* d_out, int out_size, void* d_ws, size_t ws_size,
                              hipStream_t stream) {
  const float* x       = (const float*)d_in[0];
  const float* conv1_w = (const float*)d_in[1];
  const float* conv1_b = (const float*)d_in[2];
  const float* obj_w   = (const float*)d_in[3];
  const float* obj_b   = (const float*)d_in[4];
  const float* loc_w   = (const float*)d_in[5];
  const float* loc_b   = (const float*)d_in[6];
  const float* anch    = (const float*)d_in[7];
  const int*   img_h   = (const int*)d_in[8];
  const int*   img_w   = (const int*)d_in[9];

  char* base = (char*)d_ws;
  float*        wt     = (float*)(base + 0);            // 2304*512*4 = 4,718,592
  float*        h      = (float*)(base + 4718592);      // 2*2500*512*4 = 10,240,000
  uint64_t*     M      = (uint64_t*)(base + 4718592);   // alias h (9,024,000 <= 10,240,000)
  float*        scores = (float*)(base + 14958592);     // 180,000
  float4*       boxes  = (float4*)(base + 15138592);    // 720,000
  float*        sscore = (float*)(base + 15858592);     // 48,000
  float4*       sbox   = (float4*)(base + 15906592);    // 192,000
  uint64_t*     keep   = (uint64_t*)(base + 16098592);  // 1,504
  float*        xp     = (float*)(base + 16100096);     // 5,537,792
  unsigned int* state  = (unsigned int*)(base + 21637888);  // 2*192*4 = 1,536
  // wt54b (128*64*4 floats = 131,072 B) ALIASES sbox: written by prep, read only
  // by heads, overwritten by topk_sort phase 7 afterwards (stream-ordered safe).
  float*        wt54b  = (float*)(base + 15906592);

  hipLaunchKernelGGL(prep, dim3(6668), dim3(256), 0, stream,
                     conv1_w, wt, x, xp, obj_w, loc_w, wt54b);
  hipLaunchKernelGGL(conv1_gemm, dim3(40, 8, 2), dim3(256), 0, stream, xp, wt, conv1_b, h);
  hipLaunchKernelGGL(heads, dim3(5000), dim3(64), 0, stream, h, wt54b, obj_b, loc_b,
                     anch, img_h, img_w, scores, boxes);
  hipLaunchKernelGGL(topk_sort, dim3(2), dim3(1024), 0, stream, scores, boxes, sscore, sbox);
  hipLaunchKernelGGL(iou_mat, dim3(CMAX, 24, 2), dim3(256), 0, stream, sbox, M);
  hipLaunchKernelGGL(nms_scan, dim3(2), dim3(1024), 0, stream, M, sscore, keep, state);
  hipLaunchKernelGGL(iou_rest, dim3(NW - CMAX, 24, 2), dim3(256), 0, stream, sbox, M, state);
  hipLaunchKernelGGL(nms_rest, dim3(2), dim3(1024), 0, stream, M, sscore, keep, state);
  hipLaunchKernelGGL(emit, dim3(2), dim3(128), 0, stream, keep, sscore, sbox, (float*)d_out);
}

// Round 13
// 446.133 us; speedup vs baseline: 1.2693x; 1.0065x over previous
//
#include <hip/hip_runtime.h>
#include <stdint.h>

// ---------------- constants ----------------
#define NPOS 2500      // 50*50
#define NANCH 22500    // NPOS*9
#define NPRE 6000
#define NW 94          // ceil(6000/64)
#define XPAD 2704      // 52*52 padded plane
#define NSLOT 94       // ceil(NPRE/64) radix slots
#define CMAX 32        // restricted NMS chunk budget (2048 candidates)

// async global->LDS DMA (gfx950). dst is wave-uniform base + lane*size.
__device__ __forceinline__ void gl_lds4(const float* g, float* l) {
  __builtin_amdgcn_global_load_lds((const __attribute__((address_space(1))) void*)g,
                                   (__attribute__((address_space(3))) void*)l, 4, 0, 0);
}
__device__ __forceinline__ void gl_lds16(const float* g, float* l) {
  __builtin_amdgcn_global_load_lds((const __attribute__((address_space(1))) void*)g,
                                   (__attribute__((address_space(3))) void*)l, 16, 0, 0);
}

// ---------------- fused prep: weight transpose + x pad + head-weight transpose ----------------
__global__ __launch_bounds__(256) void prep(const float* __restrict__ w,
                                            float* __restrict__ wt,
                                            const float* __restrict__ x,
                                            float* __restrict__ xp,
                                            const float* __restrict__ objw,
                                            const float* __restrict__ locw,
                                            float* __restrict__ wt54b) {
  __shared__ float tile[32][33];
  int bid = blockIdx.x;
  int tid = threadIdx.x;
  if (bid < 1152) {
    // ---- role A: conv weight transpose ----
    int k0 = (bid % 72) * 32;   // k' = ic*9 + tap
    int o0 = (bid / 72) * 32;
    int tx = tid & 31;
    int ty = tid >> 5;  // 0..7
#pragma unroll
    for (int i = 0; i < 4; ++i) {
      int oc = o0 + ty + i * 8;
      int kp = k0 + tx;
      tile[ty + i * 8][tx] = w[(size_t)oc * 2304 + kp];
    }
    __syncthreads();
#pragma unroll
    for (int i = 0; i < 4; ++i) {
      int kp = k0 + ty + i * 8;
      int ic = kp / 9, tap = kp % 9;
      wt[((size_t)tap * 256 + ic) * 512 + (o0 + tx)] = tile[tx][ty + i * 8];
    }
  } else if (bid < 6560) {
    // ---- role B: zero-pad x ----
    int t = (bid - 1152) * 256 + tid;
    if (t < 2 * 256 * XPAD) {
      int c = t / XPAD;        // b*256 + ic
      int r = t % XPAD;
      int yy = r / 52, xx = r % 52;
      float v = 0.f;
      if (yy >= 1 && yy <= 50 && xx >= 1 && xx <= 50)
        v = x[(size_t)c * NPOS + (yy - 1) * 50 + (xx - 1)];
      xp[t] = v;
    }
  } else {
    // ---- role C: head-weight transpose to [k/4][oc][4] ----
    int t = (bid - 6560) * 256 + tid;
    if (t < 54 * 512) {
      int oc = t / 512, k = t % 512;
      float v = (oc < 18) ? objw[(size_t)oc * 512 + k] : locw[(size_t)(oc - 18) * 512 + k];
      wt54b[((size_t)(k >> 2) * 64 + oc) * 4 + (k & 3)] = v;
    }
  }
}

// ---------------- conv1 3x3 SAME + bias + relu, output NHWC h[b][p][oc] ----------------
// EXACT R7 version (199-203us, best of R2..R10). LDS-read-instruction bound:
// 10 waves/CU x 2304 ksteps x 2 ds_read_b128 x 12cyc ~= 230us wall. All
// restructurings lose (R3 VGPR cliff, R4 2x staging, R8/R9 dbuf +24us,
// R10 occupancy collapse). Do not touch.
__global__ __launch_bounds__(256) void conv1_gemm(const float* __restrict__ xp,
                                                  const float* __restrict__ wt,
                                                  const float* __restrict__ bias,
                                                  float* __restrict__ h) {
  __shared__ __align__(16) float As[32][64];
  __shared__ __align__(16) float Bs[32][64];
  int b = blockIdx.z;
  int m0 = blockIdx.x * 64;
  int oc0 = blockIdx.y * 64;
  int tid = threadIdx.x;
  int lane = tid & 63;
  int wv = tid >> 6;       // wave 0..3
  int tn = tid & 15, tm = tid >> 4;
  float acc[4][4] = {};

  int p = m0 + lane;
  int pc = p < NPOS ? p : (NPOS - 1);
  int py = pc / 50, px = pc % 50;
  const float* gA0 = xp + (size_t)b * 256 * XPAD + py * 52 + px + 53;
  int brow = lane >> 4, bcol4 = (lane & 15) * 4;

  for (int tap = 0; tap < 9; ++tap) {
    int ky = tap / 3 - 1, kx = tap % 3 - 1;
    int koff = ky * 52 + kx;
    for (int icc = 0; icc < 8; ++icc) {
      int ic0 = icc * 32;
      __syncthreads();  // LDS consumed by previous chunk's compute
#pragma unroll
      for (int j = 0; j < 8; ++j) {
        int kk = wv * 8 + j;
        gl_lds4(gA0 + (size_t)(ic0 + kk) * XPAD + koff, &As[kk][0]);
      }
#pragma unroll
      for (int q = 0; q < 2; ++q) {
        int r0 = wv * 8 + q * 4;
        gl_lds16(wt + ((size_t)tap * 256 + ic0 + r0 + brow) * 512 + oc0 + bcol4,
                 &Bs[r0][0]);
      }
      __syncthreads();  // drains vmcnt -> DMAs complete
#pragma unroll
      for (int kk = 0; kk < 32; ++kk) {
        float4 av = *(const float4*)&As[kk][tm * 4];
        float4 bv = *(const float4*)&Bs[kk][tn * 4];
        float am[4] = {av.x, av.y, av.z, av.w};
        float bn[4] = {bv.x, bv.y, bv.z, bv.w};
#pragma unroll
        for (int i = 0; i < 4; ++i)
#pragma unroll
          for (int j = 0; j < 4; ++j) acc[i][j] = fmaf(am[i], bn[j], acc[i][j]);
      }
    }
  }
#pragma unroll
  for (int i = 0; i < 4; ++i) {
    int pp = m0 + tm * 4 + i;
    if (pp < NPOS) {
      float4 v;
      float* vp = (float*)&v;
#pragma unroll
      for (int j = 0; j < 4; ++j) {
        int oc = oc0 + tn * 4 + j;
        vp[j] = fmaxf(acc[i][j] + bias[oc], 0.f);
      }
      *(float4*)&h[((size_t)b * NPOS + pp) * 512 + oc0 + tn * 4] = v;
    }
  }
}

// ---------------- heads: 4 positions per wave (weight reads amortized 4x) ----------------
// R12 measured heads ~20us = L2 weight traffic (5000 blocks x 110KB = 550MB).
// R13: one wv load feeds 4 positions' FMAs -> 137MB. Per-output FMA k/component
// order identical to R12 -> bitwise-same scores/boxes.
__global__ __launch_bounds__(64) void heads(const float* __restrict__ h,
                                            const float* __restrict__ wt54b,
                                            const float* __restrict__ objb,
                                            const float* __restrict__ locb,
                                            const float* __restrict__ anch,
                                            const int* __restrict__ imgh,
                                            const int* __restrict__ imgw,
                                            float* __restrict__ scores,
                                            float4* __restrict__ boxes) {
  __shared__ float hv[4 * 512];
  __shared__ float outs[4][64];
  int blk = blockIdx.x;             // 0..1249
  int b = blk / 625;
  int p0 = (blk % 625) * 4;         // 4 consecutive positions
  int lane = threadIdx.x;
  const float4* hp4 = (const float4*)(h + ((size_t)b * NPOS + p0) * 512);
  float4* hv4 = (float4*)hv;
#pragma unroll
  for (int q = 0; q < 8; ++q) hv4[lane + 64 * q] = hp4[lane + 64 * q];
  __syncthreads();
  if (lane < 54) {
    float bias0 = (lane < 18) ? objb[lane] : locb[lane - 18];
    float a0 = bias0, a1 = bias0, a2 = bias0, a3 = bias0;
    const float4* w4 = (const float4*)wt54b;
#pragma unroll 4
    for (int k = 0; k < 128; ++k) {
      float4 wv = w4[k * 64 + lane];
      float4 h0 = hv4[k], h1 = hv4[128 + k], h2 = hv4[256 + k], h3 = hv4[384 + k];
      a0 = fmaf(wv.x, h0.x, a0); a0 = fmaf(wv.y, h0.y, a0);
      a0 = fmaf(wv.z, h0.z, a0); a0 = fmaf(wv.w, h0.w, a0);
      a1 = fmaf(wv.x, h1.x, a1); a1 = fmaf(wv.y, h1.y, a1);
      a1 = fmaf(wv.z, h1.z, a1); a1 = fmaf(wv.w, h1.w, a1);
      a2 = fmaf(wv.x, h2.x, a2); a2 = fmaf(wv.y, h2.y, a2);
      a2 = fmaf(wv.z, h2.z, a2); a2 = fmaf(wv.w, h2.w, a2);
      a3 = fmaf(wv.x, h3.x, a3); a3 = fmaf(wv.y, h3.y, a3);
      a3 = fmaf(wv.z, h3.z, a3); a3 = fmaf(wv.w, h3.w, a3);
    }
    outs[0][lane] = a0; outs[1][lane] = a1; outs[2][lane] = a2; outs[3][lane] = a3;
  }
  __syncthreads();
  if (lane < 36) {
    int pi = lane / 9, a = lane % 9;
    int p = p0 + pi;
    float l0 = outs[pi][2 * a], l1 = outs[pi][2 * a + 1];
    float mx = fmaxf(l0, l1);
    float e0 = expf(l0 - mx);
    float e1 = expf(l1 - mx);
    float s = e1 / (e0 + e1);
    float d0 = outs[pi][18 + 4 * a + 0];
    float d1 = outs[pi][18 + 4 * a + 1];
    float d2 = outs[pi][18 + 4 * a + 2];
    float d3 = outs[pi][18 + 4 * a + 3];
    int ai = p * 9 + a;
    float4 A = ((const float4*)anch)[ai];
    float aw = A.z - A.x, ah = A.w - A.y;
    float acx = A.x + 0.5f * aw, acy = A.y + 0.5f * ah;
    float cx = acx + d0 * aw, cy = acy + d1 * ah;
    float w = aw * expf(d2), hh = ah * expf(d3);
    float W = (float)imgw[0], H = (float)imgh[0];
    float x1 = fminf(fmaxf(cx - 0.5f * w, 0.f), W);
    float y1 = fminf(fmaxf(cy - 0.5f * hh, 0.f), H);
    float x2 = fminf(fmaxf(cx + 0.5f * w, 0.f), W);
    float y2 = fminf(fmaxf(cy + 0.5f * hh, 0.f), H);
    bool valid = (x2 - x1 >= 16.f) && (y2 - y1 >= 16.f);
    scores[(size_t)b * NANCH + ai] = valid ? s : -1.f;
    boxes[(size_t)b * NANCH + ai] = make_float4(x1, y1, x2, y2);
  }
}

// ---------------- top-6000 select + stable radix sort (one block per batch) ----------------
__device__ inline unsigned int mono_of(float f) {
  unsigned int u = __float_as_uint(f);
  return (u & 0x80000000u) ? ~u : (u | 0x80000000u);
}

// strict suffix sum over 1024 per-thread values (sum of v at tids > tid).
// Shuffle-based: 2 barriers vs the 20 of offset-doubling (R13: 3 scans x ~18
// barriers saved ~= 10us at 16 waves). Exact integer semantics preserved.
__device__ __forceinline__ unsigned int suffix_strict(unsigned int v,
                                                      unsigned int* partw,
                                                      int tid, int lane, int wv) {
  unsigned int inc = v;
#pragma unroll
  for (int d = 1; d < 64; d <<= 1) {
    unsigned int u = __shfl_down(inc, d, 64);
    if (lane + d < 64) inc += u;
  }
  if (lane == 0) partw[wv] = inc;  // wave total
  __syncthreads();
  if (tid < 16) {
    unsigned int tot = partw[tid];
    unsigned int inc2 = tot;
#pragma unroll
    for (int d = 1; d < 16; d <<= 1) {
      unsigned int u = __shfl_down(inc2, d, 64);
      if (tid + d < 16) inc2 += u;
    }
    partw[tid] = inc2 - tot;  // strict suffix of later waves
  }
  __syncthreads();
  return partw[wv] + (inc - v);
}

// R6 lesson: wave-aggregated hist_add REGRESSED (+67us). Plain atomics kept.
// R7: 6-pass 6-bit stable LSD radix replaced the bitonic (268 -> ~84us).
__global__ __launch_bounds__(1024) void topk_sort(const float* __restrict__ scores,
                                                  const float4* __restrict__ boxes,
                                                  float* __restrict__ sscore,
                                                  float4* __restrict__ sbox) {
  int b = blockIdx.x;
  const float* sc = scores + (size_t)b * NANCH;
  __shared__ unsigned int hist[4096];
  __shared__ unsigned int part[1024];
  __shared__ unsigned short pidA[6016];
  __shared__ unsigned short pidB[6016];
  __shared__ unsigned short table[6144];   // 64 digits x 94 slots (padded)
  __shared__ int res[8];
  int tid = threadIdx.x;
  int lane = tid & 63;
  int wv = tid >> 6;

  // ---------- phase 1: top-12-bit histogram ----------
  for (int i = tid; i < 4096; i += 1024) hist[i] = 0;
  __syncthreads();
  for (int i = tid; i < NANCH; i += 1024) atomicAdd(&hist[mono_of(sc[i]) >> 20], 1u);
  __syncthreads();
  {
    unsigned int h0 = hist[4 * tid], h1 = hist[4 * tid + 1];
    unsigned int h2 = hist[4 * tid + 2], h3 = hist[4 * tid + 3];
    unsigned int c = suffix_strict(h0 + h1 + h2 + h3, part, tid, lane, wv);
    const unsigned int need = NPRE;
    if (c < need && c + h3 >= need) { res[0] = 4 * tid + 3; res[1] = (int)c; }
    c += h3;
    if (c < need && c + h2 >= need) { res[0] = 4 * tid + 2; res[1] = (int)c; }
    c += h2;
    if (c < need && c + h1 >= need) { res[0] = 4 * tid + 1; res[1] = (int)c; }
    c += h1;
    if (c < need && c + h0 >= need) { res[0] = 4 * tid + 0; res[1] = (int)c; }
  }
  __syncthreads();
  int t1 = res[0], a1 = res[1];
  __syncthreads();

  // ---------- phase 2: middle-12 bits within bin t1 ----------
  for (int i = tid; i < 4096; i += 1024) hist[i] = 0;
  __syncthreads();
  for (int i = tid; i < NANCH; i += 1024) {
    unsigned int m = mono_of(sc[i]);
    if ((int)(m >> 20) == t1) atomicAdd(&hist[(m >> 8) & 0xFFF], 1u);
  }
  __syncthreads();
  {
    unsigned int h0 = hist[4 * tid], h1 = hist[4 * tid + 1];
    unsigned int h2 = hist[4 * tid + 2], h3 = hist[4 * tid + 3];
    unsigned int c = suffix_strict(h0 + h1 + h2 + h3, part, tid, lane, wv);
    const unsigned int need = (unsigned)(NPRE - a1);
    if (c < need && c + h3 >= need) { res[2] = 4 * tid + 3; res[3] = (int)c; }
    c += h3;
    if (c < need && c + h2 >= need) { res[2] = 4 * tid + 2; res[3] = (int)c; }
    c += h2;
    if (c < need && c + h1 >= need) { res[2] = 4 * tid + 1; res[3] = (int)c; }
    c += h1;
    if (c < need && c + h0 >= need) { res[2] = 4 * tid + 0; res[3] = (int)c; }
  }
  __syncthreads();
  int t2 = res[2], a2 = res[3];
  __syncthreads();

  // ---------- phase 3: low-8 bits within (t1,t2) ----------
  for (int i = tid; i < 256; i += 1024) hist[i] = 0;
  __syncthreads();
  unsigned int top24 = ((unsigned int)t1 << 12) | (unsigned int)t2;
  for (int i = tid; i < NANCH; i += 1024) {
    unsigned int m = mono_of(sc[i]);
    if ((m >> 8) == top24) atomicAdd(&hist[m & 0xFF], 1u);
  }
  __syncthreads();
  {
    unsigned int hb = (tid < 256) ? hist[tid] : 0;
    unsigned int c = suffix_strict(hb, part, tid, lane, wv);
    if (tid < 256) {
      const unsigned int need = (unsigned)(NPRE - a1 - a2);
      if (c < need && c + hb >= need) {
        res[4] = tid;
        res[6] = (int)(need - c);                         // ties_needed
        res[7] = (hb == need - c) ? NANCH : -1;           // idx_cut or TBD
      }
    }
  }
  __syncthreads();
  int t3 = res[4];
  unsigned int T = (top24 << 8) | (unsigned int)t3;
  int ties_needed = res[6];
  int idx_cut = res[7];
  __syncthreads();

  // ---------- phase 4 (rare): tie resolution by smallest index ----------
  if (idx_cut < 0) {
    for (int i = tid; i < 704; i += 1024) hist[i] = 0;
    __syncthreads();
    for (int i = tid; i < NANCH; i += 1024)
      if (mono_of(sc[i]) == T) atomicAdd(&hist[i >> 5], 1u);
    __syncthreads();
    if (tid == 0) {
      int c = 0, cut = NANCH;
      for (int bin = 0; bin < 704; ++bin) {
        int hc = (int)hist[bin];
        if (c + hc >= ties_needed) {
          int c2 = c;
          for (int idx = bin * 32; idx < bin * 32 + 32; ++idx) {
            if (idx < NANCH && mono_of(sc[idx]) == T) {
              ++c2;
              if (c2 == ties_needed) { cut = idx; break; }
            }
          }
          break;
        }
        c += hc;
      }
      res[7] = cut;
    }
    __syncthreads();
    idx_cut = res[7];
    __syncthreads();
  }

  // ---------- phase 5: deterministic idx-order compact (blocked ranges + scan) ----------
  int base0 = tid * 22;  // 1024*22 = 22528 >= NANCH
  unsigned int selm = 0;
  int cnt = 0;
  for (int k = 0; k < 22; ++k) {
    int i = base0 + k;
    if (i < NANCH) {
      unsigned int m = mono_of(sc[i]);
      if (m > T || (m == T && i <= idx_cut)) { selm |= 1u << k; ++cnt; }
    }
  }
  {
    int inc = cnt;
#pragma unroll
    for (int d = 1; d < 64; d <<= 1) {
      int u = __shfl_up(inc, d, 64);
      if (lane >= d) inc += u;
    }
    if (lane == 63) part[wv] = (unsigned int)inc;
    __syncthreads();
    if (tid < 16) {
      int v = (int)part[tid];
      int inc2 = v;
#pragma unroll
      for (int d = 1; d < 16; d <<= 1) {
        int u = __shfl_up(inc2, d, 16);
        if (tid >= d) inc2 += u;
      }
      part[tid] = (unsigned int)(inc2 - v);  // exclusive wave base
    }
    __syncthreads();
    int pos = (int)part[wv] + (inc - cnt);
    for (int k = 0; k < 22; ++k)
      if ((selm >> k) & 1u) pidA[pos++] = (unsigned short)(base0 + k);
  }
  __syncthreads();

  // ---------- phase 6: 6-pass 6-bit stable LSD radix, key = ~mono (asc) ----------
  unsigned short* src = pidA;
  unsigned short* dst = pidB;
  for (int pass = 0; pass < 6; ++pass) {
    int shift = pass * 6;
    for (int i = tid; i < 6144; i += 1024) table[i] = 0;
    __syncthreads();
    int dig[6], irk[6], pidr[6];
#pragma unroll
    for (int k = 0; k < 6; ++k) {
      dig[k] = 0; irk[k] = 0; pidr[k] = 0;
      int s = wv + 16 * k;          // wave-uniform
      if (s < NSLOT) {
        int e = s * 64 + lane;
        bool act = e < NPRE;
        int pid = act ? (int)src[e] : 0;
        unsigned int key = act ? ~mono_of(sc[pid]) : 0u;
        int d = (int)((key >> shift) & 63u);
        uint64_t peers = __ballot(act);
#pragma unroll
        for (int bb = 0; bb < 6; ++bb) {
          uint64_t bl = __ballot(((d >> bb) & 1) != 0);
          peers &= ((d >> bb) & 1) ? bl : ~bl;
        }
        if (act) {
          dig[k] = d;
          pidr[k] = pid;
          irk[k] = (int)__popcll(peers & ((1ull << lane) - 1ull));
          int leader = __ffsll((long long)peers) - 1;
          if (lane == leader)
            table[d * NSLOT + s] = (unsigned short)__popcll(peers);
        }
      }
    }
    __syncthreads();
    // exclusive scan over table[0..6143] (digit-major, slot-minor)
    {
      int t6 = tid * 6;
      int v0 = table[t6], v1 = table[t6 + 1], v2 = table[t6 + 2];
      int v3 = table[t6 + 3], v4 = table[t6 + 4], v5 = table[t6 + 5];
      int lsum = v0 + v1 + v2 + v3 + v4 + v5;
      int inc = lsum;
#pragma unroll
      for (int d = 1; d < 64; d <<= 1) {
        int u = __shfl_up(inc, d, 64);
        if (lane >= d) inc += u;
      }
      if (lane == 63) part[wv] = (unsigned int)inc;
      __syncthreads();
      if (tid < 16) {
        int v = (int)part[tid];
        int inc2 = v;
#pragma unroll
        for (int d = 1; d < 16; d <<= 1) {
          int u = __shfl_up(inc2, d, 16);
          if (tid >= d) inc2 += u;
        }
        part[tid] = (unsigned int)(inc2 - v);
      }
      __syncthreads();
      int run = (int)part[wv] + (inc - lsum);
      table[t6] = (unsigned short)run; run += v0;
      table[t6 + 1] = (unsigned short)run; run += v1;
      table[t6 + 2] = (unsigned short)run; run += v2;
      table[t6 + 3] = (unsigned short)run; run += v3;
      table[t6 + 4] = (unsigned short)run; run += v4;
      table[t6 + 5] = (unsigned short)run;
    }
    __syncthreads();
    // scatter (stable): pos = base(digit,slot) + intra-slot rank
#pragma unroll
    for (int k = 0; k < 6; ++k) {
      int s = wv + 16 * k;
      if (s < NSLOT) {
        int e = s * 64 + lane;
        if (e < NPRE) {
          int pos = (int)table[dig[k] * NSLOT + s] + irk[k];
          dst[pos] = (unsigned short)pidr[k];
        }
      }
    }
    __syncthreads();
    unsigned short* tmp = src; src = dst; dst = tmp;
  }
  // 6 passes -> result back in pidA (== src)

  // ---------- phase 7: gather sorted scores/boxes ----------
  for (int r = tid; r < NPRE; r += 1024) {
    int idx = (int)src[r];
    sscore[(size_t)b * NPRE + r] = sc[idx];
    sbox[(size_t)b * NPRE + r] = boxes[(size_t)b * NANCH + idx];
  }
}

// ---------------- IoU suppression bitmask (shared body) ----------------
__device__ __forceinline__ void iou_tile(const float4* __restrict__ sbox,
                                         uint64_t* __restrict__ M,
                                         int b, int it, int jt, int tid,
                                         float4* bi, float4* bj) {
  if (tid < 64) {
    int i = it * 64 + tid;
    bi[tid] = (i < NPRE) ? sbox[(size_t)b * NPRE + i] : make_float4(0, 0, 0, 0);
  }
  {
    int j = jt * 256 + tid;
    bj[tid] = (j < NPRE) ? sbox[(size_t)b * NPRE + j] : make_float4(0, 0, 0, 0);
  }
  __syncthreads();
  int li = tid & 63, wq = tid >> 6;
  int i = it * 64 + li;
  int w = jt * 4 + wq;
  if (i < NPRE && w < NW) {
    float4 A = bi[li];
    float areaA = (A.z - A.x) * (A.w - A.y);
    uint64_t bits = 0;
#pragma unroll 8
    for (int jj = 0; jj < 64; ++jj) {
      int j = w * 64 + jj;
      float4 Bx = bj[wq * 64 + jj];
      float ix1 = fmaxf(A.x, Bx.x), iy1 = fmaxf(A.y, Bx.y);
      float ix2 = fminf(A.z, Bx.z), iy2 = fminf(A.w, Bx.w);
      float inter = fmaxf(ix2 - ix1, 0.f) * fmaxf(iy2 - iy1, 0.f);
      float areaB = (Bx.z - Bx.x) * (Bx.w - Bx.y);
      float iou = inter / (areaA + areaB - inter);
      if ((j > i) && (j < NPRE) && (iou > 0.7f)) bits |= (1ull << jj);
    }
    M[((size_t)b * NPRE + i) * NW + w] = bits;
  }
}

// restricted: rows < CMAX*64 only (full 94-word width -> sup state stays complete)
__global__ __launch_bounds__(256) void iou_mat(const float4* __restrict__ sbox,
                                               uint64_t* __restrict__ M) {
  __shared__ float4 bi[64];
  __shared__ float4 bj[256];
  iou_tile(sbox, M, blockIdx.z, blockIdx.x, blockIdx.y, threadIdx.x, bi, bj);
}

// fallback: rows >= CMAX*64; no-op when NMS finished within CMAX chunks
__global__ __launch_bounds__(256) void iou_rest(const float4* __restrict__ sbox,
                                                uint64_t* __restrict__ M,
                                                const unsigned int* __restrict__ state) {
  if (state[blockIdx.z * 192 + 189]) return;  // done
  __shared__ float4 bi[64];
  __shared__ float4 bj[256];
  iou_tile(sbox, M, blockIdx.z, blockIdx.x + CMAX, blockIdx.y, threadIdx.x, bi, bj);
}

// ---------------- NMS scan: wave0 serial closure + block-parallel OR + early exit ----------------
__device__ inline uint64_t shfl64(uint64_t v, int src) {
  int lo = __shfl((int)(unsigned int)(v & 0xFFFFFFFFull), src, 64);
  int hi = __shfl((int)(unsigned int)(v >> 32), src, 64);
  return ((uint64_t)(unsigned int)hi << 32) | (unsigned int)lo;
}

// one NMS chunk step
__device__ __forceinline__ void nms_chunk(const uint64_t* __restrict__ Mb,
                                          const float* __restrict__ sscore,
                                          uint64_t* __restrict__ keep,
                                          int b, int c, int tid,
                                          unsigned int* supLo, unsigned int* supHi,
                                          int* klist, int* knS, int* countS) {
  int ibase = c * 64;
  if (tid < 64) {
    int lane = tid;
    if (lane == 0) *knS = 0;
    uint64_t supc = ((uint64_t)supHi[c] << 32) | supLo[c];
    uint64_t validm = (c == NW - 1) ? ((1ull << (NPRE - (NW - 1) * 64)) - 1ull) : ~0ull;
    int pos = ibase + lane;
    uint64_t myrow = (pos < NPRE) ? Mb[(size_t)pos * NW + c] : 0ull;
    bool sval = (pos < NPRE) && (sscore[(size_t)b * NPRE + pos] >= 0.f);
    uint64_t vb = __ballot(sval);
    uint64_t cur = validm & ~supc;
    uint64_t kept = 0;
    while (cur) {
      int i = __ffsll((long long)cur) - 1;
      kept |= (1ull << i);
      cur &= ~(1ull << i);
      uint64_t row = shfl64(myrow, i);
      cur &= ~row;
    }
    if (kept & (1ull << lane)) {
      int pp = atomicAdd(knS, 1);
      klist[pp] = lane;
    }
    if (lane == 0) {
      keep[b * NW + c] = kept;
      *countS += __popcll(kept & vb);
    }
  }
  __syncthreads();  // [A] klist/knS/count visible; sup[c] consumed
  int kn = *knS;
  for (int t = tid; t < kn * 128; t += 1024) {
    int ii = t >> 7, w = t & 127;
    if (w > c && w < NW) {
      uint64_t row = Mb[(size_t)(ibase + klist[ii]) * NW + w];
      unsigned int lo = (unsigned int)row;
      unsigned int hi = (unsigned int)(row >> 32);
      if (lo) atomicOr(&supLo[w], lo);
      if (hi) atomicOr(&supHi[w], hi);
    }
  }
  __syncthreads();  // [B] sup updated before next chunk's closure
}

// phase A: chunks 0..CMAX; persists (sup, count, done) for the gated fallback
__global__ __launch_bounds__(1024) void nms_scan(const uint64_t* __restrict__ M,
                                                 const float* __restrict__ sscore,
                                                 uint64_t* __restrict__ keep,
                                                 unsigned int* __restrict__ state) {
  __shared__ unsigned int supLo[NW], supHi[NW];
  __shared__ int klist[64];
  __shared__ int knS;
  __shared__ int countS;
  int b = blockIdx.x;
  int tid = threadIdx.x;
  const uint64_t* Mb = M + (size_t)b * NPRE * NW;

  for (int w = tid; w < NW; w += 1024) {
    supLo[w] = 0;
    supHi[w] = 0;
    keep[b * NW + w] = 0;  // early-exit / fallback leaves untouched chunks zeroed
  }
  if (tid == 0) countS = 0;
  __syncthreads();

  int done = 0;
  for (int c = 0; c < CMAX; ++c) {
    nms_chunk(Mb, sscore, keep, b, c, tid, supLo, supHi, klist, &knS, &countS);
    if (countS >= 300) { done = 1; break; }  // uniform: countS read post-barrier
  }
  __syncthreads();
  unsigned int* st = state + b * 192;
  for (int w = tid; w < NW; w += 1024) { st[w] = supLo[w]; st[94 + w] = supHi[w]; }
  if (tid == 0) { st[188] = (unsigned int)countS; st[189] = (unsigned int)done; }
}

// fallback: continues from chunk CMAX with complete sup state; no-op when done
__global__ __launch_bounds__(1024) void nms_rest(const uint64_t* __restrict__ M,
                                                 const float* __restrict__ sscore,
                                                 uint64_t* __restrict__ keep,
                                                 const unsigned int* __restrict__ state) {
  int b = blockIdx.x;
  const unsigned int* st = state + b * 192;
  if (st[189]) return;  // done — uniform
  __shared__ unsigned int supLo[NW], supHi[NW];
  __shared__ int klist[64];
  __shared__ int knS;
  __shared__ int countS;
  int tid = threadIdx.x;
  const uint64_t* Mb = M + (size_t)b * NPRE * NW;
  for (int w = tid; w < NW; w += 1024) { supLo[w] = st[w]; supHi[w] = st[94 + w]; }
  if (tid == 0) countS = (int)st[188];
  __syncthreads();
  for (int c = CMAX; c < NW; ++c) {
    nms_chunk(Mb, sscore, keep, b, c, tid, supLo, supHi, klist, &knS, &countS);
    if (countS >= 300) break;
  }
}

// ---------------- emit top-300 ----------------
__global__ __launch_bounds__(128) void emit(const uint64_t* __restrict__ keep,
                                            const float* __restrict__ sscore,
                                            const float4* __restrict__ sbox,
                                            float* __restrict__ out) {
  __shared__ int cnt[128];
  __shared__ uint64_t fw[NW];
  int b = blockIdx.x;
  int tid = threadIdx.x;
  for (int i = tid; i < 1200; i += 128) out[b * 1200 + i] = 0.f;
  for (int i = tid; i < 300; i += 128) {
    out[2400 + b * 300 + i] = 0.f;
    out[3000 + b * 300 + i] = 0.f;
  }
  uint64_t w = 0;
  if (tid < NW) {
    uint64_t kw = keep[b * NW + tid];
    while (kw) {
      int j = __ffsll((long long)kw) - 1;
      kw &= kw - 1;
      if (sscore[(size_t)b * NPRE + tid * 64 + j] >= 0.f) w |= (1ull << j);
    }
    fw[tid] = w;
  }
  cnt[tid] = (tid < NW) ? __popcll(w) : 0;
  __syncthreads();
  for (int off = 1; off < 128; off <<= 1) {
    int v = cnt[tid];
    int u = (tid >= off) ? cnt[tid - off] : 0;
    __syncthreads();
    cnt[tid] = v + u;
    __syncthreads();
  }
  if (tid < NW) {
    int base = cnt[tid] - __popcll(fw[tid]);
    uint64_t ww = fw[tid];
    while (ww) {
      int j = __ffsll((long long)ww) - 1;
      ww &= ww - 1;
      if (base < 300) {
        int p = tid * 64 + j;
        float4 bx = sbox[(size_t)b * NPRE + p];
        float* ob = out + b * 1200 + base * 4;
        ob[0] = bx.x; ob[1] = bx.y; ob[2] = bx.z; ob[3] = bx.w;
        out[2400 + b * 300 + base] = sscore[(size_t)b * NPRE + p];
        out[3000 + b * 300 + base] = 1.0f;
      }
      ++base;
    }
  }
}

// ---------------- launch ----------------
extern "C" void kernel_launch(void* const* d_in, const int* in_sizes, int n_in,
                              void* d_out, int out_size, void* d_ws, size_t ws_size,
                              hipStream_t stream) {
  const float* x       = (const float*)d_in[0];
  const float* conv1_w = (const float*)d_in[1];
  const float* conv1_b = (const float*)d_in[2];
  const float* obj_w   = (const float*)d_in[3];
  const float* obj_b   = (const float*)d_in[4];
  const float* loc_w   = (const float*)d_in[5];
  const float* loc_b   = (const float*)d_in[6];
  const float* anch    = (const float*)d_in[7];
  const int*   img_h   = (const int*)d_in[8];
  const int*   img_w   = (const int*)d_in[9];

  char* base = (char*)d_ws;
  float*        wt     = (float*)(base + 0);            // 2304*512*4 = 4,718,592
  float*        h      = (float*)(base + 4718592);      // 2*2500*512*4 = 10,240,000
  uint64_t*     M      = (uint64_t*)(base + 4718592);   // alias h (9,024,000 <= 10,240,000)
  float*        scores = (float*)(base + 14958592);     // 180,000
  float4*       boxes  = (float4*)(base + 15138592);    // 720,000
  float*        sscore = (float*)(base + 15858592);     // 48,000
  float4*       sbox   = (float4*)(base + 15906592);    // 192,000
  uint64_t*     keep   = (uint64_t*)(base + 16098592);  // 1,504
  float*        xp     = (float*)(base + 16100096);     // 5,537,792
  unsigned int* state  = (unsigned int*)(base + 21637888);  // 1,536
  // wt54b (131,072 B) ALIASES sbox: written by prep, read only by heads,
  // overwritten by topk_sort phase 7 afterwards (stream-ordered safe).
  float*        wt54b  = (float*)(base + 15906592);

  hipLaunchKernelGGL(prep, dim3(6668), dim3(256), 0, stream,
                     conv1_w, wt, x, xp, obj_w, loc_w, wt54b);
  hipLaunchKernelGGL(conv1_gemm, dim3(40, 8, 2), dim3(256), 0, stream, xp, wt, conv1_b, h);
  hipLaunchKernelGGL(heads, dim3(1250), dim3(64), 0, stream, h, wt54b, obj_b, loc_b,
                     anch, img_h, img_w, scores, boxes);
  hipLaunchKernelGGL(topk_sort, dim3(2), dim3(1024), 0, stream, scores, boxes, sscore, sbox);
  hipLaunchKernelGGL(iou_mat, dim3(CMAX, 24, 2), dim3(256), 0, stream, sbox, M);
  hipLaunchKernelGGL(nms_scan, dim3(2), dim3(1024), 0, stream, M, sscore, keep, state);
  hipLaunchKernelGGL(iou_rest, dim3(NW - CMAX, 24, 2), dim3(256), 0, stream, sbox, M, state);
  hipLaunchKernelGGL(nms_rest, dim3(2), dim3(1024), 0, stream, M, sscore, keep, state);
  hipLaunchKernelGGL(emit, dim3(2), dim3(128), 0, stream, keep, sscore, sbox, (float*)d_out);
}

// Round 14
// 425.160 us; speedup vs baseline: 1.3319x; 1.0493x over previous
//
#include <hip/hip_runtime.h>
#include <stdint.h>

// ---------------- constants ----------------
#define NPOS 2500      // 50*50
#define NANCH 22500    // NPOS*9
#define NPRE 6000
#define NW 94          // ceil(6000/64)
#define XPAD 2704      // 52*52 padded plane
#define NSLOT 94       // ceil(NPRE/64) radix slots
#define CMAX 32        // restricted NMS chunk budget (2048 candidates)

// async global->LDS DMA (gfx950). dst is wave-uniform base + lane*size.
__device__ __forceinline__ void gl_lds4(const float* g, float* l) {
  __builtin_amdgcn_global_load_lds((const __attribute__((address_space(1))) void*)g,
                                   (__attribute__((address_space(3))) void*)l, 4, 0, 0);
}
__device__ __forceinline__ void gl_lds16(const float* g, float* l) {
  __builtin_amdgcn_global_load_lds((const __attribute__((address_space(1))) void*)g,
                                   (__attribute__((address_space(3))) void*)l, 16, 0, 0);
}

// ---------------- fused prep: weight transpose + x pad + head-weight transpose ----------------
__global__ __launch_bounds__(256) void prep(const float* __restrict__ w,
                                            float* __restrict__ wt,
                                            const float* __restrict__ x,
                                            float* __restrict__ xp,
                                            const float* __restrict__ objw,
                                            const float* __restrict__ locw,
                                            float* __restrict__ wt54b) {
  __shared__ float tile[32][33];
  int bid = blockIdx.x;
  int tid = threadIdx.x;
  if (bid < 1152) {
    // ---- role A: conv weight transpose ----
    int k0 = (bid % 72) * 32;   // k' = ic*9 + tap
    int o0 = (bid / 72) * 32;
    int tx = tid & 31;
    int ty = tid >> 5;  // 0..7
#pragma unroll
    for (int i = 0; i < 4; ++i) {
      int oc = o0 + ty + i * 8;
      int kp = k0 + tx;
      tile[ty + i * 8][tx] = w[(size_t)oc * 2304 + kp];
    }
    __syncthreads();
#pragma unroll
    for (int i = 0; i < 4; ++i) {
      int kp = k0 + ty + i * 8;
      int ic = kp / 9, tap = kp % 9;
      wt[((size_t)tap * 256 + ic) * 512 + (o0 + tx)] = tile[tx][ty + i * 8];
    }
  } else if (bid < 6560) {
    // ---- role B: zero-pad x ----
    int t = (bid - 1152) * 256 + tid;
    if (t < 2 * 256 * XPAD) {
      int c = t / XPAD;        // b*256 + ic
      int r = t % XPAD;
      int yy = r / 52, xx = r % 52;
      float v = 0.f;
      if (yy >= 1 && yy <= 50 && xx >= 1 && xx <= 50)
        v = x[(size_t)c * NPOS + (yy - 1) * 50 + (xx - 1)];
      xp[t] = v;
    }
  } else {
    // ---- role C: head-weight transpose to [k/4][oc][4] ----
    int t = (bid - 6560) * 256 + tid;
    if (t < 54 * 512) {
      int oc = t / 512, k = t % 512;
      float v = (oc < 18) ? objw[(size_t)oc * 512 + k] : locw[(size_t)(oc - 18) * 512 + k];
      wt54b[((size_t)(k >> 2) * 64 + oc) * 4 + (k & 3)] = v;
    }
  }
}

// ---------------- conv1 3x3 SAME + bias + relu, output NHWC h[b][p][oc] ----------------
// EXACT R7 version (199-203us, best of R2..R10). LDS-read-instruction bound.
// All restructurings lose (R3/R4/R8/R9/R10). Do not touch.
__global__ __launch_bounds__(256) void conv1_gemm(const float* __restrict__ xp,
                                                  const float* __restrict__ wt,
                                                  const float* __restrict__ bias,
                                                  float* __restrict__ h) {
  __shared__ __align__(16) float As[32][64];
  __shared__ __align__(16) float Bs[32][64];
  int b = blockIdx.z;
  int m0 = blockIdx.x * 64;
  int oc0 = blockIdx.y * 64;
  int tid = threadIdx.x;
  int lane = tid & 63;
  int wv = tid >> 6;       // wave 0..3
  int tn = tid & 15, tm = tid >> 4;
  float acc[4][4] = {};

  int p = m0 + lane;
  int pc = p < NPOS ? p : (NPOS - 1);
  int py = pc / 50, px = pc % 50;
  const float* gA0 = xp + (size_t)b * 256 * XPAD + py * 52 + px + 53;
  int brow = lane >> 4, bcol4 = (lane & 15) * 4;

  for (int tap = 0; tap < 9; ++tap) {
    int ky = tap / 3 - 1, kx = tap % 3 - 1;
    int koff = ky * 52 + kx;
    for (int icc = 0; icc < 8; ++icc) {
      int ic0 = icc * 32;
      __syncthreads();  // LDS consumed by previous chunk's compute
#pragma unroll
      for (int j = 0; j < 8; ++j) {
        int kk = wv * 8 + j;
        gl_lds4(gA0 + (size_t)(ic0 + kk) * XPAD + koff, &As[kk][0]);
      }
#pragma unroll
      for (int q = 0; q < 2; ++q) {
        int r0 = wv * 8 + q * 4;
        gl_lds16(wt + ((size_t)tap * 256 + ic0 + r0 + brow) * 512 + oc0 + bcol4,
                 &Bs[r0][0]);
      }
      __syncthreads();  // drains vmcnt -> DMAs complete
#pragma unroll
      for (int kk = 0; kk < 32; ++kk) {
        float4 av = *(const float4*)&As[kk][tm * 4];
        float4 bv = *(const float4*)&Bs[kk][tn * 4];
        float am[4] = {av.x, av.y, av.z, av.w};
        float bn[4] = {bv.x, bv.y, bv.z, bv.w};
#pragma unroll
        for (int i = 0; i < 4; ++i)
#pragma unroll
          for (int j = 0; j < 4; ++j) acc[i][j] = fmaf(am[i], bn[j], acc[i][j]);
      }
    }
  }
#pragma unroll
  for (int i = 0; i < 4; ++i) {
    int pp = m0 + tm * 4 + i;
    if (pp < NPOS) {
      float4 v;
      float* vp = (float*)&v;
#pragma unroll
      for (int j = 0; j < 4; ++j) {
        int oc = oc0 + tn * 4 + j;
        vp[j] = fmaxf(acc[i][j] + bias[oc], 0.f);
      }
      *(float4*)&h[((size_t)b * NPOS + pp) * 512 + oc0 + tn * 4] = v;
    }
  }
}

// ---------------- heads: 4 positions per wave (weight reads amortized 4x) ----------------
__global__ __launch_bounds__(64) void heads(const float* __restrict__ h,
                                            const float* __restrict__ wt54b,
                                            const float* __restrict__ objb,
                                            const float* __restrict__ locb,
                                            const float* __restrict__ anch,
                                            const int* __restrict__ imgh,
                                            const int* __restrict__ imgw,
                                            float* __restrict__ scores,
                                            float4* __restrict__ boxes) {
  __shared__ float hv[4 * 512];
  __shared__ float outs[4][64];
  int blk = blockIdx.x;             // 0..1249
  int b = blk / 625;
  int p0 = (blk % 625) * 4;         // 4 consecutive positions
  int lane = threadIdx.x;
  const float4* hp4 = (const float4*)(h + ((size_t)b * NPOS + p0) * 512);
  float4* hv4 = (float4*)hv;
#pragma unroll
  for (int q = 0; q < 8; ++q) hv4[lane + 64 * q] = hp4[lane + 64 * q];
  __syncthreads();
  if (lane < 54) {
    float bias0 = (lane < 18) ? objb[lane] : locb[lane - 18];
    float a0 = bias0, a1 = bias0, a2 = bias0, a3 = bias0;
    const float4* w4 = (const float4*)wt54b;
#pragma unroll 4
    for (int k = 0; k < 128; ++k) {
      float4 wv = w4[k * 64 + lane];
      float4 h0 = hv4[k], h1 = hv4[128 + k], h2 = hv4[256 + k], h3 = hv4[384 + k];
      a0 = fmaf(wv.x, h0.x, a0); a0 = fmaf(wv.y, h0.y, a0);
      a0 = fmaf(wv.z, h0.z, a0); a0 = fmaf(wv.w, h0.w, a0);
      a1 = fmaf(wv.x, h1.x, a1); a1 = fmaf(wv.y, h1.y, a1);
      a1 = fmaf(wv.z, h1.z, a1); a1 = fmaf(wv.w, h1.w, a1);
      a2 = fmaf(wv.x, h2.x, a2); a2 = fmaf(wv.y, h2.y, a2);
      a2 = fmaf(wv.z, h2.z, a2); a2 = fmaf(wv.w, h2.w, a2);
      a3 = fmaf(wv.x, h3.x, a3); a3 = fmaf(wv.y, h3.y, a3);
      a3 = fmaf(wv.z, h3.z, a3); a3 = fmaf(wv.w, h3.w, a3);
    }
    outs[0][lane] = a0; outs[1][lane] = a1; outs[2][lane] = a2; outs[3][lane] = a3;
  }
  __syncthreads();
  if (lane < 36) {
    int pi = lane / 9, a = lane % 9;
    int p = p0 + pi;
    float l0 = outs[pi][2 * a], l1 = outs[pi][2 * a + 1];
    float mx = fmaxf(l0, l1);
    float e0 = expf(l0 - mx);
    float e1 = expf(l1 - mx);
    float s = e1 / (e0 + e1);
    float d0 = outs[pi][18 + 4 * a + 0];
    float d1 = outs[pi][18 + 4 * a + 1];
    float d2 = outs[pi][18 + 4 * a + 2];
    float d3 = outs[pi][18 + 4 * a + 3];
    int ai = p * 9 + a;
    float4 A = ((const float4*)anch)[ai];
    float aw = A.z - A.x, ah = A.w - A.y;
    float acx = A.x + 0.5f * aw, acy = A.y + 0.5f * ah;
    float cx = acx + d0 * aw, cy = acy + d1 * ah;
    float w = aw * expf(d2), hh = ah * expf(d3);
    float W = (float)imgw[0], H = (float)imgh[0];
    float x1 = fminf(fmaxf(cx - 0.5f * w, 0.f), W);
    float y1 = fminf(fmaxf(cy - 0.5f * hh, 0.f), H);
    float x2 = fminf(fmaxf(cx + 0.5f * w, 0.f), W);
    float y2 = fminf(fmaxf(cy + 0.5f * hh, 0.f), H);
    bool valid = (x2 - x1 >= 16.f) && (y2 - y1 >= 16.f);
    scores[(size_t)b * NANCH + ai] = valid ? s : -1.f;
    boxes[(size_t)b * NANCH + ai] = make_float4(x1, y1, x2, y2);
  }
}

// ---------------- top-6000 select + stable radix sort (one block per batch) ----------------
__device__ inline unsigned int mono_of(float f) {
  unsigned int u = __float_as_uint(f);
  return (u & 0x80000000u) ? ~u : (u | 0x80000000u);
}

// strict suffix sum over 1024 per-thread values (2 barriers)
__device__ __forceinline__ unsigned int suffix_strict(unsigned int v,
                                                      unsigned int* partw,
                                                      int tid, int lane, int wv) {
  unsigned int inc = v;
#pragma unroll
  for (int d = 1; d < 64; d <<= 1) {
    unsigned int u = __shfl_down(inc, d, 64);
    if (lane + d < 64) inc += u;
  }
  if (lane == 0) partw[wv] = inc;  // wave total
  __syncthreads();
  if (tid < 16) {
    unsigned int tot = partw[tid];
    unsigned int inc2 = tot;
#pragma unroll
    for (int d = 1; d < 16; d <<= 1) {
      unsigned int u = __shfl_down(inc2, d, 64);
      if (tid + d < 16) inc2 += u;
    }
    partw[tid] = inc2 - tot;  // strict suffix of later waves
  }
  __syncthreads();
  return partw[wv] + (inc - v);
}

// R6 lesson: wave-aggregated hist_add REGRESSED. Plain atomics kept.
// R7: 6-pass 6-bit stable LSD radix (268 -> ~84us).
__global__ __launch_bounds__(1024) void topk_sort(const float* __restrict__ scores,
                                                  const float4* __restrict__ boxes,
                                                  float* __restrict__ sscore,
                                                  float4* __restrict__ sbox) {
  int b = blockIdx.x;
  const float* sc = scores + (size_t)b * NANCH;
  __shared__ unsigned int hist[4096];
  __shared__ unsigned int part[1024];
  __shared__ unsigned short pidA[6016];
  __shared__ unsigned short pidB[6016];
  __shared__ unsigned short table[6144];   // 64 digits x 94 slots (padded)
  __shared__ int res[8];
  int tid = threadIdx.x;
  int lane = tid & 63;
  int wv = tid >> 6;

  // ---------- phase 1: top-12-bit histogram ----------
  for (int i = tid; i < 4096; i += 1024) hist[i] = 0;
  __syncthreads();
  for (int i = tid; i < NANCH; i += 1024) atomicAdd(&hist[mono_of(sc[i]) >> 20], 1u);
  __syncthreads();
  {
    unsigned int h0 = hist[4 * tid], h1 = hist[4 * tid + 1];
    unsigned int h2 = hist[4 * tid + 2], h3 = hist[4 * tid + 3];
    unsigned int c = suffix_strict(h0 + h1 + h2 + h3, part, tid, lane, wv);
    const unsigned int need = NPRE;
    if (c < need && c + h3 >= need) { res[0] = 4 * tid + 3; res[1] = (int)c; }
    c += h3;
    if (c < need && c + h2 >= need) { res[0] = 4 * tid + 2; res[1] = (int)c; }
    c += h2;
    if (c < need && c + h1 >= need) { res[0] = 4 * tid + 1; res[1] = (int)c; }
    c += h1;
    if (c < need && c + h0 >= need) { res[0] = 4 * tid + 0; res[1] = (int)c; }
  }
  __syncthreads();
  int t1 = res[0], a1 = res[1];
  __syncthreads();

  // ---------- phase 2: middle-12 bits within bin t1 ----------
  for (int i = tid; i < 4096; i += 1024) hist[i] = 0;
  __syncthreads();
  for (int i = tid; i < NANCH; i += 1024) {
    unsigned int m = mono_of(sc[i]);
    if ((int)(m >> 20) == t1) atomicAdd(&hist[(m >> 8) & 0xFFF], 1u);
  }
  __syncthreads();
  {
    unsigned int h0 = hist[4 * tid], h1 = hist[4 * tid + 1];
    unsigned int h2 = hist[4 * tid + 2], h3 = hist[4 * tid + 3];
    unsigned int c = suffix_strict(h0 + h1 + h2 + h3, part, tid, lane, wv);
    const unsigned int need = (unsigned)(NPRE - a1);
    if (c < need && c + h3 >= need) { res[2] = 4 * tid + 3; res[3] = (int)c; }
    c += h3;
    if (c < need && c + h2 >= need) { res[2] = 4 * tid + 2; res[3] = (int)c; }
    c += h2;
    if (c < need && c + h1 >= need) { res[2] = 4 * tid + 1; res[3] = (int)c; }
    c += h1;
    if (c < need && c + h0 >= need) { res[2] = 4 * tid + 0; res[3] = (int)c; }
  }
  __syncthreads();
  int t2 = res[2], a2 = res[3];
  __syncthreads();

  // ---------- phase 3: low-8 bits within (t1,t2) ----------
  for (int i = tid; i < 256; i += 1024) hist[i] = 0;
  __syncthreads();
  unsigned int top24 = ((unsigned int)t1 << 12) | (unsigned int)t2;
  for (int i = tid; i < NANCH; i += 1024) {
    unsigned int m = mono_of(sc[i]);
    if ((m >> 8) == top24) atomicAdd(&hist[m & 0xFF], 1u);
  }
  __syncthreads();
  {
    unsigned int hb = (tid < 256) ? hist[tid] : 0;
    unsigned int c = suffix_strict(hb, part, tid, lane, wv);
    if (tid < 256) {
      const unsigned int need = (unsigned)(NPRE - a1 - a2);
      if (c < need && c + hb >= need) {
        res[4] = tid;
        res[6] = (int)(need - c);                         // ties_needed
        res[7] = (hb == need - c) ? NANCH : -1;           // idx_cut or TBD
      }
    }
  }
  __syncthreads();
  int t3 = res[4];
  unsigned int T = (top24 << 8) | (unsigned int)t3;
  int ties_needed = res[6];
  int idx_cut = res[7];
  __syncthreads();

  // ---------- phase 4 (rare): tie resolution by smallest index ----------
  if (idx_cut < 0) {
    for (int i = tid; i < 704; i += 1024) hist[i] = 0;
    __syncthreads();
    for (int i = tid; i < NANCH; i += 1024)
      if (mono_of(sc[i]) == T) atomicAdd(&hist[i >> 5], 1u);
    __syncthreads();
    if (tid == 0) {
      int c = 0, cut = NANCH;
      for (int bin = 0; bin < 704; ++bin) {
        int hc = (int)hist[bin];
        if (c + hc >= ties_needed) {
          int c2 = c;
          for (int idx = bin * 32; idx < bin * 32 + 32; ++idx) {
            if (idx < NANCH && mono_of(sc[idx]) == T) {
              ++c2;
              if (c2 == ties_needed) { cut = idx; break; }
            }
          }
          break;
        }
        c += hc;
      }
      res[7] = cut;
    }
    __syncthreads();
    idx_cut = res[7];
    __syncthreads();
  }

  // ---------- phase 5: deterministic idx-order compact (blocked ranges + scan) ----------
  int base0 = tid * 22;  // 1024*22 = 22528 >= NANCH
  unsigned int selm = 0;
  int cnt = 0;
  for (int k = 0; k < 22; ++k) {
    int i = base0 + k;
    if (i < NANCH) {
      unsigned int m = mono_of(sc[i]);
      if (m > T || (m == T && i <= idx_cut)) { selm |= 1u << k; ++cnt; }
    }
  }
  {
    int inc = cnt;
#pragma unroll
    for (int d = 1; d < 64; d <<= 1) {
      int u = __shfl_up(inc, d, 64);
      if (lane >= d) inc += u;
    }
    if (lane == 63) part[wv] = (unsigned int)inc;
    __syncthreads();
    if (tid < 16) {
      int v = (int)part[tid];
      int inc2 = v;
#pragma unroll
      for (int d = 1; d < 16; d <<= 1) {
        int u = __shfl_up(inc2, d, 16);
        if (tid >= d) inc2 += u;
      }
      part[tid] = (unsigned int)(inc2 - v);  // exclusive wave base
    }
    __syncthreads();
    int pos = (int)part[wv] + (inc - cnt);
    for (int k = 0; k < 22; ++k)
      if ((selm >> k) & 1u) pidA[pos++] = (unsigned short)(base0 + k);
  }
  __syncthreads();

  // ---------- phase 6: 6-pass 6-bit stable LSD radix, key = ~mono (asc) ----------
  unsigned short* src = pidA;
  unsigned short* dst = pidB;
  for (int pass = 0; pass < 6; ++pass) {
    int shift = pass * 6;
    for (int i = tid; i < 6144; i += 1024) table[i] = 0;
    __syncthreads();
    int dig[6], irk[6], pidr[6];
#pragma unroll
    for (int k = 0; k < 6; ++k) {
      dig[k] = 0; irk[k] = 0; pidr[k] = 0;
      int s = wv + 16 * k;          // wave-uniform
      if (s < NSLOT) {
        int e = s * 64 + lane;
        bool act = e < NPRE;
        int pid = act ? (int)src[e] : 0;
        unsigned int key = act ? ~mono_of(sc[pid]) : 0u;
        int d = (int)((key >> shift) & 63u);
        uint64_t peers = __ballot(act);
#pragma unroll
        for (int bb = 0; bb < 6; ++bb) {
          uint64_t bl = __ballot(((d >> bb) & 1) != 0);
          peers &= ((d >> bb) & 1) ? bl : ~bl;
        }
        if (act) {
          dig[k] = d;
          pidr[k] = pid;
          irk[k] = (int)__popcll(peers & ((1ull << lane) - 1ull));
          int leader = __ffsll((long long)peers) - 1;
          if (lane == leader)
            table[d * NSLOT + s] = (unsigned short)__popcll(peers);
        }
      }
    }
    __syncthreads();
    // exclusive scan over table[0..6143] (digit-major, slot-minor)
    {
      int t6 = tid * 6;
      int v0 = table[t6], v1 = table[t6 + 1], v2 = table[t6 + 2];
      int v3 = table[t6 + 3], v4 = table[t6 + 4], v5 = table[t6 + 5];
      int lsum = v0 + v1 + v2 + v3 + v4 + v5;
      int inc = lsum;
#pragma unroll
      for (int d = 1; d < 64; d <<= 1) {
        int u = __shfl_up(inc, d, 64);
        if (lane >= d) inc += u;
      }
      if (lane == 63) part[wv] = (unsigned int)inc;
      __syncthreads();
      if (tid < 16) {
        int v = (int)part[tid];
        int inc2 = v;
#pragma unroll
        for (int d = 1; d < 16; d <<= 1) {
          int u = __shfl_up(inc2, d, 16);
          if (tid >= d) inc2 += u;
        }
        part[tid] = (unsigned int)(inc2 - v);
      }
      __syncthreads();
      int run = (int)part[wv] + (inc - lsum);
      table[t6] = (unsigned short)run; run += v0;
      table[t6 + 1] = (unsigned short)run; run += v1;
      table[t6 + 2] = (unsigned short)run; run += v2;
      table[t6 + 3] = (unsigned short)run; run += v3;
      table[t6 + 4] = (unsigned short)run; run += v4;
      table[t6 + 5] = (unsigned short)run;
    }
    __syncthreads();
    // scatter (stable): pos = base(digit,slot) + intra-slot rank
#pragma unroll
    for (int k = 0; k < 6; ++k) {
      int s = wv + 16 * k;
      if (s < NSLOT) {
        int e = s * 64 + lane;
        if (e < NPRE) {
          int pos = (int)table[dig[k] * NSLOT + s] + irk[k];
          dst[pos] = (unsigned short)pidr[k];
        }
      }
    }
    __syncthreads();
    unsigned short* tmp = src; src = dst; dst = tmp;
  }
  // 6 passes -> result back in pidA (== src)

  // ---------- phase 7: gather sorted scores/boxes ----------
  for (int r = tid; r < NPRE; r += 1024) {
    int idx = (int)src[r];
    sscore[(size_t)b * NPRE + r] = sc[idx];
    sbox[(size_t)b * NPRE + r] = boxes[(size_t)b * NANCH + idx];
  }
}

// ---------------- IoU suppression bitmask (shared body) ----------------
__device__ __forceinline__ void iou_tile(const float4* __restrict__ sbox,
                                         uint64_t* __restrict__ M,
                                         int b, int it, int jt, int tid,
                                         float4* bi, float4* bj) {
  if (tid < 64) {
    int i = it * 64 + tid;
    bi[tid] = (i < NPRE) ? sbox[(size_t)b * NPRE + i] : make_float4(0, 0, 0, 0);
  }
  {
    int j = jt * 256 + tid;
    bj[tid] = (j < NPRE) ? sbox[(size_t)b * NPRE + j] : make_float4(0, 0, 0, 0);
  }
  __syncthreads();
  int li = tid & 63, wq = tid >> 6;
  int i = it * 64 + li;
  int w = jt * 4 + wq;
  if (i < NPRE && w < NW) {
    float4 A = bi[li];
    float areaA = (A.z - A.x) * (A.w - A.y);
    uint64_t bits = 0;
#pragma unroll 8
    for (int jj = 0; jj < 64; ++jj) {
      int j = w * 64 + jj;
      float4 Bx = bj[wq * 64 + jj];
      float ix1 = fmaxf(A.x, Bx.x), iy1 = fmaxf(A.y, Bx.y);
      float ix2 = fminf(A.z, Bx.z), iy2 = fminf(A.w, Bx.w);
      float inter = fmaxf(ix2 - ix1, 0.f) * fmaxf(iy2 - iy1, 0.f);
      float areaB = (Bx.z - Bx.x) * (Bx.w - Bx.y);
      float iou = inter / (areaA + areaB - inter);
      if ((j > i) && (j < NPRE) && (iou > 0.7f)) bits |= (1ull << jj);
    }
    M[((size_t)b * NPRE + i) * NW + w] = bits;
  }
}

// common path: rows < CMAX*64 AND columns w < CMAX (all the scan reads pre-done)
__global__ __launch_bounds__(256) void iou_mat(const float4* __restrict__ sbox,
                                               uint64_t* __restrict__ M) {
  __shared__ float4 bi[64];
  __shared__ float4 bj[256];
  iou_tile(sbox, M, blockIdx.z, blockIdx.x, blockIdx.y, threadIdx.x, bi, bj);
}

// fallback complement: (rows >= 2048, all cols) + (rows < 2048, cols >= 32)
__global__ __launch_bounds__(256) void iou_rest(const float4* __restrict__ sbox,
                                                uint64_t* __restrict__ M,
                                                const unsigned int* __restrict__ state) {
  if (state[blockIdx.z * 192 + 189]) return;  // done
  int it = blockIdx.x, jt = blockIdx.y;
  if (it < CMAX && jt < CMAX / 4) return;     // covered by iou_mat
  __shared__ float4 bi[64];
  __shared__ float4 bj[256];
  iou_tile(sbox, M, blockIdx.z, it, jt, threadIdx.x, bi, bj);
}

// ---------------- NMS scan: wave0 serial closure + block-parallel OR + early exit ----------------
__device__ inline uint64_t shfl64(uint64_t v, int src) {
  int lo = __shfl((int)(unsigned int)(v & 0xFFFFFFFFull), src, 64);
  int hi = __shfl((int)(unsigned int)(v >> 32), src, 64);
  return ((uint64_t)(unsigned int)hi << 32) | (unsigned int)lo;
}

// one NMS chunk step; OR restricted to w < wlimit
__device__ __forceinline__ void nms_chunk(const uint64_t* __restrict__ Mb,
                                          const float* __restrict__ sscore,
                                          uint64_t* __restrict__ keep,
                                          int b, int c, int tid, int wlimit,
                                          unsigned int* supLo, unsigned int* supHi,
                                          int* klist, int* knS, int* countS) {
  int ibase = c * 64;
  if (tid < 64) {
    int lane = tid;
    if (lane == 0) *knS = 0;
    uint64_t supc = ((uint64_t)supHi[c] << 32) | supLo[c];
    uint64_t validm = (c == NW - 1) ? ((1ull << (NPRE - (NW - 1) * 64)) - 1ull) : ~0ull;
    int pos = ibase + lane;
    uint64_t myrow = (pos < NPRE) ? Mb[(size_t)pos * NW + c] : 0ull;
    bool sval = (pos < NPRE) && (sscore[(size_t)b * NPRE + pos] >= 0.f);
    uint64_t vb = __ballot(sval);
    uint64_t cur = validm & ~supc;
    uint64_t kept = 0;
    while (cur) {
      int i = __ffsll((long long)cur) - 1;
      kept |= (1ull << i);
      cur &= ~(1ull << i);
      uint64_t row = shfl64(myrow, i);
      cur &= ~row;
    }
    if (kept & (1ull << lane)) {
      int pp = atomicAdd(knS, 1);
      klist[pp] = lane;
    }
    if (lane == 0) {
      keep[b * NW + c] = kept;
      *countS += __popcll(kept & vb);
    }
  }
  __syncthreads();  // [A] klist/knS/count visible; sup[c] consumed
  int kn = *knS;
  for (int t = tid; t < kn * 128; t += 1024) {
    int ii = t >> 7, w = t & 127;
    if (w > c && w < wlimit) {
      uint64_t row = Mb[(size_t)(ibase + klist[ii]) * NW + w];
      unsigned int lo = (unsigned int)row;
      unsigned int hi = (unsigned int)(row >> 32);
      if (lo) atomicOr(&supLo[w], lo);
      if (hi) atomicOr(&supHi[w], hi);
    }
  }
  __syncthreads();  // [B] sup updated before next chunk's closure
}

// phase A: chunks 0..CMAX, OR width limited to CMAX (words >= CMAX never read
// here; they remain 0 in saved state and are reconstructed by nms_finish).
__global__ __launch_bounds__(1024) void nms_scan(const uint64_t* __restrict__ M,
                                                 const float* __restrict__ sscore,
                                                 uint64_t* __restrict__ keep,
                                                 unsigned int* __restrict__ state) {
  __shared__ unsigned int supLo[NW], supHi[NW];
  __shared__ int klist[64];
  __shared__ int knS;
  __shared__ int countS;
  int b = blockIdx.x;
  int tid = threadIdx.x;
  const uint64_t* Mb = M + (size_t)b * NPRE * NW;

  for (int w = tid; w < NW; w += 1024) {
    supLo[w] = 0;
    supHi[w] = 0;
    keep[b * NW + w] = 0;  // early-exit / fallback leaves untouched chunks zeroed
  }
  if (tid == 0) countS = 0;
  __syncthreads();

  int done = 0;
  for (int c = 0; c < CMAX; ++c) {
    nms_chunk(Mb, sscore, keep, b, c, tid, CMAX, supLo, supHi, klist, &knS, &countS);
    if (countS >= 300) { done = 1; break; }  // uniform: countS read post-barrier
  }
  __syncthreads();
  unsigned int* st = state + b * 192;
  for (int w = tid; w < NW; w += 1024) { st[w] = supLo[w]; st[94 + w] = supHi[w]; }
  if (tid == 0) { st[188] = (unsigned int)countS; st[189] = (unsigned int)done; }
}

// fallback scan + emit, merged (R13: 9 launches x ~5us; -1 launch).
// Part 1 (only when !done): reconstruct sup[w>=CMAX] exactly by re-ORing kept
// rows (from keep[]) over M's high columns (computed by iou_rest), then continue
// chunks CMAX..NW full-width. Part 2: emit top-300 (always).
__global__ __launch_bounds__(1024) void nms_finish(const uint64_t* __restrict__ M,
                                                   const float* __restrict__ sscore,
                                                   uint64_t* __restrict__ keep,
                                                   const unsigned int* __restrict__ state,
                                                   const float4* __restrict__ sbox,
                                                   float* __restrict__ out) {
  __shared__ unsigned int supLo[NW], supHi[NW];
  __shared__ int klist[64];
  __shared__ int knS;
  __shared__ int countS;
  __shared__ int cnt[128];
  __shared__ uint64_t fw[NW];
  int b = blockIdx.x;
  int tid = threadIdx.x;
  const uint64_t* Mb = M + (size_t)b * NPRE * NW;
  const unsigned int* st = state + b * 192;

  if (!st[189]) {  // fallback path (uniform)
    for (int w = tid; w < NW; w += 1024) { supLo[w] = st[w]; supHi[w] = st[94 + w]; }
    if (tid == 0) countS = (int)st[188];
    __syncthreads();
    // reconstruct sup words >= CMAX from kept rows of chunks < CMAX
    for (int c = 0; c < CMAX; ++c) {
      uint64_t kw = keep[b * NW + c];
      if (!kw) continue;  // uniform (all threads read same global)
      int ibase = c * 64;
      const int WREST = NW - CMAX;  // 62
      for (int t = tid; t < 64 * WREST; t += 1024) {
        int j = t / WREST;
        int w = CMAX + (t % WREST);
        if ((kw >> j) & 1ull) {
          uint64_t row = Mb[(size_t)(ibase + j) * NW + w];
          unsigned int lo = (unsigned int)row;
          unsigned int hi = (unsigned int)(row >> 32);
          if (lo) atomicOr(&supLo[w], lo);
          if (hi) atomicOr(&supHi[w], hi);
        }
      }
    }
    __syncthreads();
    for (int c = CMAX; c < NW; ++c) {
      nms_chunk(Mb, sscore, keep, b, c, tid, NW, supLo, supHi, klist, &knS, &countS);
      if (countS >= 300) break;
    }
    __threadfence();  // keep[] writes visible to part 2 reads
    __syncthreads();
  }

  // ---- part 2: emit ----
  for (int i = tid; i < 1200; i += 1024) out[b * 1200 + i] = 0.f;
  for (int i = tid; i < 300; i += 1024) {
    out[2400 + b * 300 + i] = 0.f;
    out[3000 + b * 300 + i] = 0.f;
  }
  uint64_t w = 0;
  if (tid < NW) {
    uint64_t kw = keep[b * NW + tid];
    while (kw) {
      int j = __ffsll((long long)kw) - 1;
      kw &= kw - 1;
      if (sscore[(size_t)b * NPRE + tid * 64 + j] >= 0.f) w |= (1ull << j);
    }
    fw[tid] = w;
  }
  if (tid < 128) cnt[tid] = (tid < NW) ? __popcll(w) : 0;
  __syncthreads();
  for (int off = 1; off < 128; off <<= 1) {
    int v = 0, u = 0;
    if (tid < 128) {
      v = cnt[tid];
      u = (tid >= off) ? cnt[tid - off] : 0;
    }
    __syncthreads();
    if (tid < 128) cnt[tid] = v + u;
    __syncthreads();
  }
  if (tid < NW) {
    int base = cnt[tid] - __popcll(fw[tid]);
    uint64_t ww = fw[tid];
    while (ww) {
      int j = __ffsll((long long)ww) - 1;
      ww &= ww - 1;
      if (base < 300) {
        int p = tid * 64 + j;
        float4 bx = sbox[(size_t)b * NPRE + p];
        float* ob = out + b * 1200 + base * 4;
        ob[0] = bx.x; ob[1] = bx.y; ob[2] = bx.z; ob[3] = bx.w;
        out[2400 + b * 300 + base] = sscore[(size_t)b * NPRE + p];
        out[3000 + b * 300 + base] = 1.0f;
      }
      ++base;
    }
  }
}

// ---------------- launch ----------------
extern "C" void kernel_launch(void* const* d_in, const int* in_sizes, int n_in,
                              void* d_out, int out_size, void* d_ws, size_t ws_size,
                              hipStream_t stream) {
  const float* x       = (const float*)d_in[0];
  const float* conv1_w = (const float*)d_in[1];
  const float* conv1_b = (const float*)d_in[2];
  const float* obj_w   = (const float*)d_in[3];
  const float* obj_b   = (const float*)d_in[4];
  const float* loc_w   = (const float*)d_in[5];
  const float* loc_b   = (const float*)d_in[6];
  const float* anch    = (const float*)d_in[7];
  const int*   img_h   = (const int*)d_in[8];
  const int*   img_w   = (const int*)d_in[9];

  char* base = (char*)d_ws;
  float*        wt     = (float*)(base + 0);            // 2304*512*4 = 4,718,592
  float*        h      = (float*)(base + 4718592);      // 2*2500*512*4 = 10,240,000
  uint64_t*     M      = (uint64_t*)(base + 4718592);   // alias h (9,024,000 <= 10,240,000)
  float*        scores = (float*)(base + 14958592);     // 180,000
  float4*       boxes  = (float4*)(base + 15138592);    // 720,000
  float*        sscore = (float*)(base + 15858592);     // 48,000
  float4*       sbox   = (float4*)(base + 15906592);    // 192,000
  uint64_t*     keep   = (uint64_t*)(base + 16098592);  // 1,504
  float*        xp     = (float*)(base + 16100096);     // 5,537,792
  unsigned int* state  = (unsigned int*)(base + 21637888);  // 1,536
  // wt54b (131,072 B) ALIASES sbox: written by prep, read only by heads,
  // overwritten by topk_sort phase 7 afterwards (stream-ordered safe).
  float*        wt54b  = (float*)(base + 15906592);

  hipLaunchKernelGGL(prep, dim3(6668), dim3(256), 0, stream,
                     conv1_w, wt, x, xp, obj_w, loc_w, wt54b);
  hipLaunchKernelGGL(conv1_gemm, dim3(40, 8, 2), dim3(256), 0, stream, xp, wt, conv1_b, h);
  hipLaunchKernelGGL(heads, dim3(1250), dim3(64), 0, stream, h, wt54b, obj_b, loc_b,
                     anch, img_h, img_w, scores, boxes);
  hipLaunchKernelGGL(topk_sort, dim3(2), dim3(1024), 0, stream, scores, boxes, sscore, sbox);
  hipLaunchKernelGGL(iou_mat, dim3(CMAX, CMAX / 4, 2), dim3(256), 0, stream, sbox, M);
  hipLaunchKernelGGL(nms_scan, dim3(2), dim3(1024), 0, stream, M, sscore, keep, state);
  hipLaunchKernelGGL(iou_rest, dim3(NW, 24, 2), dim3(256), 0, stream, sbox, M, state);
  hipLaunchKernelGGL(nms_finish, dim3(2), dim3(1024), 0, stream, M, sscore, keep, state,
                     sbox, (float*)d_out);
}

// Round 15
// 401.998 us; speedup vs baseline: 1.4086x; 1.0576x over previous
//
#include <hip/hip_runtime.h>
#include <stdint.h>

// ---------------- constants ----------------
#define NPOS 2500      // 50*50
#define NANCH 22500    // NPOS*9
#define NPRE 6000
#define NW 94          // ceil(6000/64)
#define XPAD 2704      // 52*52 padded plane
#define CMAX 32        // restricted NMS chunk budget (2048 candidates)
#define KFAST 2048     // common-path sort depth (= CMAX*64)

// async global->LDS DMA (gfx950). dst is wave-uniform base + lane*size.
__device__ __forceinline__ void gl_lds4(const float* g, float* l) {
  __builtin_amdgcn_global_load_lds((const __attribute__((address_space(1))) void*)g,
                                   (__attribute__((address_space(3))) void*)l, 4, 0, 0);
}
__device__ __forceinline__ void gl_lds16(const float* g, float* l) {
  __builtin_amdgcn_global_load_lds((const __attribute__((address_space(1))) void*)g,
                                   (__attribute__((address_space(3))) void*)l, 16, 0, 0);
}

// ---------------- fused prep: weight transpose + x pad + head-weight transpose ----------------
__global__ __launch_bounds__(256) void prep(const float* __restrict__ w,
                                            float* __restrict__ wt,
                                            const float* __restrict__ x,
                                            float* __restrict__ xp,
                                            const float* __restrict__ objw,
                                            const float* __restrict__ locw,
                                            float* __restrict__ wt54b) {
  __shared__ float tile[32][33];
  int bid = blockIdx.x;
  int tid = threadIdx.x;
  if (bid < 1152) {
    // ---- role A: conv weight transpose ----
    int k0 = (bid % 72) * 32;   // k' = ic*9 + tap
    int o0 = (bid / 72) * 32;
    int tx = tid & 31;
    int ty = tid >> 5;  // 0..7
#pragma unroll
    for (int i = 0; i < 4; ++i) {
      int oc = o0 + ty + i * 8;
      int kp = k0 + tx;
      tile[ty + i * 8][tx] = w[(size_t)oc * 2304 + kp];
    }
    __syncthreads();
#pragma unroll
    for (int i = 0; i < 4; ++i) {
      int kp = k0 + ty + i * 8;
      int ic = kp / 9, tap = kp % 9;
      wt[((size_t)tap * 256 + ic) * 512 + (o0 + tx)] = tile[tx][ty + i * 8];
    }
  } else if (bid < 6560) {
    // ---- role B: zero-pad x ----
    int t = (bid - 1152) * 256 + tid;
    if (t < 2 * 256 * XPAD) {
      int c = t / XPAD;        // b*256 + ic
      int r = t % XPAD;
      int yy = r / 52, xx = r % 52;
      float v = 0.f;
      if (yy >= 1 && yy <= 50 && xx >= 1 && xx <= 50)
        v = x[(size_t)c * NPOS + (yy - 1) * 50 + (xx - 1)];
      xp[t] = v;
    }
  } else {
    // ---- role C: head-weight transpose to [k/4][oc][4] ----
    int t = (bid - 6560) * 256 + tid;
    if (t < 54 * 512) {
      int oc = t / 512, k = t % 512;
      float v = (oc < 18) ? objw[(size_t)oc * 512 + k] : locw[(size_t)(oc - 18) * 512 + k];
      wt54b[((size_t)(k >> 2) * 64 + oc) * 4 + (k & 3)] = v;
    }
  }
}

// ---------------- conv1 3x3 SAME + bias + relu, output NHWC h[b][p][oc] ----------------
// EXACT R7 version (199-203us, best of R2..R10). LDS-read-instruction bound:
// ~46K ds_read_b128/CU x ~10cyc ~= the whole runtime. All restructurings lose
// (R3 VGPR cliff, R4 2x staging, R8/R9 dbuf, R10 occupancy collapse). Frozen.
__global__ __launch_bounds__(256) void conv1_gemm(const float* __restrict__ xp,
                                                  const float* __restrict__ wt,
                                                  const float* __restrict__ bias,
                                                  float* __restrict__ h) {
  __shared__ __align__(16) float As[32][64];
  __shared__ __align__(16) float Bs[32][64];
  int b = blockIdx.z;
  int m0 = blockIdx.x * 64;
  int oc0 = blockIdx.y * 64;
  int tid = threadIdx.x;
  int lane = tid & 63;
  int wv = tid >> 6;       // wave 0..3
  int tn = tid & 15, tm = tid >> 4;
  float acc[4][4] = {};

  int p = m0 + lane;
  int pc = p < NPOS ? p : (NPOS - 1);
  int py = pc / 50, px = pc % 50;
  const float* gA0 = xp + (size_t)b * 256 * XPAD + py * 52 + px + 53;
  int brow = lane >> 4, bcol4 = (lane & 15) * 4;

  for (int tap = 0; tap < 9; ++tap) {
    int ky = tap / 3 - 1, kx = tap % 3 - 1;
    int koff = ky * 52 + kx;
    for (int icc = 0; icc < 8; ++icc) {
      int ic0 = icc * 32;
      __syncthreads();  // LDS consumed by previous chunk's compute
#pragma unroll
      for (int j = 0; j < 8; ++j) {
        int kk = wv * 8 + j;
        gl_lds4(gA0 + (size_t)(ic0 + kk) * XPAD + koff, &As[kk][0]);
      }
#pragma unroll
      for (int q = 0; q < 2; ++q) {
        int r0 = wv * 8 + q * 4;
        gl_lds16(wt + ((size_t)tap * 256 + ic0 + r0 + brow) * 512 + oc0 + bcol4,
                 &Bs[r0][0]);
      }
      __syncthreads();  // drains vmcnt -> DMAs complete
#pragma unroll
      for (int kk = 0; kk < 32; ++kk) {
        float4 av = *(const float4*)&As[kk][tm * 4];
        float4 bv = *(const float4*)&Bs[kk][tn * 4];
        float am[4] = {av.x, av.y, av.z, av.w};
        float bn[4] = {bv.x, bv.y, bv.z, bv.w};
#pragma unroll
        for (int i = 0; i < 4; ++i)
#pragma unroll
          for (int j = 0; j < 4; ++j) acc[i][j] = fmaf(am[i], bn[j], acc[i][j]);
      }
    }
  }
#pragma unroll
  for (int i = 0; i < 4; ++i) {
    int pp = m0 + tm * 4 + i;
    if (pp < NPOS) {
      float4 v;
      float* vp = (float*)&v;
#pragma unroll
      for (int j = 0; j < 4; ++j) {
        int oc = oc0 + tn * 4 + j;
        vp[j] = fmaxf(acc[i][j] + bias[oc], 0.f);
      }
      *(float4*)&h[((size_t)b * NPOS + pp) * 512 + oc0 + tn * 4] = v;
    }
  }
}

// ---------------- heads: 4 positions per wave (weight reads amortized 4x) ----------------
__global__ __launch_bounds__(64) void heads(const float* __restrict__ h,
                                            const float* __restrict__ wt54b,
                                            const float* __restrict__ objb,
                                            const float* __restrict__ locb,
                                            const float* __restrict__ anch,
                                            const int* __restrict__ imgh,
                                            const int* __restrict__ imgw,
                                            float* __restrict__ scores,
                                            float4* __restrict__ boxes) {
  __shared__ float hv[4 * 512];
  __shared__ float outs[4][64];
  int blk = blockIdx.x;             // 0..1249
  int b = blk / 625;
  int p0 = (blk % 625) * 4;         // 4 consecutive positions
  int lane = threadIdx.x;
  const float4* hp4 = (const float4*)(h + ((size_t)b * NPOS + p0) * 512);
  float4* hv4 = (float4*)hv;
#pragma unroll
  for (int q = 0; q < 8; ++q) hv4[lane + 64 * q] = hp4[lane + 64 * q];
  __syncthreads();
  if (lane < 54) {
    float bias0 = (lane < 18) ? objb[lane] : locb[lane - 18];
    float a0 = bias0, a1 = bias0, a2 = bias0, a3 = bias0;
    const float4* w4 = (const float4*)wt54b;
#pragma unroll 4
    for (int k = 0; k < 128; ++k) {
      float4 wv = w4[k * 64 + lane];
      float4 h0 = hv4[k], h1 = hv4[128 + k], h2 = hv4[256 + k], h3 = hv4[384 + k];
      a0 = fmaf(wv.x, h0.x, a0); a0 = fmaf(wv.y, h0.y, a0);
      a0 = fmaf(wv.z, h0.z, a0); a0 = fmaf(wv.w, h0.w, a0);
      a1 = fmaf(wv.x, h1.x, a1); a1 = fmaf(wv.y, h1.y, a1);
      a1 = fmaf(wv.z, h1.z, a1); a1 = fmaf(wv.w, h1.w, a1);
      a2 = fmaf(wv.x, h2.x, a2); a2 = fmaf(wv.y, h2.y, a2);
      a2 = fmaf(wv.z, h2.z, a2); a2 = fmaf(wv.w, h2.w, a2);
      a3 = fmaf(wv.x, h3.x, a3); a3 = fmaf(wv.y, h3.y, a3);
      a3 = fmaf(wv.z, h3.z, a3); a3 = fmaf(wv.w, h3.w, a3);
    }
    outs[0][lane] = a0; outs[1][lane] = a1; outs[2][lane] = a2; outs[3][lane] = a3;
  }
  __syncthreads();
  if (lane < 36) {
    int pi = lane / 9, a = lane % 9;
    int p = p0 + pi;
    float l0 = outs[pi][2 * a], l1 = outs[pi][2 * a + 1];
    float mx = fmaxf(l0, l1);
    float e0 = expf(l0 - mx);
    float e1 = expf(l1 - mx);
    float s = e1 / (e0 + e1);
    float d0 = outs[pi][18 + 4 * a + 0];
    float d1 = outs[pi][18 + 4 * a + 1];
    float d2 = outs[pi][18 + 4 * a + 2];
    float d3 = outs[pi][18 + 4 * a + 3];
    int ai = p * 9 + a;
    float4 A = ((const float4*)anch)[ai];
    float aw = A.z - A.x, ah = A.w - A.y;
    float acx = A.x + 0.5f * aw, acy = A.y + 0.5f * ah;
    float cx = acx + d0 * aw, cy = acy + d1 * ah;
    float w = aw * expf(d2), hh = ah * expf(d3);
    float W = (float)imgw[0], H = (float)imgh[0];
    float x1 = fminf(fmaxf(cx - 0.5f * w, 0.f), W);
    float y1 = fminf(fmaxf(cy - 0.5f * hh, 0.f), H);
    float x2 = fminf(fmaxf(cx + 0.5f * w, 0.f), W);
    float y2 = fminf(fmaxf(cy + 0.5f * hh, 0.f), H);
    bool valid = (x2 - x1 >= 16.f) && (y2 - y1 >= 16.f);
    scores[(size_t)b * NANCH + ai] = valid ? s : -1.f;
    boxes[(size_t)b * NANCH + ai] = make_float4(x1, y1, x2, y2);
  }
}

// ---------------- top-K select + stable radix sort (one block per batch) ----------------
__device__ inline unsigned int mono_of(float f) {
  unsigned int u = __float_as_uint(f);
  return (u & 0x80000000u) ? ~u : (u | 0x80000000u);
}

// strict suffix sum over 1024 per-thread values (2 barriers)
__device__ __forceinline__ unsigned int suffix_strict(unsigned int v,
                                                      unsigned int* partw,
                                                      int tid, int lane, int wv) {
  unsigned int inc = v;
#pragma unroll
  for (int d = 1; d < 64; d <<= 1) {
    unsigned int u = __shfl_down(inc, d, 64);
    if (lane + d < 64) inc += u;
  }
  if (lane == 0) partw[wv] = inc;  // wave total
  __syncthreads();
  if (tid < 16) {
    unsigned int tot = partw[tid];
    unsigned int inc2 = tot;
#pragma unroll
    for (int d = 1; d < 16; d <<= 1) {
      unsigned int u = __shfl_down(inc2, d, 64);
      if (tid + d < 16) inc2 += u;
    }
    partw[tid] = inc2 - tot;  // strict suffix of later waves
  }
  __syncthreads();
  return partw[wv] + (inc - v);
}

// R6: wave-aggregated hist adds regressed — plain atomics. R7: 6-pass 6-bit
// stable LSD radix. R15: templated on sort depth — common path sorts only
// KFAST=2048 (all NMS consumes within the CMAX budget; first 2048 of the
// 6000-sort are identical by determinism). GATED full version runs only on the
// fallback path (state.done==0) to produce the complete 6000 for nms_finish.
template <int KSEL, int SLOTK, int TBLSZ, bool GATED>
__global__ __launch_bounds__(1024) void topk_sort_t(const float* __restrict__ scores,
                                                    const float4* __restrict__ boxes,
                                                    float* __restrict__ sscore,
                                                    float4* __restrict__ sbox,
                                                    const unsigned int* __restrict__ state) {
  int b = blockIdx.x;
  if (GATED && state[b * 192 + 189]) return;  // common path: NMS already done
  const float* sc = scores + (size_t)b * NANCH;
  __shared__ unsigned int hist[4096];
  __shared__ unsigned int part[1024];
  __shared__ unsigned short pidA[SLOTK * 64];
  __shared__ unsigned short pidB[SLOTK * 64];
  __shared__ unsigned short table[TBLSZ];   // 64 digits x SLOTK slots (padded)
  __shared__ int res[8];
  int tid = threadIdx.x;
  int lane = tid & 63;
  int wv = tid >> 6;

  // ---------- phase 1: top-12-bit histogram ----------
  for (int i = tid; i < 4096; i += 1024) hist[i] = 0;
  __syncthreads();
  for (int i = tid; i < NANCH; i += 1024) atomicAdd(&hist[mono_of(sc[i]) >> 20], 1u);
  __syncthreads();
  {
    unsigned int h0 = hist[4 * tid], h1 = hist[4 * tid + 1];
    unsigned int h2 = hist[4 * tid + 2], h3 = hist[4 * tid + 3];
    unsigned int c = suffix_strict(h0 + h1 + h2 + h3, part, tid, lane, wv);
    const unsigned int need = KSEL;
    if (c < need && c + h3 >= need) { res[0] = 4 * tid + 3; res[1] = (int)c; }
    c += h3;
    if (c < need && c + h2 >= need) { res[0] = 4 * tid + 2; res[1] = (int)c; }
    c += h2;
    if (c < need && c + h1 >= need) { res[0] = 4 * tid + 1; res[1] = (int)c; }
    c += h1;
    if (c < need && c + h0 >= need) { res[0] = 4 * tid + 0; res[1] = (int)c; }
  }
  __syncthreads();
  int t1 = res[0], a1 = res[1];
  __syncthreads();

  // ---------- phase 2: middle-12 bits within bin t1 ----------
  for (int i = tid; i < 4096; i += 1024) hist[i] = 0;
  __syncthreads();
  for (int i = tid; i < NANCH; i += 1024) {
    unsigned int m = mono_of(sc[i]);
    if ((int)(m >> 20) == t1) atomicAdd(&hist[(m >> 8) & 0xFFF], 1u);
  }
  __syncthreads();
  {
    unsigned int h0 = hist[4 * tid], h1 = hist[4 * tid + 1];
    unsigned int h2 = hist[4 * tid + 2], h3 = hist[4 * tid + 3];
    unsigned int c = suffix_strict(h0 + h1 + h2 + h3, part, tid, lane, wv);
    const unsigned int need = (unsigned)(KSEL - a1);
    if (c < need && c + h3 >= need) { res[2] = 4 * tid + 3; res[3] = (int)c; }
    c += h3;
    if (c < need && c + h2 >= need) { res[2] = 4 * tid + 2; res[3] = (int)c; }
    c += h2;
    if (c < need && c + h1 >= need) { res[2] = 4 * tid + 1; res[3] = (int)c; }
    c += h1;
    if (c < need && c + h0 >= need) { res[2] = 4 * tid + 0; res[3] = (int)c; }
  }
  __syncthreads();
  int t2 = res[2], a2 = res[3];
  __syncthreads();

  // ---------- phase 3: low-8 bits within (t1,t2) ----------
  for (int i = tid; i < 256; i += 1024) hist[i] = 0;
  __syncthreads();
  unsigned int top24 = ((unsigned int)t1 << 12) | (unsigned int)t2;
  for (int i = tid; i < NANCH; i += 1024) {
    unsigned int m = mono_of(sc[i]);
    if ((m >> 8) == top24) atomicAdd(&hist[m & 0xFF], 1u);
  }
  __syncthreads();
  {
    unsigned int hb = (tid < 256) ? hist[tid] : 0;
    unsigned int c = suffix_strict(hb, part, tid, lane, wv);
    if (tid < 256) {
      const unsigned int need = (unsigned)(KSEL - a1 - a2);
      if (c < need && c + hb >= need) {
        res[4] = tid;
        res[6] = (int)(need - c);                         // ties_needed
        res[7] = (hb == need - c) ? NANCH : -1;           // idx_cut or TBD
      }
    }
  }
  __syncthreads();
  int t3 = res[4];
  unsigned int T = (top24 << 8) | (unsigned int)t3;
  int ties_needed = res[6];
  int idx_cut = res[7];
  __syncthreads();

  // ---------- phase 4 (rare): tie resolution by smallest index ----------
  if (idx_cut < 0) {
    for (int i = tid; i < 704; i += 1024) hist[i] = 0;
    __syncthreads();
    for (int i = tid; i < NANCH; i += 1024)
      if (mono_of(sc[i]) == T) atomicAdd(&hist[i >> 5], 1u);
    __syncthreads();
    if (tid == 0) {
      int c = 0, cut = NANCH;
      for (int bin = 0; bin < 704; ++bin) {
        int hc = (int)hist[bin];
        if (c + hc >= ties_needed) {
          int c2 = c;
          for (int idx = bin * 32; idx < bin * 32 + 32; ++idx) {
            if (idx < NANCH && mono_of(sc[idx]) == T) {
              ++c2;
              if (c2 == ties_needed) { cut = idx; break; }
            }
          }
          break;
        }
        c += hc;
      }
      res[7] = cut;
    }
    __syncthreads();
    idx_cut = res[7];
    __syncthreads();
  }

  // ---------- phase 5: deterministic idx-order compact (blocked ranges + scan) ----------
  int base0 = tid * 22;  // 1024*22 = 22528 >= NANCH
  unsigned int selm = 0;
  int cnt = 0;
  for (int k = 0; k < 22; ++k) {
    int i = base0 + k;
    if (i < NANCH) {
      unsigned int m = mono_of(sc[i]);
      if (m > T || (m == T && i <= idx_cut)) { selm |= 1u << k; ++cnt; }
    }
  }
  {
    int inc = cnt;
#pragma unroll
    for (int d = 1; d < 64; d <<= 1) {
      int u = __shfl_up(inc, d, 64);
      if (lane >= d) inc += u;
    }
    if (lane == 63) part[wv] = (unsigned int)inc;
    __syncthreads();
    if (tid < 16) {
      int v = (int)part[tid];
      int inc2 = v;
#pragma unroll
      for (int d = 1; d < 16; d <<= 1) {
        int u = __shfl_up(inc2, d, 16);
        if (tid >= d) inc2 += u;
      }
      part[tid] = (unsigned int)(inc2 - v);  // exclusive wave base
    }
    __syncthreads();
    int pos = (int)part[wv] + (inc - cnt);
    for (int k = 0; k < 22; ++k)
      if ((selm >> k) & 1u) pidA[pos++] = (unsigned short)(base0 + k);
  }
  __syncthreads();

  // ---------- phase 6: 6-pass 6-bit stable LSD radix, key = ~mono (asc) ----------
  unsigned short* src = pidA;
  unsigned short* dst = pidB;
  constexpr int KITER = (SLOTK + 15) / 16;
  constexpr int VPT = TBLSZ / 1024;
  for (int pass = 0; pass < 6; ++pass) {
    int shift = pass * 6;
    for (int i = tid; i < TBLSZ; i += 1024) table[i] = 0;
    __syncthreads();
    int dig[KITER], irk[KITER], pidr[KITER];
#pragma unroll
    for (int k = 0; k < KITER; ++k) {
      dig[k] = 0; irk[k] = 0; pidr[k] = 0;
      int s = wv + 16 * k;          // wave-uniform
      if (s < SLOTK) {
        int e = s * 64 + lane;
        bool act = e < KSEL;
        int pid = act ? (int)src[e] : 0;
        unsigned int key = act ? ~mono_of(sc[pid]) : 0u;
        int d = (int)((key >> shift) & 63u);
        uint64_t peers = __ballot(act);
#pragma unroll
        for (int bb = 0; bb < 6; ++bb) {
          uint64_t bl = __ballot(((d >> bb) & 1) != 0);
          peers &= ((d >> bb) & 1) ? bl : ~bl;
        }
        if (act) {
          dig[k] = d;
          pidr[k] = pid;
          irk[k] = (int)__popcll(peers & ((1ull << lane) - 1ull));
          int leader = __ffsll((long long)peers) - 1;
          if (lane == leader)
            table[d * SLOTK + s] = (unsigned short)__popcll(peers);
        }
      }
    }
    __syncthreads();
    // exclusive scan over table[0..TBLSZ) (digit-major, slot-minor)
    {
      int tb = tid * VPT;
      int v[VPT];
      int lsum = 0;
#pragma unroll
      for (int q = 0; q < VPT; ++q) { v[q] = table[tb + q]; lsum += v[q]; }
      int inc = lsum;
#pragma unroll
      for (int d = 1; d < 64; d <<= 1) {
        int u = __shfl_up(inc, d, 64);
        if (lane >= d) inc += u;
      }
      if (lane == 63) part[wv] = (unsigned int)inc;
      __syncthreads();
      if (tid < 16) {
        int vv = (int)part[tid];
        int inc2 = vv;
#pragma unroll
        for (int d = 1; d < 16; d <<= 1) {
          int u = __shfl_up(inc2, d, 16);
          if (tid >= d) inc2 += u;
        }
        part[tid] = (unsigned int)(inc2 - vv);
      }
      __syncthreads();
      int run = (int)part[wv] + (inc - lsum);
#pragma unroll
      for (int q = 0; q < VPT; ++q) { table[tb + q] = (unsigned short)run; run += v[q]; }
    }
    __syncthreads();
    // scatter (stable): pos = base(digit,slot) + intra-slot rank
#pragma unroll
    for (int k = 0; k < KITER; ++k) {
      int s = wv + 16 * k;
      if (s < SLOTK) {
        int e = s * 64 + lane;
        if (e < KSEL) {
          int pos = (int)table[dig[k] * SLOTK + s] + irk[k];
          dst[pos] = (unsigned short)pidr[k];
        }
      }
    }
    __syncthreads();
    unsigned short* tmp = src; src = dst; dst = tmp;
  }
  // 6 passes -> result back in pidA (== src)

  // ---------- phase 7: gather sorted scores/boxes ----------
  for (int r = tid; r < KSEL; r += 1024) {
    int idx = (int)src[r];
    sscore[(size_t)b * NPRE + r] = sc[idx];
    sbox[(size_t)b * NPRE + r] = boxes[(size_t)b * NANCH + idx];
  }
}

// ---------------- IoU suppression bitmask (shared body) ----------------
__device__ __forceinline__ void iou_tile(const float4* __restrict__ sbox,
                                         uint64_t* __restrict__ M,
                                         int b, int it, int jt, int tid,
                                         float4* bi, float4* bj) {
  if (tid < 64) {
    int i = it * 64 + tid;
    bi[tid] = (i < NPRE) ? sbox[(size_t)b * NPRE + i] : make_float4(0, 0, 0, 0);
  }
  {
    int j = jt * 256 + tid;
    bj[tid] = (j < NPRE) ? sbox[(size_t)b * NPRE + j] : make_float4(0, 0, 0, 0);
  }
  __syncthreads();
  int li = tid & 63, wq = tid >> 6;
  int i = it * 64 + li;
  int w = jt * 4 + wq;
  if (i < NPRE && w < NW) {
    float4 A = bi[li];
    float areaA = (A.z - A.x) * (A.w - A.y);
    uint64_t bits = 0;
#pragma unroll 8
    for (int jj = 0; jj < 64; ++jj) {
      int j = w * 64 + jj;
      float4 Bx = bj[wq * 64 + jj];
      float ix1 = fmaxf(A.x, Bx.x), iy1 = fmaxf(A.y, Bx.y);
      float ix2 = fminf(A.z, Bx.z), iy2 = fminf(A.w, Bx.w);
      float inter = fmaxf(ix2 - ix1, 0.f) * fmaxf(iy2 - iy1, 0.f);
      float areaB = (Bx.z - Bx.x) * (Bx.w - Bx.y);
      float iou = inter / (areaA + areaB - inter);
      if ((j > i) && (j < NPRE) && (iou > 0.7f)) bits |= (1ull << jj);
    }
    M[((size_t)b * NPRE + i) * NW + w] = bits;
  }
}

// common path: rows < CMAX*64 AND columns w < CMAX
__global__ __launch_bounds__(256) void iou_mat(const float4* __restrict__ sbox,
                                               uint64_t* __restrict__ M) {
  __shared__ float4 bi[64];
  __shared__ float4 bj[256];
  iou_tile(sbox, M, blockIdx.z, blockIdx.x, blockIdx.y, threadIdx.x, bi, bj);
}

// fallback complement: (rows >= 2048, all cols) + (rows < 2048, cols >= 32)
__global__ __launch_bounds__(256) void iou_rest(const float4* __restrict__ sbox,
                                                uint64_t* __restrict__ M,
                                                const unsigned int* __restrict__ state) {
  if (state[blockIdx.z * 192 + 189]) return;  // done
  int it = blockIdx.x, jt = blockIdx.y;
  if (it < CMAX && jt < CMAX / 4) return;     // covered by iou_mat
  __shared__ float4 bi[64];
  __shared__ float4 bj[256];
  iou_tile(sbox, M, blockIdx.z, it, jt, threadIdx.x, bi, bj);
}

// ---------------- NMS scan: wave0 serial closure + block-parallel OR + early exit ----------------
__device__ inline uint64_t shfl64(uint64_t v, int src) {
  int lo = __shfl((int)(unsigned int)(v & 0xFFFFFFFFull), src, 64);
  int hi = __shfl((int)(unsigned int)(v >> 32), src, 64);
  return ((uint64_t)(unsigned int)hi << 32) | (unsigned int)lo;
}

// one NMS chunk step; OR restricted to w < wlimit
__device__ __forceinline__ void nms_chunk(const uint64_t* __restrict__ Mb,
                                          const float* __restrict__ sscore,
                                          uint64_t* __restrict__ keep,
                                          int b, int c, int tid, int wlimit,
                                          unsigned int* supLo, unsigned int* supHi,
                                          int* klist, int* knS, int* countS) {
  int ibase = c * 64;
  if (tid < 64) {
    int lane = tid;
    if (lane == 0) *knS = 0;
    uint64_t supc = ((uint64_t)supHi[c] << 32) | supLo[c];
    uint64_t validm = (c == NW - 1) ? ((1ull << (NPRE - (NW - 1) * 64)) - 1ull) : ~0ull;
    int pos = ibase + lane;
    uint64_t myrow = (pos < NPRE) ? Mb[(size_t)pos * NW + c] : 0ull;
    bool sval = (pos < NPRE) && (sscore[(size_t)b * NPRE + pos] >= 0.f);
    uint64_t vb = __ballot(sval);
    uint64_t cur = validm & ~supc;
    uint64_t kept = 0;
    while (cur) {
      int i = __ffsll((long long)cur) - 1;
      kept |= (1ull << i);
      cur &= ~(1ull << i);
      uint64_t row = shfl64(myrow, i);
      cur &= ~row;
    }
    if (kept & (1ull << lane)) {
      int pp = atomicAdd(knS, 1);
      klist[pp] = lane;
    }
    if (lane == 0) {
      keep[b * NW + c] = kept;
      *countS += __popcll(kept & vb);
    }
  }
  __syncthreads();  // [A] klist/knS/count visible; sup[c] consumed
  int kn = *knS;
  for (int t = tid; t < kn * 128; t += 1024) {
    int ii = t >> 7, w = t & 127;
    if (w > c && w < wlimit) {
      uint64_t row = Mb[(size_t)(ibase + klist[ii]) * NW + w];
      unsigned int lo = (unsigned int)row;
      unsigned int hi = (unsigned int)(row >> 32);
      if (lo) atomicOr(&supLo[w], lo);
      if (hi) atomicOr(&supHi[w], hi);
    }
  }
  __syncthreads();  // [B] sup updated before next chunk's closure
}

// phase A: chunks 0..CMAX, OR width limited to CMAX
__global__ __launch_bounds__(1024) void nms_scan(const uint64_t* __restrict__ M,
                                                 const float* __restrict__ sscore,
                                                 uint64_t* __restrict__ keep,
                                                 unsigned int* __restrict__ state) {
  __shared__ unsigned int supLo[NW], supHi[NW];
  __shared__ int klist[64];
  __shared__ int knS;
  __shared__ int countS;
  int b = blockIdx.x;
  int tid = threadIdx.x;
  const uint64_t* Mb = M + (size_t)b * NPRE * NW;

  for (int w = tid; w < NW; w += 1024) {
    supLo[w] = 0;
    supHi[w] = 0;
    keep[b * NW + w] = 0;  // early-exit / fallback leaves untouched chunks zeroed
  }
  if (tid == 0) countS = 0;
  __syncthreads();

  int done = 0;
  for (int c = 0; c < CMAX; ++c) {
    nms_chunk(Mb, sscore, keep, b, c, tid, CMAX, supLo, supHi, klist, &knS, &countS);
    if (countS >= 300) { done = 1; break; }  // uniform: countS read post-barrier
  }
  __syncthreads();
  unsigned int* st = state + b * 192;
  for (int w = tid; w < NW; w += 1024) { st[w] = supLo[w]; st[94 + w] = supHi[w]; }
  if (tid == 0) { st[188] = (unsigned int)countS; st[189] = (unsigned int)done; }
}

// fallback scan + emit, merged. Part 1 (only when !done): reconstruct
// sup[w>=CMAX] exactly by re-ORing kept rows over M's high columns, continue
// chunks CMAX..NW full-width. Part 2: emit top-300 (always).
__global__ __launch_bounds__(1024) void nms_finish(const uint64_t* __restrict__ M,
                                                   const float* __restrict__ sscore,
                                                   uint64_t* __restrict__ keep,
                                                   const unsigned int* __restrict__ state,
                                                   const float4* __restrict__ sbox,
                                                   float* __restrict__ out) {
  __shared__ unsigned int supLo[NW], supHi[NW];
  __shared__ int klist[64];
  __shared__ int knS;
  __shared__ int countS;
  __shared__ int cnt[128];
  __shared__ uint64_t fw[NW];
  int b = blockIdx.x;
  int tid = threadIdx.x;
  const uint64_t* Mb = M + (size_t)b * NPRE * NW;
  const unsigned int* st = state + b * 192;

  if (!st[189]) {  // fallback path (uniform)
    for (int w = tid; w < NW; w += 1024) { supLo[w] = st[w]; supHi[w] = st[94 + w]; }
    if (tid == 0) countS = (int)st[188];
    __syncthreads();
    // reconstruct sup words >= CMAX from kept rows of chunks < CMAX
    for (int c = 0; c < CMAX; ++c) {
      uint64_t kw = keep[b * NW + c];
      if (!kw) continue;  // uniform (all threads read same global)
      int ibase = c * 64;
      const int WREST = NW - CMAX;  // 62
      for (int t = tid; t < 64 * WREST; t += 1024) {
        int j = t / WREST;
        int w = CMAX + (t % WREST);
        if ((kw >> j) & 1ull) {
          uint64_t row = Mb[(size_t)(ibase + j) * NW + w];
          unsigned int lo = (unsigned int)row;
          unsigned int hi = (unsigned int)(row >> 32);
          if (lo) atomicOr(&supLo[w], lo);
          if (hi) atomicOr(&supHi[w], hi);
        }
      }
    }
    __syncthreads();
    for (int c = CMAX; c < NW; ++c) {
      nms_chunk(Mb, sscore, keep, b, c, tid, NW, supLo, supHi, klist, &knS, &countS);
      if (countS >= 300) break;
    }
    __threadfence();  // keep[] writes visible to part 2 reads
    __syncthreads();
  }

  // ---- part 2: emit ----
  for (int i = tid; i < 1200; i += 1024) out[b * 1200 + i] = 0.f;
  for (int i = tid; i < 300; i += 1024) {
    out[2400 + b * 300 + i] = 0.f;
    out[3000 + b * 300 + i] = 0.f;
  }
  uint64_t w = 0;
  if (tid < NW) {
    uint64_t kw = keep[b * NW + tid];
    while (kw) {
      int j = __ffsll((long long)kw) - 1;
      kw &= kw - 1;
      if (sscore[(size_t)b * NPRE + tid * 64 + j] >= 0.f) w |= (1ull << j);
    }
    fw[tid] = w;
  }
  if (tid < 128) cnt[tid] = (tid < NW) ? __popcll(w) : 0;
  __syncthreads();
  for (int off = 1; off < 128; off <<= 1) {
    int v = 0, u = 0;
    if (tid < 128) {
      v = cnt[tid];
      u = (tid >= off) ? cnt[tid - off] : 0;
    }
    __syncthreads();
    if (tid < 128) cnt[tid] = v + u;
    __syncthreads();
  }
  if (tid < NW) {
    int base = cnt[tid] - __popcll(fw[tid]);
    uint64_t ww = fw[tid];
    while (ww) {
      int j = __ffsll((long long)ww) - 1;
      ww &= ww - 1;
      if (base < 300) {
        int p = tid * 64 + j;
        float4 bx = sbox[(size_t)b * NPRE + p];
        float* ob = out + b * 1200 + base * 4;
        ob[0] = bx.x; ob[1] = bx.y; ob[2] = bx.z; ob[3] = bx.w;
        out[2400 + b * 300 + base] = sscore[(size_t)b * NPRE + p];
        out[3000 + b * 300 + base] = 1.0f;
      }
      ++base;
    }
  }
}

// ---------------- launch ----------------
extern "C" void kernel_launch(void* const* d_in, const int* in_sizes, int n_in,
                              void* d_out, int out_size, void* d_ws, size_t ws_size,
                              hipStream_t stream) {
  const float* x       = (const float*)d_in[0];
  const float* conv1_w = (const float*)d_in[1];
  const float* conv1_b = (const float*)d_in[2];
  const float* obj_w   = (const float*)d_in[3];
  const float* obj_b   = (const float*)d_in[4];
  const float* loc_w   = (const float*)d_in[5];
  const float* loc_b   = (const float*)d_in[6];
  const float* anch    = (const float*)d_in[7];
  const int*   img_h   = (const int*)d_in[8];
  const int*   img_w   = (const int*)d_in[9];

  char* base = (char*)d_ws;
  float*        wt     = (float*)(base + 0);            // 4,718,592
  float*        h      = (float*)(base + 4718592);      // 10,240,000
  uint64_t*     M      = (uint64_t*)(base + 4718592);   // alias h (9,024,000 <= 10,240,000)
  float*        scores = (float*)(base + 14958592);     // 180,000
  float4*       boxes  = (float4*)(base + 15138592);    // 720,000
  float*        sscore = (float*)(base + 15858592);     // 48,000
  float4*       sbox   = (float4*)(base + 15906592);    // 192,000
  uint64_t*     keep   = (uint64_t*)(base + 16098592);  // 1,504
  float*        xp     = (float*)(base + 16100096);     // 5,537,792
  unsigned int* state  = (unsigned int*)(base + 21637888);  // 1,536
  // wt54b (131,072 B) ALIASES sbox: written by prep, read only by heads,
  // overwritten by topk phase 7 afterwards (stream-ordered safe).
  float*        wt54b  = (float*)(base + 15906592);

  hipLaunchKernelGGL(prep, dim3(6668), dim3(256), 0, stream,
                     conv1_w, wt, x, xp, obj_w, loc_w, wt54b);
  hipLaunchKernelGGL(conv1_gemm, dim3(40, 8, 2), dim3(256), 0, stream, xp, wt, conv1_b, h);
  hipLaunchKernelGGL(heads, dim3(1250), dim3(64), 0, stream, h, wt54b, obj_b, loc_b,
                     anch, img_h, img_w, scores, boxes);
  // common path: sort only top-2048 (all NMS consumes within CMAX budget)
  hipLaunchKernelGGL((topk_sort_t<KFAST, 32, 2048, false>), dim3(2), dim3(1024), 0, stream,
                     scores, boxes, sscore, sbox, state);
  hipLaunchKernelGGL(iou_mat, dim3(CMAX, CMAX / 4, 2), dim3(256), 0, stream, sbox, M);
  hipLaunchKernelGGL(nms_scan, dim3(2), dim3(1024), 0, stream, M, sscore, keep, state);
  // fallback chain (gated on !done): full 6000 sort -> remaining IoU -> rest-scan+emit
  hipLaunchKernelGGL((topk_sort_t<NPRE, 94, 6144, true>), dim3(2), dim3(1024), 0, stream,
                     scores, boxes, sscore, sbox, state);
  hipLaunchKernelGGL(iou_rest, dim3(NW, 24, 2), dim3(256), 0, stream, sbox, M, state);
  hipLaunchKernelGGL(nms_finish, dim3(2), dim3(1024), 0, stream, M, sscore, keep, state,
                     sbox, (float*)d_out);
}